// Round 8
// baseline (442.628 us; speedup 1.0000x reference)
//
#include <hip/hip_runtime.h>
#include <hip/hip_bf16.h>

// LSH attention (Reformer-style), B=16, S=4096, D=128, H=8, bucket=64.
// hash (f32 + f64-fallback argmax, fused rnorm) -> counting sort (+inv, +sorted rnrm) ->
// MFMA chunked attention (trunc bf16 3-term split, dense f16 stores) -> combine.

#define B_ 16
#define S_ 4096
#define D_ 128
#define H_ 8
#define C_ 512          // H * n_buckets
#define SCALE_ 0.08838834764831845f   // D^-0.5

typedef __attribute__((ext_vector_type(8))) short bf16x8;
typedef __attribute__((ext_vector_type(4))) float f32x4;
typedef __attribute__((ext_vector_type(2))) float f32x2;
typedef __attribute__((ext_vector_type(4))) int int4v;
typedef __attribute__((ext_vector_type(2))) _Float16 f16x2;

union BF8U { int4v i; bf16x8 b; };

// pack truncated-bf16 of two floats into one u32 (x0 -> low short)
__device__ __forceinline__ unsigned hi_pack(float x0, float x1) {
    unsigned a, b;
    __builtin_memcpy(&b, &x0, 4);
    __builtin_memcpy(&a, &x1, 4);
    return __builtin_amdgcn_perm(a, b, 0x07060302u);   // [x0.b2,x0.b3,x1.b2,x1.b3]
}
__device__ __forceinline__ float truncbf(float x) {
    unsigned u; __builtin_memcpy(&u, &x, 4);
    u &= 0xFFFF0000u;
    float f; __builtin_memcpy(&f, &u, 4);
    return f;
}

// ---------------------------------------------------------------- hashing (+ fused rnorm)
// f32 packed-FMA main pass; if top-2 margin < 1e-2, recompute in f64.
__global__ __launch_bounds__(256) void hash_kernel(const float* __restrict__ qk,
                                                   const float* __restrict__ rot,
                                                   int* __restrict__ buckets,
                                                   float* __restrict__ rnrm) {
    __shared__ float qtile[64 * 132];
    __shared__ float rtile[128 * 32];
    int b = blockIdx.x >> 6;
    int tile = blockIdx.x & 63;
    int tid = threadIdx.x;

    const float* qbase = qk + ((size_t)b * S_ + (size_t)tile * 64) * D_;
    #pragma unroll
    for (int u = 0; u < 8; ++u) {
        int fi = u * 256 + tid;
        int row = fi >> 5, c = fi & 31;
        float4 vv = ((const float4*)qbase)[fi];
        *((float4*)(qtile + row * 132 + c * 4)) = vv;
        // fused row-norm: 32 consecutive threads hold one row
        float ss = vv.x * vv.x + vv.y * vv.y + vv.z * vv.z + vv.w * vv.w;
        #pragma unroll
        for (int mm = 1; mm < 32; mm <<= 1) ss += __shfl_xor(ss, mm, 64);
        if ((tid & 31) == 0)
            rnrm[(size_t)b * S_ + tile * 64 + row] = 1.0f / fmaxf(sqrtf(ss), 1e-12f);
    }

    int tok = tid >> 2, part = tid & 3;
    int t = tile * 64 + tok;

    for (int h = 0; h < H_; ++h) {
        __syncthreads();
        #pragma unroll
        for (int u = 0; u < 4; ++u) {
            int fi = u * 256 + tid;
            int f = fi >> 3, i4 = fi & 7;
            ((float4*)rtile)[f * 8 + i4] = ((const float4*)rot)[f * 64 + h * 8 + i4];
        }
        __syncthreads();

        f32x2 pf[4] = {};
        #pragma unroll 4
        for (int f = 0; f < 128; ++f) {
            float q = qtile[tok * 132 + f];
            f32x2 q2 = {q, q};
            float4 r0 = *(const float4*)(rtile + f * 32 + part * 8);
            float4 r1 = *(const float4*)(rtile + f * 32 + part * 8 + 4);
            f32x2 ra = {r0.x, r0.y}, rb = {r0.z, r0.w};
            f32x2 rc = {r1.x, r1.y}, rd = {r1.z, r1.w};
            pf[0] += q2 * ra;
            pf[1] += q2 * rb;
            pf[2] += q2 * rc;
            pf[3] += q2 * rd;
        }
        float v1 = -1e30f, v2 = -1e30f; int i1 = 0;
        #pragma unroll
        for (int jj = 0; jj < 8; ++jj) {
            float v = pf[jj >> 1][jj & 1];
            int i = part * 8 + jj;
            if (v > v1 || (v == v1 && i < i1)) { v2 = v1; v1 = v; i1 = i; }
            else v2 = fmaxf(v2, v);
            float nv = -v; int ni = i + 32;
            if (nv > v1 || (nv == v1 && ni < i1)) { v2 = v1; v1 = nv; i1 = ni; }
            else v2 = fmaxf(v2, nv);
        }
        #pragma unroll
        for (int mm = 1; mm <= 2; mm <<= 1) {
            float ov1 = __shfl_xor(v1, mm, 64);
            int   oi1 = __shfl_xor(i1, mm, 64);
            float ov2 = __shfl_xor(v2, mm, 64);
            bool takeOther = (ov1 > v1) || (ov1 == v1 && oi1 < i1);
            float loser = takeOther ? v1 : ov1;
            float nv1 = takeOther ? ov1 : v1;
            int   ni1 = takeOther ? oi1 : i1;
            v2 = fmaxf(fmaxf(v2, ov2), loser);
            v1 = nv1; i1 = ni1;
        }

        int winner = i1;
        if (v1 - v2 < 1e-2f) {          // rare; uniform across the token quad
            double pd[8] = {0, 0, 0, 0, 0, 0, 0, 0};
            #pragma unroll 2
            for (int f = 0; f < 128; ++f) {
                double q = (double)qtile[tok * 132 + f];
                float4 r0 = *((const float4*)(rtile + f * 32 + part * 8));
                float4 r1 = *((const float4*)(rtile + f * 32 + part * 8 + 4));
                pd[0] = fma(q, (double)r0.x, pd[0]);
                pd[1] = fma(q, (double)r0.y, pd[1]);
                pd[2] = fma(q, (double)r0.z, pd[2]);
                pd[3] = fma(q, (double)r0.w, pd[3]);
                pd[4] = fma(q, (double)r1.x, pd[4]);
                pd[5] = fma(q, (double)r1.y, pd[5]);
                pd[6] = fma(q, (double)r1.z, pd[6]);
                pd[7] = fma(q, (double)r1.w, pd[7]);
            }
            double bv = -1e300; int bi = 0;
            #pragma unroll
            for (int ii = 0; ii < 8; ++ii) {
                int i = part * 8 + ii;
                double v = pd[ii];
                if (v > bv || (v == bv && i < bi)) { bv = v; bi = i; }
                double nv = -v; int ni = i + 32;
                if (nv > bv || (nv == bv && ni < bi)) { bv = nv; bi = ni; }
            }
            #pragma unroll
            for (int mm = 1; mm <= 2; mm <<= 1) {
                double ov = __shfl_xor(bv, mm, 64);
                int oi = __shfl_xor(bi, mm, 64);
                if (ov > bv || (ov == bv && oi < bi)) { bv = ov; bi = oi; }
            }
            winner = bi;
        }
        if (part == 0) buckets[(((size_t)b * H_ + h) << 12) + t] = winner;
    }
}

// ---------------------------------------------------------------- stable counting sort
// st[pos] = t, inv[t] = pos, rnrm_s[pos] = rnrm[t]*SCALE (per (b,h)).
// NOTE: inv may alias buckets (each index read once before written).
__global__ __launch_bounds__(256) void sort_kernel(const int* __restrict__ buckets,
                                                   int* __restrict__ st,
                                                   int* __restrict__ inv,
                                                   const float* __restrict__ rnrm,
                                                   float* __restrict__ rnrm_s) {
    __shared__ unsigned short hist[256][64];
    __shared__ int base[64];
    __shared__ int totals[64];
    int tid = threadIdx.x;
    const int* bkrow = buckets + (size_t)blockIdx.x * S_;
    const float* rnb = rnrm + (size_t)(blockIdx.x >> 3) * S_;

    unsigned int* h32 = (unsigned int*)hist;
    #pragma unroll
    for (int u = 0; u < 32; ++u) h32[u * 256 + tid] = 0;
    __syncthreads();

    #pragma unroll
    for (int u = 0; u < 16; ++u) {
        int t = tid * 16 + u;
        int bk = bkrow[t];
        hist[tid][bk]++;
    }
    __syncthreads();

    if (tid < 64) {
        int bucket = tid;
        int run = 0;
        for (int ch = 0; ch < 256; ++ch) {
            int v = hist[ch][bucket];
            hist[ch][bucket] = (unsigned short)run;
            run += v;
        }
        totals[bucket] = run;
    }
    __syncthreads();
    if (tid == 0) {
        int acc = 0;
        for (int k = 0; k < 64; ++k) { base[k] = acc; acc += totals[k]; }
    }
    __syncthreads();

    int* strow = st + (size_t)blockIdx.x * S_;
    int* invrow = inv + (size_t)blockIdx.x * S_;
    float* rnsrow = rnrm_s + (size_t)blockIdx.x * S_;
    #pragma unroll
    for (int u = 0; u < 16; ++u) {
        int t = tid * 16 + u;
        int bk = bkrow[t];
        int off = hist[tid][bk];
        hist[tid][bk] = (unsigned short)(off + 1);
        int pos = base[bk] + off;
        strow[pos] = t;
        invrow[t] = pos;
        rnsrow[pos] = rnb[t] * SCALE_;
    }
}

// ---------------------------------------------------------------- in-reg 4x4 transpose
__device__ __forceinline__ void transpose4(const float4 v, int g, float (&w_)[4]) {
    bool b0 = (g & 1) != 0, b1 = (g & 2) != 0;
    float k0 = b1 ? v.z : v.x;
    float k1 = b1 ? v.w : v.y;
    float s0 = b1 ? v.x : v.z;
    float s1 = b1 ? v.y : v.w;
    float r0 = __shfl_xor(s0, 32, 64);
    float r1 = __shfl_xor(s1, 32, 64);
    float kq_ = b0 ? k1 : k0;
    float rq_ = b0 ? r1 : r0;
    float sk  = b0 ? k0 : k1;
    float sr  = b0 ? r0 : r1;
    float tk_ = __shfl_xor(sk, 16, 64);
    float tr_ = __shfl_xor(sr, 16, 64);
    float A0 = b0 ? tk_ : kq_;
    float A1 = b0 ? kq_ : tk_;
    float B0 = b0 ? tr_ : rq_;
    float B1 = b0 ? rq_ : tr_;
    w_[0] = b1 ? B0 : A0;
    w_[1] = b1 ? B1 : A1;
    w_[2] = b1 ? A0 : B0;
    w_[3] = b1 ? A1 : B1;
}

// ---------------------------------------------------------------- MFMA attention
// One block per (b, chunk c): 64 q vs 128 k (chunks c, c-1 mod 512).
// LDS = exactly 32 KB (kvs only) -> 5 blocks/CU. Token ids / sorted rnrm read
// straight from L2. Trunc-based hi/lo bf16 splits packed via v_perm.
template<bool DENSE>
__global__ __launch_bounds__(256) void attn_mfma_kernel(
        const float* __restrict__ qk, const float* __restrict__ rnrm_s,
        const float* __restrict__ vglob, const int* __restrict__ st,
        float* __restrict__ outnum, float* __restrict__ den,
        _Float16* __restrict__ snum, float* __restrict__ sden) {
    // union: {khi [0,8192), klo [8192,16384)} | {vhi, vlo} (short indices)
    __shared__ short kvs[16384];

    // XCD swizzle: logical L = (p%8)*1024 + p/8 -> each batch on one XCD.
    const int p = blockIdx.x;
    const int bc = (p & 7) * 1024 + (p >> 3);
    const int b  = bc >> 9;
    const int c  = bc & 511;
    const int tid = threadIdx.x;
    const int w   = tid >> 6;   // wave 0..3
    const int l   = tid & 63;
    const int g   = l >> 4;     // quad 0..3
    const int m   = l & 15;
    const size_t bS = ((size_t)b << 12);
    const int* stb = st + ((size_t)b << 15);

    const int c1 = (c + 511) & 511;
    const int* tq_p  = stb + c * 64;
    const int* tk1_p = stb + c1 * 64;
    const float* rns0p = rnrm_s + (((size_t)(b * H_ + (c >> 6))) << 12) + (size_t)(c & 63) * 64;
    const float* rns1p = rnrm_s + (((size_t)(b * H_ + (c1 >> 6))) << 12) + (size_t)(c1 & 63) * 64;

    const int qtok_m = tq_p[w * 16 + m];   // this lane's q column token

    bf16x8 qh[4], ql[4];
    f32x4 e4[4];
    f32x4 acc_o[8];
    #pragma unroll
    for (int dt = 0; dt < 8; ++dt) acc_o[dt] = (f32x4){0.f, 0.f, 0.f, 0.f};
    float densum = 0.0f;

    // stage raw qk rows as trunc-bf16 hi/lo, swizzled 16B slots (^ row&7)
    auto stage_k = [&](const int* __restrict__ toks) {
        #pragma unroll
        for (int u = 0; u < 8; ++u) {
            int token = u * 8 + (tid >> 5);
            int cc = tid & 31;
            int tkt = toks[token];
            float4 vv = *(const float4*)(qk + (bS + tkt) * D_ + cc * 4);
            unsigned h0 = hi_pack(vv.x, vv.y), h1 = hi_pack(vv.z, vv.w);
            float r0 = vv.x - truncbf(vv.x), r1 = vv.y - truncbf(vv.y);
            float r2 = vv.z - truncbf(vv.z), r3 = vv.w - truncbf(vv.w);
            unsigned l0 = hi_pack(r0, r1), l1 = hi_pack(r2, r3);
            int kw = token * 128 + ((((cc >> 1) ^ (token & 7)) << 3) | ((cc & 1) << 2));
            *(int2*)&kvs[kw] = make_int2((int)h0, (int)h1);
            *(int2*)&kvs[8192 + kw] = make_int2((int)l0, (int)l1);
        }
    };
    auto stage_v = [&](const int* __restrict__ toks) {
        #pragma unroll
        for (int up = 0; up < 4; ++up) {
            int kq8 = w * 16 + (up & 1) * 8;
            int cc = (up >> 1) * 16 + m;
            float4 va = *(const float4*)(vglob + (bS + toks[kq8 + g]) * D_ + cc * 4);
            float4 vb = *(const float4*)(vglob + (bS + toks[kq8 + 4 + g]) * D_ + cc * 4);
            float wa[4], wb[4];
            transpose4(va, g, wa);              // wa[i] = (token kq8+i, dim cc*4+g)
            transpose4(vb, g, wb);
            unsigned h0 = hi_pack(wa[0], wa[1]), h1 = hi_pack(wa[2], wa[3]);
            unsigned h2 = hi_pack(wb[0], wb[1]), h3 = hi_pack(wb[2], wb[3]);
            float ra0 = wa[0] - truncbf(wa[0]), ra1 = wa[1] - truncbf(wa[1]);
            float ra2 = wa[2] - truncbf(wa[2]), ra3 = wa[3] - truncbf(wa[3]);
            float rb0 = wb[0] - truncbf(wb[0]), rb1 = wb[1] - truncbf(wb[1]);
            float rb2 = wb[2] - truncbf(wb[2]), rb3 = wb[3] - truncbf(wb[3]);
            unsigned l0 = hi_pack(ra0, ra1), l1 = hi_pack(ra2, ra3);
            unsigned l2 = hi_pack(rb0, rb1), l3 = hi_pack(rb2, rb3);
            int d = cc * 4 + g;
            int ds = d ^ ((d >> 3) & 7);
            int kg = kq8 >> 3;
            int idx = (kg * 128 + ds) * 8;
            *(int4*)&kvs[idx] = make_int4((int)h0, (int)h1, (int)h2, (int)h3);
            *(int4*)&kvs[8192 + idx] = make_int4((int)l0, (int)l1, (int)l2, (int)l3);
        }
    };
    // mode 0: self chunk (slot-equality mask); mode 1: look-back chunk
    // (token-id mask — handles hash-round-boundary wrap)
    auto qk_pass = [&](int mode, const float* __restrict__ rns,
                       const int* __restrict__ tkp) {
        #pragma unroll
        for (int kt = 0; kt < 4; ++kt) {
            f32x4 acc = (f32x4){0.f, 0.f, 0.f, 0.f};
            #pragma unroll
            for (int s4 = 0; s4 < 4; ++s4) {
                int kr = (kt * 16 + m) * 128 + (((s4 * 4 + g) ^ (m & 7)) << 3);
                bf16x8 ah = *(const bf16x8*)&kvs[kr];
                bf16x8 al = *(const bf16x8*)&kvs[8192 + kr];
                acc = __builtin_amdgcn_mfma_f32_16x16x32_bf16(ah, qh[s4], acc, 0, 0, 0);
                acc = __builtin_amdgcn_mfma_f32_16x16x32_bf16(ah, ql[s4], acc, 0, 0, 0);
                acc = __builtin_amdgcn_mfma_f32_16x16x32_bf16(al, qh[s4], acc, 0, 0, 0);
            }
            f32x4 rn4 = *(const f32x4*)&rns[kt * 16 + g * 4];
            int4v kt4;
            if (mode == 1) kt4 = *(const int4v*)&tkp[kt * 16 + g * 4];
            f32x4 e;
            #pragma unroll
            for (int r = 0; r < 4; ++r) {
                float ev = __expf(acc[r] * rn4[r]);
                if (mode == 0) {
                    if (kt == w && (g * 4 + r) == m) ev = 0.0f;
                } else {
                    if (kt4[r] == qtok_m) ev = 0.0f;
                }
                e[r] = ev;
                densum += ev;
            }
            e4[kt] = e;
        }
    };
    auto pv_pass = [&]() {
        #pragma unroll
        for (int s = 0; s < 2; ++s) {
            float pav[8];
            #pragma unroll
            for (int c2 = 0; c2 < 2; ++c2) {
                int srcLane = ((g & 1) * 2 + c2) * 16 + m;
                #pragma unroll
                for (int r = 0; r < 4; ++r) {
                    float v0 = __shfl(e4[2 * s][r], srcLane, 64);
                    float v1 = __shfl(e4[2 * s + 1][r], srcLane, 64);
                    pav[c2 * 4 + r] = (g >> 1) ? v1 : v0;
                }
            }
            BF8U pahu, palu;
            #pragma unroll
            for (int j2 = 0; j2 < 4; ++j2) {
                float x0 = pav[2 * j2], x1 = pav[2 * j2 + 1];
                pahu.i[j2] = (int)hi_pack(x0, x1);
                float q0 = x0 - truncbf(x0), q1 = x1 - truncbf(x1);
                palu.i[j2] = (int)hi_pack(q0, q1);
            }
            bf16x8 pah = pahu.b, pal = palu.b;
            #pragma unroll
            for (int dt = 0; dt < 8; ++dt) {
                int d = dt * 16 + m;
                int ds = d ^ ((d >> 3) & 7);
                int base = ((s * 4 + g) * 128 + ds) * 8;
                bf16x8 vh = *(const bf16x8*)&kvs[base];
                bf16x8 vl = *(const bf16x8*)&kvs[8192 + base];
                acc_o[dt] = __builtin_amdgcn_mfma_f32_16x16x32_bf16(pah, vh, acc_o[dt], 0, 0, 0);
                acc_o[dt] = __builtin_amdgcn_mfma_f32_16x16x32_bf16(pal, vh, acc_o[dt], 0, 0, 0);
                acc_o[dt] = __builtin_amdgcn_mfma_f32_16x16x32_bf16(pah, vl, acc_o[dt], 0, 0, 0);
            }
        }
    };

    // ---- P1: stage K0 (self chunk = q tokens)
    stage_k(tq_p);
    __syncthreads();

    // ---- P2: Q B-frags directly from staged LDS (q rows == k rows); QK0
    #pragma unroll
    for (int s4 = 0; s4 < 4; ++s4) {
        int qr = (w * 16 + m) * 128 + (((s4 * 4 + g) ^ (m & 7)) << 3);
        qh[s4] = *(const bf16x8*)&kvs[qr];
        ql[s4] = *(const bf16x8*)&kvs[8192 + qr];
    }
    qk_pass(0, rns0p, tq_p);
    __syncthreads();

    // ---- P3: stage V0 (overwrites kvs)
    stage_v(tq_p);
    __syncthreads();

    // ---- P4: PV0
    pv_pass();
    __syncthreads();

    // ---- P5: stage K1 (look-back chunk)
    stage_k(tk1_p);
    __syncthreads();

    // ---- P6: QK1
    qk_pass(1, rns1p, tk1_p);
    __syncthreads();

    // ---- P7: stage V1
    stage_v(tk1_p);
    __syncthreads();

    // ---- P8: PV1 + epilogue
    pv_pass();

    densum += __shfl_xor(densum, 16, 64);
    densum += __shfl_xor(densum, 32, 64);

    if (DENSE) {
        // dense store at sorted positions: row 'row' of chunk c -> pos
        const int h = c >> 6;
        const size_t base = (((size_t)(b * H_ + h)) << 12) + (size_t)(c & 63) * 64;
        #pragma unroll
        for (int r = 0; r < 4; ++r) {
            int row = w * 16 + g * 4 + r;
            _Float16* nrow = snum + (base + row) * D_;
            #pragma unroll
            for (int dt = 0; dt < 8; ++dt)
                nrow[dt * 16 + m] = (_Float16)acc_o[dt][r];
        }
        if (g == 0) sden[base + w * 16 + m] = densum;
    } else {
        if (g == 0) atomicAdd(den + bS + qtok_m, densum);
        int4v q4tok = *(const int4v*)&tq_p[w * 16 + g * 4];
        #pragma unroll
        for (int r = 0; r < 4; ++r) {
            float* obase = outnum + ((bS + q4tok[r]) * D_);
            #pragma unroll
            for (int dt = 0; dt < 8; ++dt)
                atomicAdd(obase + dt * 16 + m, acc_o[dt][r]);
        }
    }
}

// ---------------------------------------------------------------- combine
// out[b,t,:] = sum_h snum[(b,h), inv[t], :] / sum_h sden[(b,h), inv[t]]
__global__ __launch_bounds__(256) void combine_kernel(
        const _Float16* __restrict__ snum, const float* __restrict__ sden,
        const int* __restrict__ inv, float* __restrict__ out) {
    int wv = threadIdx.x >> 6, l = threadIdx.x & 63;
    int t = blockIdx.x * 4 + wv;          // 0 .. B*S-1
    int b = t >> 12, s = t & 4095;
    float s0 = 0.f, s1 = 0.f, dsum = 0.f;
    #pragma unroll
    for (int h = 0; h < H_; ++h) {
        int bh = b * H_ + h;
        int pos = inv[((size_t)bh << 12) + s];
        size_t row = ((size_t)bh << 12) + pos;
        dsum += sden[row];
        f16x2 v = *(const f16x2*)(snum + row * D_ + 2 * l);
        s0 += (float)v[0];
        s1 += (float)v[1];
    }
    float rd = 1.0f / dsum;
    ((float2*)(out + (size_t)t * D_))[l] = make_float2(s0 * rd, s1 * rd);
}

// ---------------------------------------------------------------- divide (fallback)
__global__ __launch_bounds__(256) void div_kernel(float* __restrict__ out,
                                                  const float* __restrict__ den) {
    int i = blockIdx.x * 256 + threadIdx.x;  // float4 index
    float4 o = ((float4*)out)[i];
    float dn = den[i >> 5];
    ((float4*)out)[i] = make_float4(o.x / dn, o.y / dn, o.z / dn, o.w / dn);
}

// ---------------------------------------------------------------- launch
extern "C" void kernel_launch(void* const* d_in, const int* in_sizes, int n_in,
                              void* d_out, int out_size, void* d_ws, size_t ws_size,
                              hipStream_t stream) {
    const float* qk  = (const float*)d_in[0];
    const float* v   = (const float*)d_in[1];
    const float* rot = (const float*)d_in[2];
    float* out = (float*)d_out;

    char* ws = (char*)d_ws;
    float* rnrm    = (float*)ws;                        //   262,144 B
    int* buckets   = (int*)(ws + 262144);               // 2,097,152 B
    int* inv       = buckets;                           // aliased (safe: RAW per index)
    int* st        = (int*)(ws + 2359296);              // 2,097,152 B
    float* rnrm_s  = (float*)(ws + 4456448);            // 2,097,152 B
    float* sden    = (float*)(ws + 6553600);            // 2,097,152 B
    _Float16* snum = (_Float16*)(ws + 8650752);         // 134,217,728 B
    const size_t need = 8650752ull + 134217728ull;

    hash_kernel<<<B_ * (S_ / 64), 256, 0, stream>>>(qk, rot, buckets, rnrm);
    sort_kernel<<<B_ * H_, 256, 0, stream>>>(buckets, st, inv, rnrm, rnrm_s);

    if (ws_size >= need) {
        attn_mfma_kernel<true><<<B_ * C_, 256, 0, stream>>>(
            qk, rnrm_s, v, st, nullptr, nullptr, snum, sden);
        combine_kernel<<<B_ * S_ / 4, 256, 0, stream>>>(snum, sden, inv, out);
    } else {
        float* den = sden;   // reuse slot
        hipMemsetAsync(out, 0, (size_t)B_ * S_ * D_ * 4, stream);
        hipMemsetAsync(den, 0, (size_t)B_ * S_ * 4, stream);
        attn_mfma_kernel<false><<<B_ * C_, 256, 0, stream>>>(
            qk, rnrm_s, v, st, out, den, nullptr, nullptr);
        div_kernel<<<B_ * S_ * D_ / 4 / 256, 256, 0, stream>>>(out, den);
    }
}

// Round 9
// 377.255 us; speedup vs baseline: 1.1733x; 1.1733x over previous
//
#include <hip/hip_runtime.h>
#include <hip/hip_bf16.h>

// LSH attention (Reformer-style), B=16, S=4096, D=128, H=8, bucket=64.
// norm -> MFMA hash (trunc-bf16 3-term + f64 margin-fallback argmax) ->
// counting sort (+inv, +sorted rnrm) -> MFMA chunked attention (trunc split,
// LDS token arrays, dense f16 stores) -> combine.

#define B_ 16
#define S_ 4096
#define D_ 128
#define H_ 8
#define C_ 512          // H * n_buckets
#define SCALE_ 0.08838834764831845f   // D^-0.5

typedef __attribute__((ext_vector_type(8))) short bf16x8;
typedef __attribute__((ext_vector_type(4))) float f32x4;
typedef __attribute__((ext_vector_type(4))) int int4v;
typedef __attribute__((ext_vector_type(2))) _Float16 f16x2;

union BF8U { int4v i; bf16x8 b; };

// pack truncated-bf16 of two floats into one u32 (x0 -> low short)
__device__ __forceinline__ unsigned hi_pack(float x0, float x1) {
    unsigned a, b;
    __builtin_memcpy(&b, &x0, 4);
    __builtin_memcpy(&a, &x1, 4);
    return __builtin_amdgcn_perm(a, b, 0x07060302u);   // [x0.b2,x0.b3,x1.b2,x1.b3]
}
__device__ __forceinline__ float truncbf(float x) {
    unsigned u; __builtin_memcpy(&u, &x, 4);
    u &= 0xFFFF0000u;
    float f; __builtin_memcpy(&f, &u, 4);
    return f;
}

// ---------------------------------------------------------------- row 1/norm
__global__ __launch_bounds__(256) void norm_kernel(const float* __restrict__ qk,
                                                   float* __restrict__ rnrm) {
    int half = threadIdx.x >> 5;
    int lane32 = threadIdx.x & 31;
    size_t row = (size_t)blockIdx.x * 8 + half;
    float4 vv = ((const float4*)(qk + row * D_))[lane32];
    float ss = vv.x * vv.x + vv.y * vv.y + vv.z * vv.z + vv.w * vv.w;
    #pragma unroll
    for (int m = 1; m < 32; m <<= 1) ss += __shfl_xor(ss, m, 64);
    if (lane32 == 0) rnrm[row] = 1.0f / fmaxf(sqrtf(ss), 1e-12f);
}

// ---------------------------------------------------------------- in-reg 4x4 transpose
// Lanes l, l^16, l^32, l^48 each hold v = row g (cols 0..3); after: w_[i] = (row i, col g).
__device__ __forceinline__ void transpose4(const float4 v, int g, float (&w_)[4]) {
    bool b0 = (g & 1) != 0, b1 = (g & 2) != 0;
    float k0 = b1 ? v.z : v.x;
    float k1 = b1 ? v.w : v.y;
    float s0 = b1 ? v.x : v.z;
    float s1 = b1 ? v.y : v.w;
    float r0 = __shfl_xor(s0, 32, 64);
    float r1 = __shfl_xor(s1, 32, 64);
    float kq_ = b0 ? k1 : k0;
    float rq_ = b0 ? r1 : r0;
    float sk  = b0 ? k0 : k1;
    float sr  = b0 ? r0 : r1;
    float tk_ = __shfl_xor(sk, 16, 64);
    float tr_ = __shfl_xor(sr, 16, 64);
    float A0 = b0 ? tk_ : kq_;
    float A1 = b0 ? kq_ : tk_;
    float B0 = b0 ? tr_ : rq_;
    float B1 = b0 ? rq_ : tr_;
    w_[0] = b1 ? B0 : A0;
    w_[1] = b1 ? B1 : A1;
    w_[2] = b1 ? A0 : B0;
    w_[3] = b1 ? A1 : B1;
}

// ---------------------------------------------------------------- MFMA hashing
// Per block: 64 tokens. dots = Q(64x128) . W(128x256), W = rot cols, staged
// transposed (Wt[i][f]) in h-pairs of 64 cols. Argmax over [dots, -dots] with
// first-index tiebreak; margin < 2e-2 -> exact f64 recompute (rare).
__global__ __launch_bounds__(256) void hash_kernel(const float* __restrict__ qk,
                                                   const float* __restrict__ rot,
                                                   int* __restrict__ buckets) {
    __shared__ float qtile[64 * 132];          // 33792 B
    __shared__ short wts[16384];               // Wt hi [0,8192), lo [8192,16384)
    __shared__ unsigned char flags[8][64];     // fallback flags

    const int b = blockIdx.x >> 6;
    const int tile = blockIdx.x & 63;
    const int tid = threadIdx.x;
    const int w = tid >> 6, l = tid & 63, g = l >> 4, m = l & 15;

    const float* qbase = qk + ((size_t)b * S_ + (size_t)tile * 64) * D_;
    #pragma unroll
    for (int u = 0; u < 8; ++u) {
        int fi = u * 256 + tid;
        int row = fi >> 5, c = fi & 31;
        float4 vv = ((const float4*)qbase)[fi];
        *((float4*)(qtile + row * 132 + c * 4)) = vv;
    }
    if (tid < 32) ((int4*)flags)[tid] = make_int4(0, 0, 0, 0);
    __syncthreads();

    // A-frags: Q[w*16+m][s*32+g*8+j] trunc hi/lo
    bf16x8 qh[4], qlr[4];
    #pragma unroll
    for (int s = 0; s < 4; ++s) {
        const float* qp = qtile + (w * 16 + m) * 132 + s * 32 + g * 8;
        float4 xa = *(const float4*)qp;
        float4 xb = *(const float4*)(qp + 4);
        BF8U hu, lu;
        hu.i[0] = (int)hi_pack(xa.x, xa.y); hu.i[1] = (int)hi_pack(xa.z, xa.w);
        hu.i[2] = (int)hi_pack(xb.x, xb.y); hu.i[3] = (int)hi_pack(xb.z, xb.w);
        lu.i[0] = (int)hi_pack(xa.x - truncbf(xa.x), xa.y - truncbf(xa.y));
        lu.i[1] = (int)hi_pack(xa.z - truncbf(xa.z), xa.w - truncbf(xa.w));
        lu.i[2] = (int)hi_pack(xb.x - truncbf(xb.x), xb.y - truncbf(xb.y));
        lu.i[3] = (int)hi_pack(xb.z - truncbf(xb.z), xb.w - truncbf(xb.w));
        qh[s] = hu.b; qlr[s] = lu.b;
    }

    for (int hp = 0; hp < 4; ++hp) {
        __syncthreads();                       // prior hp's wts reads done
        // ---- stage Wt pair (cols hp*64 .. hp*64+63), transposed, swizzled
        #pragma unroll
        for (int up = 0; up < 4; ++up) {
            int ftA = w * 8 + up;              // f-tile (4 f's) for va
            int ftB = w * 8 + 4 + up;
            float4 va = *(const float4*)&rot[(size_t)(ftA * 4 + g) * 256 + hp * 64 + m * 4];
            float4 vb = *(const float4*)&rot[(size_t)(ftB * 4 + g) * 256 + hp * 64 + m * 4];
            float wa[4], wb[4];
            transpose4(va, g, wa);             // wa[j] = rot[ftA*4+j][hp*64+m*4+g]
            transpose4(vb, g, wb);
            int ia = m * 4 + g;                // Wt row (i within pair)
            int offA = (((ftA >> 1) ^ (ia & 7)) << 3) | ((ftA & 1) << 2);
            int offB = (((ftB >> 1) ^ (ia & 7)) << 3) | ((ftB & 1) << 2);
            *(int2*)&wts[ia * 128 + offA] =
                make_int2((int)hi_pack(wa[0], wa[1]), (int)hi_pack(wa[2], wa[3]));
            *(int2*)&wts[8192 + ia * 128 + offA] =
                make_int2((int)hi_pack(wa[0] - truncbf(wa[0]), wa[1] - truncbf(wa[1])),
                          (int)hi_pack(wa[2] - truncbf(wa[2]), wa[3] - truncbf(wa[3])));
            *(int2*)&wts[ia * 128 + offB] =
                make_int2((int)hi_pack(wb[0], wb[1]), (int)hi_pack(wb[2], wb[3]));
            *(int2*)&wts[8192 + ia * 128 + offB] =
                make_int2((int)hi_pack(wb[0] - truncbf(wb[0]), wb[1] - truncbf(wb[1])),
                          (int)hi_pack(wb[2] - truncbf(wb[2]), wb[3] - truncbf(wb[3])));
        }
        __syncthreads();

        // ---- dots tiles: C[tok = w*16+g*4+r][i = nt*16+m]
        f32x4 dots_n[4];
        #pragma unroll
        for (int nt = 0; nt < 4; ++nt) {
            f32x4 acc = (f32x4){0.f, 0.f, 0.f, 0.f};
            #pragma unroll
            for (int s = 0; s < 4; ++s) {
                int kr = (nt * 16 + m) * 128 + (((s * 4 + g) ^ (m & 7)) << 3);
                bf16x8 bh = *(const bf16x8*)&wts[kr];
                bf16x8 bl = *(const bf16x8*)&wts[8192 + kr];
                acc = __builtin_amdgcn_mfma_f32_16x16x32_bf16(qh[s], bh, acc, 0, 0, 0);
                acc = __builtin_amdgcn_mfma_f32_16x16x32_bf16(qh[s], bl, acc, 0, 0, 0);
                acc = __builtin_amdgcn_mfma_f32_16x16x32_bf16(qlr[s], bh, acc, 0, 0, 0);
            }
            dots_n[nt] = acc;
        }

        // ---- argmax per (token, h); h = hp*2 + hh
        #pragma unroll
        for (int hh = 0; hh < 2; ++hh) {
            int h = hp * 2 + hh;
            #pragma unroll
            for (int r = 0; r < 4; ++r) {
                float v1 = -1e30f, v2 = -1e30f; int i1 = 0;
                #pragma unroll
                for (int nn = 0; nn < 2; ++nn) {
                    float v = dots_n[hh * 2 + nn][r];
                    int i = nn * 16 + m;
                    if (v > v1 || (v == v1 && i < i1)) { v2 = v1; v1 = v; i1 = i; }
                    else v2 = fmaxf(v2, v);
                    float nv = -v; int ni = i + 32;
                    if (nv > v1 || (nv == v1 && ni < i1)) { v2 = v1; v1 = nv; i1 = ni; }
                    else v2 = fmaxf(v2, nv);
                }
                #pragma unroll
                for (int mask = 1; mask <= 8; mask <<= 1) {
                    float ov1 = __shfl_xor(v1, mask, 64);
                    int   oi1 = __shfl_xor(i1, mask, 64);
                    float ov2 = __shfl_xor(v2, mask, 64);
                    bool takeOther = (ov1 > v1) || (ov1 == v1 && oi1 < i1);
                    float loser = takeOther ? v1 : ov1;
                    float nv1 = takeOther ? ov1 : v1;
                    int   ni1 = takeOther ? oi1 : i1;
                    v2 = fmaxf(fmaxf(v2, ov2), loser);
                    v1 = nv1; i1 = ni1;
                }
                if (m == 0) {
                    int tok = w * 16 + g * 4 + r;
                    if (v1 - v2 < 2e-2f) flags[h][tok] = 1;
                    buckets[(((size_t)(b * H_ + h)) << 12) + tile * 64 + tok] = i1;
                }
            }
        }
    }
    __syncthreads();

    // ---- exact f64 fallback for small-margin (tok,h) (rare)
    int tok = tid >> 2, part = tid & 3;
    for (int h = 0; h < H_; ++h) {
        if (!flags[h][tok]) continue;
        double pd[8] = {0, 0, 0, 0, 0, 0, 0, 0};
        #pragma unroll 2
        for (int f = 0; f < 128; ++f) {
            double q = (double)qtile[tok * 132 + f];
            const float* rp = rot + (size_t)f * 256 + h * 32 + part * 8;
            float4 r0 = *(const float4*)rp;
            float4 r1 = *(const float4*)(rp + 4);
            pd[0] = fma(q, (double)r0.x, pd[0]);
            pd[1] = fma(q, (double)r0.y, pd[1]);
            pd[2] = fma(q, (double)r0.z, pd[2]);
            pd[3] = fma(q, (double)r0.w, pd[3]);
            pd[4] = fma(q, (double)r1.x, pd[4]);
            pd[5] = fma(q, (double)r1.y, pd[5]);
            pd[6] = fma(q, (double)r1.z, pd[6]);
            pd[7] = fma(q, (double)r1.w, pd[7]);
        }
        double bv = -1e300; int bi = 0;
        #pragma unroll
        for (int ii = 0; ii < 8; ++ii) {
            int i = part * 8 + ii;
            double v = pd[ii];
            if (v > bv || (v == bv && i < bi)) { bv = v; bi = i; }
            double nv = -v; int ni = i + 32;
            if (nv > bv || (nv == bv && ni < bi)) { bv = nv; bi = ni; }
        }
        #pragma unroll
        for (int mm = 1; mm <= 2; mm <<= 1) {
            double ov = __shfl_xor(bv, mm, 64);
            int oi = __shfl_xor(bi, mm, 64);
            if (ov > bv || (ov == bv && oi < bi)) { bv = ov; bi = oi; }
        }
        if (part == 0) buckets[(((size_t)(b * H_ + h)) << 12) + tile * 64 + tok] = bi;
    }
}

// ---------------------------------------------------------------- stable counting sort
// st[pos] = t, inv[t] = pos, rnrm_s[pos] = rnrm[t]*SCALE (per (b,h)).
// inv may alias buckets (per-index read-before-write within owning thread).
__global__ __launch_bounds__(256) void sort_kernel(const int* __restrict__ buckets,
                                                   int* __restrict__ st,
                                                   int* __restrict__ inv,
                                                   const float* __restrict__ rnrm,
                                                   float* __restrict__ rnrm_s) {
    __shared__ unsigned short hist[256][64];
    __shared__ int base[64];
    __shared__ int totals[64];
    int tid = threadIdx.x;
    const int* bkrow = buckets + (size_t)blockIdx.x * S_;
    const float* rnb = rnrm + (size_t)(blockIdx.x >> 3) * S_;

    unsigned int* h32 = (unsigned int*)hist;
    #pragma unroll
    for (int u = 0; u < 32; ++u) h32[u * 256 + tid] = 0;
    __syncthreads();

    #pragma unroll
    for (int u = 0; u < 16; ++u) {
        int t = tid * 16 + u;
        int bk = bkrow[t];
        hist[tid][bk]++;
    }
    __syncthreads();

    if (tid < 64) {
        int bucket = tid;
        int run = 0;
        for (int ch = 0; ch < 256; ++ch) {
            int v = hist[ch][bucket];
            hist[ch][bucket] = (unsigned short)run;
            run += v;
        }
        totals[bucket] = run;
    }
    __syncthreads();
    if (tid == 0) {
        int acc = 0;
        for (int k = 0; k < 64; ++k) { base[k] = acc; acc += totals[k]; }
    }
    __syncthreads();

    int* strow = st + (size_t)blockIdx.x * S_;
    int* invrow = inv + (size_t)blockIdx.x * S_;
    float* rnsrow = rnrm_s + (size_t)blockIdx.x * S_;
    #pragma unroll
    for (int u = 0; u < 16; ++u) {
        int t = tid * 16 + u;
        int bk = bkrow[t];
        int off = hist[tid][bk];
        hist[tid][bk] = (unsigned short)(off + 1);
        int pos = base[bk] + off;
        strow[pos] = t;
        invrow[t] = pos;
        rnsrow[pos] = rnb[t] * SCALE_;
    }
}

// ---------------------------------------------------------------- MFMA attention
// One block per (b, chunk c): 64 q vs 128 k (chunks c, c-1 mod 512).
// Token ids + sorted rnrm in LDS (fast phase-head deps); trunc bf16 splits.
template<bool DENSE>
__global__ __launch_bounds__(256) void attn_mfma_kernel(
        const float* __restrict__ qk, const float* __restrict__ rnrm_s,
        const float* __restrict__ vglob, const int* __restrict__ st,
        float* __restrict__ outnum, float* __restrict__ den,
        _Float16* __restrict__ snum, float* __restrict__ sden) {
    __shared__ int tq_s[64];
    __shared__ int tk1_s[64];
    __shared__ float rns0[64];
    __shared__ float rns1[64];
    // union: {khi [0,8192), klo [8192,16384)} | {vhi, vlo} (short indices)
    __shared__ short kvs[16384];

    // XCD swizzle: logical L = (p%8)*1024 + p/8 -> each batch on one XCD.
    const int p = blockIdx.x;
    const int bc = (p & 7) * 1024 + (p >> 3);
    const int b  = bc >> 9;
    const int c  = bc & 511;
    const int tid = threadIdx.x;
    const int w   = tid >> 6;   // wave 0..3
    const int l   = tid & 63;
    const int g   = l >> 4;     // quad 0..3
    const int m   = l & 15;
    const size_t bS = ((size_t)b << 12);
    const int* stb = st + ((size_t)b << 15);

    const int c1 = (c + 511) & 511;
    if (tid < 64) {
        tq_s[tid]  = stb[c * 64 + tid];
        tk1_s[tid] = stb[c1 * 64 + tid];
        rns0[tid] = rnrm_s[(((size_t)(b * H_ + (c >> 6))) << 12) + (size_t)(c & 63) * 64 + tid];
        rns1[tid] = rnrm_s[(((size_t)(b * H_ + (c1 >> 6))) << 12) + (size_t)(c1 & 63) * 64 + tid];
    }
    __syncthreads();

    const int qtok_m = tq_s[w * 16 + m];   // this lane's q column token

    bf16x8 qh[4], ql[4];
    f32x4 e4[4];
    f32x4 acc_o[8];
    #pragma unroll
    for (int dt = 0; dt < 8; ++dt) acc_o[dt] = (f32x4){0.f, 0.f, 0.f, 0.f};
    float densum = 0.0f;

    // stage raw qk rows as trunc-bf16 hi/lo, swizzled 16B slots (^ row&7)
    auto stage_k = [&](const int* __restrict__ toks) {
        #pragma unroll
        for (int u = 0; u < 8; ++u) {
            int token = u * 8 + (tid >> 5);
            int cc = tid & 31;
            int tkt = toks[token];
            float4 vv = *(const float4*)(qk + (bS + tkt) * D_ + cc * 4);
            unsigned h0 = hi_pack(vv.x, vv.y), h1 = hi_pack(vv.z, vv.w);
            unsigned l0 = hi_pack(vv.x - truncbf(vv.x), vv.y - truncbf(vv.y));
            unsigned l1 = hi_pack(vv.z - truncbf(vv.z), vv.w - truncbf(vv.w));
            int kw = token * 128 + ((((cc >> 1) ^ (token & 7)) << 3) | ((cc & 1) << 2));
            *(int2*)&kvs[kw] = make_int2((int)h0, (int)h1);
            *(int2*)&kvs[8192 + kw] = make_int2((int)l0, (int)l1);
        }
    };
    auto stage_v = [&](const int* __restrict__ toks) {
        #pragma unroll
        for (int up = 0; up < 4; ++up) {
            int kq8 = w * 16 + (up & 1) * 8;
            int cc = (up >> 1) * 16 + m;
            float4 va = *(const float4*)(vglob + (bS + toks[kq8 + g]) * D_ + cc * 4);
            float4 vb = *(const float4*)(vglob + (bS + toks[kq8 + 4 + g]) * D_ + cc * 4);
            float wa[4], wb[4];
            transpose4(va, g, wa);              // wa[i] = (token kq8+i, dim cc*4+g)
            transpose4(vb, g, wb);
            unsigned h0 = hi_pack(wa[0], wa[1]), h1 = hi_pack(wa[2], wa[3]);
            unsigned h2 = hi_pack(wb[0], wb[1]), h3 = hi_pack(wb[2], wb[3]);
            unsigned l0 = hi_pack(wa[0] - truncbf(wa[0]), wa[1] - truncbf(wa[1]));
            unsigned l1 = hi_pack(wa[2] - truncbf(wa[2]), wa[3] - truncbf(wa[3]));
            unsigned l2 = hi_pack(wb[0] - truncbf(wb[0]), wb[1] - truncbf(wb[1]));
            unsigned l3 = hi_pack(wb[2] - truncbf(wb[2]), wb[3] - truncbf(wb[3]));
            int d = cc * 4 + g;
            int ds = d ^ ((d >> 3) & 7);
            int kg = kq8 >> 3;
            int idx = (kg * 128 + ds) * 8;
            *(int4*)&kvs[idx] = make_int4((int)h0, (int)h1, (int)h2, (int)h3);
            *(int4*)&kvs[8192 + idx] = make_int4((int)l0, (int)l1, (int)l2, (int)l3);
        }
    };
    // mode 0: self chunk (slot-equality mask); mode 1: look-back chunk
    // (token-id mask — handles hash-round-boundary wrap)
    auto qk_pass = [&](int mode, const float* __restrict__ rns,
                       const int* __restrict__ tkp) {
        #pragma unroll
        for (int kt = 0; kt < 4; ++kt) {
            f32x4 acc = (f32x4){0.f, 0.f, 0.f, 0.f};
            #pragma unroll
            for (int s4 = 0; s4 < 4; ++s4) {
                int kr = (kt * 16 + m) * 128 + (((s4 * 4 + g) ^ (m & 7)) << 3);
                bf16x8 ah = *(const bf16x8*)&kvs[kr];
                bf16x8 al = *(const bf16x8*)&kvs[8192 + kr];
                acc = __builtin_amdgcn_mfma_f32_16x16x32_bf16(ah, qh[s4], acc, 0, 0, 0);
                acc = __builtin_amdgcn_mfma_f32_16x16x32_bf16(ah, ql[s4], acc, 0, 0, 0);
                acc = __builtin_amdgcn_mfma_f32_16x16x32_bf16(al, qh[s4], acc, 0, 0, 0);
            }
            f32x4 rn4 = *(const f32x4*)&rns[kt * 16 + g * 4];
            int4v kt4;
            if (mode == 1) kt4 = *(const int4v*)&tkp[kt * 16 + g * 4];
            f32x4 e;
            #pragma unroll
            for (int r = 0; r < 4; ++r) {
                float ev = __expf(acc[r] * rn4[r]);
                if (mode == 0) {
                    if (kt == w && (g * 4 + r) == m) ev = 0.0f;
                } else {
                    if (kt4[r] == qtok_m) ev = 0.0f;
                }
                e[r] = ev;
                densum += ev;
            }
            e4[kt] = e;
        }
    };
    auto pv_pass = [&]() {
        #pragma unroll
        for (int s = 0; s < 2; ++s) {
            float pav[8];
            #pragma unroll
            for (int c2 = 0; c2 < 2; ++c2) {
                int srcLane = ((g & 1) * 2 + c2) * 16 + m;
                #pragma unroll
                for (int r = 0; r < 4; ++r) {
                    float v0 = __shfl(e4[2 * s][r], srcLane, 64);
                    float v1 = __shfl(e4[2 * s + 1][r], srcLane, 64);
                    pav[c2 * 4 + r] = (g >> 1) ? v1 : v0;
                }
            }
            BF8U pahu, palu;
            #pragma unroll
            for (int j2 = 0; j2 < 4; ++j2) {
                float x0 = pav[2 * j2], x1 = pav[2 * j2 + 1];
                pahu.i[j2] = (int)hi_pack(x0, x1);
                palu.i[j2] = (int)hi_pack(x0 - truncbf(x0), x1 - truncbf(x1));
            }
            bf16x8 pah = pahu.b, pal = palu.b;
            #pragma unroll
            for (int dt = 0; dt < 8; ++dt) {
                int d = dt * 16 + m;
                int ds = d ^ ((d >> 3) & 7);
                int base = ((s * 4 + g) * 128 + ds) * 8;
                bf16x8 vh = *(const bf16x8*)&kvs[base];
                bf16x8 vl = *(const bf16x8*)&kvs[8192 + base];
                acc_o[dt] = __builtin_amdgcn_mfma_f32_16x16x32_bf16(pah, vh, acc_o[dt], 0, 0, 0);
                acc_o[dt] = __builtin_amdgcn_mfma_f32_16x16x32_bf16(pal, vh, acc_o[dt], 0, 0, 0);
                acc_o[dt] = __builtin_amdgcn_mfma_f32_16x16x32_bf16(pah, vl, acc_o[dt], 0, 0, 0);
            }
        }
    };

    // ---- P1: stage K0 (self chunk = q tokens)
    stage_k(tq_s);
    __syncthreads();

    // ---- P2: Q B-frags directly from staged LDS (q rows == k rows); QK0
    #pragma unroll
    for (int s4 = 0; s4 < 4; ++s4) {
        int qr = (w * 16 + m) * 128 + (((s4 * 4 + g) ^ (m & 7)) << 3);
        qh[s4] = *(const bf16x8*)&kvs[qr];
        ql[s4] = *(const bf16x8*)&kvs[8192 + qr];
    }
    qk_pass(0, rns0, tq_s);
    __syncthreads();

    // ---- P3: stage V0 (overwrites kvs)
    stage_v(tq_s);
    __syncthreads();

    // ---- P4: PV0
    pv_pass();
    __syncthreads();

    // ---- P5: stage K1 (look-back chunk)
    stage_k(tk1_s);
    __syncthreads();

    // ---- P6: QK1
    qk_pass(1, rns1, tk1_s);
    __syncthreads();

    // ---- P7: stage V1
    stage_v(tk1_s);
    __syncthreads();

    // ---- P8: PV1 + epilogue
    pv_pass();

    densum += __shfl_xor(densum, 16, 64);
    densum += __shfl_xor(densum, 32, 64);

    if (DENSE) {
        const int h = c >> 6;
        const size_t base = (((size_t)(b * H_ + h)) << 12) + (size_t)(c & 63) * 64;
        #pragma unroll
        for (int r = 0; r < 4; ++r) {
            int row = w * 16 + g * 4 + r;
            _Float16* nrow = snum + (base + row) * D_;
            #pragma unroll
            for (int dt = 0; dt < 8; ++dt)
                nrow[dt * 16 + m] = (_Float16)acc_o[dt][r];
        }
        if (g == 0) sden[base + w * 16 + m] = densum;
    } else {
        if (g == 0) atomicAdd(den + bS + qtok_m, densum);
        int4v q4tok = *(const int4v*)&tq_s[w * 16 + g * 4];
        #pragma unroll
        for (int r = 0; r < 4; ++r) {
            float* obase = outnum + ((bS + q4tok[r]) * D_);
            #pragma unroll
            for (int dt = 0; dt < 8; ++dt)
                atomicAdd(obase + dt * 16 + m, acc_o[dt][r]);
        }
    }
}

// ---------------------------------------------------------------- combine
__global__ __launch_bounds__(256) void combine_kernel(
        const _Float16* __restrict__ snum, const float* __restrict__ sden,
        const int* __restrict__ inv, float* __restrict__ out) {
    int wv = threadIdx.x >> 6, l = threadIdx.x & 63;
    int t = blockIdx.x * 4 + wv;          // 0 .. B*S-1
    int b = t >> 12, s = t & 4095;
    float s0 = 0.f, s1 = 0.f, dsum = 0.f;
    #pragma unroll
    for (int h = 0; h < H_; ++h) {
        int bh = b * H_ + h;
        int pos = inv[((size_t)bh << 12) + s];
        size_t row = ((size_t)bh << 12) + pos;
        dsum += sden[row];
        f16x2 v = *(const f16x2*)(snum + row * D_ + 2 * l);
        s0 += (float)v[0];
        s1 += (float)v[1];
    }
    float rd = 1.0f / dsum;
    ((float2*)(out + (size_t)t * D_))[l] = make_float2(s0 * rd, s1 * rd);
}

// ---------------------------------------------------------------- divide (fallback)
__global__ __launch_bounds__(256) void div_kernel(float* __restrict__ out,
                                                  const float* __restrict__ den) {
    int i = blockIdx.x * 256 + threadIdx.x;  // float4 index
    float4 o = ((float4*)out)[i];
    float dn = den[i >> 5];
    ((float4*)out)[i] = make_float4(o.x / dn, o.y / dn, o.z / dn, o.w / dn);
}

// ---------------------------------------------------------------- launch
extern "C" void kernel_launch(void* const* d_in, const int* in_sizes, int n_in,
                              void* d_out, int out_size, void* d_ws, size_t ws_size,
                              hipStream_t stream) {
    const float* qk  = (const float*)d_in[0];
    const float* v   = (const float*)d_in[1];
    const float* rot = (const float*)d_in[2];
    float* out = (float*)d_out;

    char* ws = (char*)d_ws;
    float* rnrm    = (float*)ws;                        //   262,144 B
    int* buckets   = (int*)(ws + 262144);               // 2,097,152 B
    int* inv       = buckets;                           // aliased (safe: RAW per index)
    int* st        = (int*)(ws + 2359296);              // 2,097,152 B
    float* rnrm_s  = (float*)(ws + 4456448);            // 2,097,152 B
    float* sden    = (float*)(ws + 6553600);            // 2,097,152 B
    _Float16* snum = (_Float16*)(ws + 8650752);         // 134,217,728 B
    const size_t need = 8650752ull + 134217728ull;

    norm_kernel<<<B_ * S_ / 8, 256, 0, stream>>>(qk, rnrm);
    hash_kernel<<<B_ * (S_ / 64), 256, 0, stream>>>(qk, rot, buckets);
    sort_kernel<<<B_ * H_, 256, 0, stream>>>(buckets, st, inv, rnrm, rnrm_s);

    if (ws_size >= need) {
        attn_mfma_kernel<true><<<B_ * C_, 256, 0, stream>>>(
            qk, rnrm_s, v, st, nullptr, nullptr, snum, sden);
        combine_kernel<<<B_ * S_ / 4, 256, 0, stream>>>(snum, sden, inv, out);
    } else {
        float* den = sden;   // reuse slot
        hipMemsetAsync(out, 0, (size_t)B_ * S_ * D_ * 4, stream);
        hipMemsetAsync(den, 0, (size_t)B_ * S_ * 4, stream);
        attn_mfma_kernel<false><<<B_ * C_, 256, 0, stream>>>(
            qk, rnrm_s, v, st, out, den, nullptr, nullptr);
        div_kernel<<<B_ * S_ * D_ / 4 / 256, 256, 0, stream>>>(out, den);
    }
}

// Round 10
// 361.081 us; speedup vs baseline: 1.2258x; 1.0448x over previous
//
#include <hip/hip_runtime.h>
#include <hip/hip_bf16.h>

// LSH attention (Reformer-style), B=16, S=4096, D=128, H=8, bucket=64.
// norm -> MFMA hash (trunc-bf16 3-term + f64 margin-fallback argmax) ->
// counting sort (+inv, +sorted rnrm) -> MFMA chunked attention (2-buffer
// software pipeline, trunc split, dense f16 nt-stores) -> combine.

#define B_ 16
#define S_ 4096
#define D_ 128
#define H_ 8
#define C_ 512          // H * n_buckets
#define SCALE_ 0.08838834764831845f   // D^-0.5

typedef __attribute__((ext_vector_type(8))) short bf16x8;
typedef __attribute__((ext_vector_type(4))) float f32x4;
typedef __attribute__((ext_vector_type(2))) float f32x2v;
typedef __attribute__((ext_vector_type(4))) int int4v;

union BF8U { int4v i; bf16x8 b; };

// pack truncated-bf16 of two floats into one u32 (x0 -> low short)
__device__ __forceinline__ unsigned hi_pack(float x0, float x1) {
    unsigned a, b;
    __builtin_memcpy(&b, &x0, 4);
    __builtin_memcpy(&a, &x1, 4);
    return __builtin_amdgcn_perm(a, b, 0x07060302u);   // [x0.b2,x0.b3,x1.b2,x1.b3]
}
__device__ __forceinline__ float truncbf(float x) {
    unsigned u; __builtin_memcpy(&u, &x, 4);
    u &= 0xFFFF0000u;
    float f; __builtin_memcpy(&f, &u, 4);
    return f;
}

// ---------------------------------------------------------------- row 1/norm
__global__ __launch_bounds__(256) void norm_kernel(const float* __restrict__ qk,
                                                   float* __restrict__ rnrm) {
    int half = threadIdx.x >> 5;
    int lane32 = threadIdx.x & 31;
    size_t row = (size_t)blockIdx.x * 8 + half;
    float4 vv = ((const float4*)(qk + row * D_))[lane32];
    float ss = vv.x * vv.x + vv.y * vv.y + vv.z * vv.z + vv.w * vv.w;
    #pragma unroll
    for (int m = 1; m < 32; m <<= 1) ss += __shfl_xor(ss, m, 64);
    if (lane32 == 0) rnrm[row] = 1.0f / fmaxf(sqrtf(ss), 1e-12f);
}

// ---------------------------------------------------------------- in-reg 4x4 transpose
// Lanes l, l^16, l^32, l^48 each hold v = row g (cols 0..3); after: w_[i] = (row i, col g).
__device__ __forceinline__ void transpose4(const float4 v, int g, float (&w_)[4]) {
    bool b0 = (g & 1) != 0, b1 = (g & 2) != 0;
    float k0 = b1 ? v.z : v.x;
    float k1 = b1 ? v.w : v.y;
    float s0 = b1 ? v.x : v.z;
    float s1 = b1 ? v.y : v.w;
    float r0 = __shfl_xor(s0, 32, 64);
    float r1 = __shfl_xor(s1, 32, 64);
    float kq_ = b0 ? k1 : k0;
    float rq_ = b0 ? r1 : r0;
    float sk  = b0 ? k0 : k1;
    float sr  = b0 ? r0 : r1;
    float tk_ = __shfl_xor(sk, 16, 64);
    float tr_ = __shfl_xor(sr, 16, 64);
    float A0 = b0 ? tk_ : kq_;
    float A1 = b0 ? kq_ : tk_;
    float B0 = b0 ? tr_ : rq_;
    float B1 = b0 ? rq_ : tr_;
    w_[0] = b1 ? B0 : A0;
    w_[1] = b1 ? B1 : A1;
    w_[2] = b1 ? A0 : B0;
    w_[3] = b1 ? A1 : B1;
}

// ---------------------------------------------------------------- MFMA hashing
__global__ __launch_bounds__(256) void hash_kernel(const float* __restrict__ qk,
                                                   const float* __restrict__ rot,
                                                   int* __restrict__ buckets) {
    __shared__ float qtile[64 * 132];          // 33792 B
    __shared__ short wts[16384];               // Wt hi [0,8192), lo [8192,16384)
    __shared__ unsigned char flags[8][64];     // fallback flags

    const int b = blockIdx.x >> 6;
    const int tile = blockIdx.x & 63;
    const int tid = threadIdx.x;
    const int w = tid >> 6, l = tid & 63, g = l >> 4, m = l & 15;

    const float* qbase = qk + ((size_t)b * S_ + (size_t)tile * 64) * D_;
    #pragma unroll
    for (int u = 0; u < 8; ++u) {
        int fi = u * 256 + tid;
        int row = fi >> 5, c = fi & 31;
        float4 vv = ((const float4*)qbase)[fi];
        *((float4*)(qtile + row * 132 + c * 4)) = vv;
    }
    if (tid < 32) ((int4*)flags)[tid] = make_int4(0, 0, 0, 0);
    __syncthreads();

    // A-frags: Q[w*16+m][s*32+g*8+j] trunc hi/lo
    bf16x8 qh[4], qlr[4];
    #pragma unroll
    for (int s = 0; s < 4; ++s) {
        const float* qp = qtile + (w * 16 + m) * 132 + s * 32 + g * 8;
        float4 xa = *(const float4*)qp;
        float4 xb = *(const float4*)(qp + 4);
        BF8U hu, lu;
        hu.i[0] = (int)hi_pack(xa.x, xa.y); hu.i[1] = (int)hi_pack(xa.z, xa.w);
        hu.i[2] = (int)hi_pack(xb.x, xb.y); hu.i[3] = (int)hi_pack(xb.z, xb.w);
        lu.i[0] = (int)hi_pack(xa.x - truncbf(xa.x), xa.y - truncbf(xa.y));
        lu.i[1] = (int)hi_pack(xa.z - truncbf(xa.z), xa.w - truncbf(xa.w));
        lu.i[2] = (int)hi_pack(xb.x - truncbf(xb.x), xb.y - truncbf(xb.y));
        lu.i[3] = (int)hi_pack(xb.z - truncbf(xb.z), xb.w - truncbf(xb.w));
        qh[s] = hu.b; qlr[s] = lu.b;
    }

    for (int hp = 0; hp < 4; ++hp) {
        __syncthreads();                       // prior hp's wts reads done
        #pragma unroll
        for (int up = 0; up < 4; ++up) {
            int ftA = w * 8 + up;
            int ftB = w * 8 + 4 + up;
            float4 va = *(const float4*)&rot[(size_t)(ftA * 4 + g) * 256 + hp * 64 + m * 4];
            float4 vb = *(const float4*)&rot[(size_t)(ftB * 4 + g) * 256 + hp * 64 + m * 4];
            float wa[4], wb[4];
            transpose4(va, g, wa);
            transpose4(vb, g, wb);
            int ia = m * 4 + g;
            int offA = (((ftA >> 1) ^ (ia & 7)) << 3) | ((ftA & 1) << 2);
            int offB = (((ftB >> 1) ^ (ia & 7)) << 3) | ((ftB & 1) << 2);
            *(int2*)&wts[ia * 128 + offA] =
                make_int2((int)hi_pack(wa[0], wa[1]), (int)hi_pack(wa[2], wa[3]));
            *(int2*)&wts[8192 + ia * 128 + offA] =
                make_int2((int)hi_pack(wa[0] - truncbf(wa[0]), wa[1] - truncbf(wa[1])),
                          (int)hi_pack(wa[2] - truncbf(wa[2]), wa[3] - truncbf(wa[3])));
            *(int2*)&wts[ia * 128 + offB] =
                make_int2((int)hi_pack(wb[0], wb[1]), (int)hi_pack(wb[2], wb[3]));
            *(int2*)&wts[8192 + ia * 128 + offB] =
                make_int2((int)hi_pack(wb[0] - truncbf(wb[0]), wb[1] - truncbf(wb[1])),
                          (int)hi_pack(wb[2] - truncbf(wb[2]), wb[3] - truncbf(wb[3])));
        }
        __syncthreads();

        f32x4 dots_n[4];
        #pragma unroll
        for (int nt = 0; nt < 4; ++nt) {
            f32x4 acc = (f32x4){0.f, 0.f, 0.f, 0.f};
            #pragma unroll
            for (int s = 0; s < 4; ++s) {
                int kr = (nt * 16 + m) * 128 + (((s * 4 + g) ^ (m & 7)) << 3);
                bf16x8 bh = *(const bf16x8*)&wts[kr];
                bf16x8 bl = *(const bf16x8*)&wts[8192 + kr];
                acc = __builtin_amdgcn_mfma_f32_16x16x32_bf16(qh[s], bh, acc, 0, 0, 0);
                acc = __builtin_amdgcn_mfma_f32_16x16x32_bf16(qh[s], bl, acc, 0, 0, 0);
                acc = __builtin_amdgcn_mfma_f32_16x16x32_bf16(qlr[s], bh, acc, 0, 0, 0);
            }
            dots_n[nt] = acc;
        }

        #pragma unroll
        for (int hh = 0; hh < 2; ++hh) {
            int h = hp * 2 + hh;
            #pragma unroll
            for (int r = 0; r < 4; ++r) {
                float v1 = -1e30f, v2 = -1e30f; int i1 = 0;
                #pragma unroll
                for (int nn = 0; nn < 2; ++nn) {
                    float v = dots_n[hh * 2 + nn][r];
                    int i = nn * 16 + m;
                    if (v > v1 || (v == v1 && i < i1)) { v2 = v1; v1 = v; i1 = i; }
                    else v2 = fmaxf(v2, v);
                    float nv = -v; int ni = i + 32;
                    if (nv > v1 || (nv == v1 && ni < i1)) { v2 = v1; v1 = nv; i1 = ni; }
                    else v2 = fmaxf(v2, nv);
                }
                #pragma unroll
                for (int mask = 1; mask <= 8; mask <<= 1) {
                    float ov1 = __shfl_xor(v1, mask, 64);
                    int   oi1 = __shfl_xor(i1, mask, 64);
                    float ov2 = __shfl_xor(v2, mask, 64);
                    bool takeOther = (ov1 > v1) || (ov1 == v1 && oi1 < i1);
                    float loser = takeOther ? v1 : ov1;
                    float nv1 = takeOther ? ov1 : v1;
                    int   ni1 = takeOther ? oi1 : i1;
                    v2 = fmaxf(fmaxf(v2, ov2), loser);
                    v1 = nv1; i1 = ni1;
                }
                if (m == 0) {
                    int tok = w * 16 + g * 4 + r;
                    if (v1 - v2 < 2e-2f) flags[h][tok] = 1;
                    buckets[(((size_t)(b * H_ + h)) << 12) + tile * 64 + tok] = i1;
                }
            }
        }
    }
    __syncthreads();

    // exact f64 fallback for small-margin (tok,h) (rare)
    int tok = tid >> 2, part = tid & 3;
    for (int h = 0; h < H_; ++h) {
        if (!flags[h][tok]) continue;
        double pd[8] = {0, 0, 0, 0, 0, 0, 0, 0};
        #pragma unroll 2
        for (int f = 0; f < 128; ++f) {
            double q = (double)qtile[tok * 132 + f];
            const float* rp = rot + (size_t)f * 256 + h * 32 + part * 8;
            float4 r0 = *(const float4*)rp;
            float4 r1 = *(const float4*)(rp + 4);
            pd[0] = fma(q, (double)r0.x, pd[0]);
            pd[1] = fma(q, (double)r0.y, pd[1]);
            pd[2] = fma(q, (double)r0.z, pd[2]);
            pd[3] = fma(q, (double)r0.w, pd[3]);
            pd[4] = fma(q, (double)r1.x, pd[4]);
            pd[5] = fma(q, (double)r1.y, pd[5]);
            pd[6] = fma(q, (double)r1.z, pd[6]);
            pd[7] = fma(q, (double)r1.w, pd[7]);
        }
        double bv = -1e300; int bi = 0;
        #pragma unroll
        for (int ii = 0; ii < 8; ++ii) {
            int i = part * 8 + ii;
            double v = pd[ii];
            if (v > bv || (v == bv && i < bi)) { bv = v; bi = i; }
            double nv = -v; int ni = i + 32;
            if (nv > bv || (nv == bv && ni < bi)) { bv = nv; bi = ni; }
        }
        #pragma unroll
        for (int mm = 1; mm <= 2; mm <<= 1) {
            double ov = __shfl_xor(bv, mm, 64);
            int oi = __shfl_xor(bi, mm, 64);
            if (ov > bv || (ov == bv && oi < bi)) { bv = ov; bi = oi; }
        }
        if (part == 0) buckets[(((size_t)(b * H_ + h)) << 12) + tile * 64 + tok] = bi;
    }
}

// ---------------------------------------------------------------- stable counting sort
__global__ __launch_bounds__(256) void sort_kernel(const int* __restrict__ buckets,
                                                   int* __restrict__ st,
                                                   int* __restrict__ inv,
                                                   const float* __restrict__ rnrm,
                                                   float* __restrict__ rnrm_s) {
    __shared__ unsigned short hist[256][64];
    __shared__ int base[64];
    __shared__ int totals[64];
    int tid = threadIdx.x;
    const int* bkrow = buckets + (size_t)blockIdx.x * S_;
    const float* rnb = rnrm + (size_t)(blockIdx.x >> 3) * S_;

    unsigned int* h32 = (unsigned int*)hist;
    #pragma unroll
    for (int u = 0; u < 32; ++u) h32[u * 256 + tid] = 0;
    __syncthreads();

    #pragma unroll
    for (int u = 0; u < 16; ++u) {
        int t = tid * 16 + u;
        int bk = bkrow[t];
        hist[tid][bk]++;
    }
    __syncthreads();

    if (tid < 64) {
        int bucket = tid;
        int run = 0;
        for (int ch = 0; ch < 256; ++ch) {
            int v = hist[ch][bucket];
            hist[ch][bucket] = (unsigned short)run;
            run += v;
        }
        totals[bucket] = run;
    }
    __syncthreads();
    if (tid == 0) {
        int acc = 0;
        for (int k = 0; k < 64; ++k) { base[k] = acc; acc += totals[k]; }
    }
    __syncthreads();

    int* strow = st + (size_t)blockIdx.x * S_;
    int* invrow = inv + (size_t)blockIdx.x * S_;
    float* rnsrow = rnrm_s + (size_t)blockIdx.x * S_;
    #pragma unroll
    for (int u = 0; u < 16; ++u) {
        int t = tid * 16 + u;
        int bk = bkrow[t];
        int off = hist[tid][bk];
        hist[tid][bk] = (unsigned short)(off + 1);
        int pos = base[bk] + off;
        strow[pos] = t;
        invrow[t] = pos;
        rnsrow[pos] = rnb[t] * SCALE_;
    }
}

// ---------------------------------------------------------------- MFMA attention
// One block per (b, chunk c): 64 q vs 128 k (chunks c, c-1 mod 512).
// Two LDS buffers (K 32KB, V 32KB); each phase: issue next gather -> MFMA pass
// (hides latency) -> convert+write. 4 syncs. launch_bounds(256,2): LDS caps
// at 2 blocks/CU, so VGPR budget is 256 (no prefetch sinking pressure).
template<bool DENSE>
__global__ __launch_bounds__(256, 2) void attn_mfma_kernel(
        const float* __restrict__ qk, const float* __restrict__ rnrm_s,
        const float* __restrict__ vglob, const int* __restrict__ st,
        float* __restrict__ outnum, float* __restrict__ den,
        _Float16* __restrict__ snum, float* __restrict__ sden) {
    __shared__ int tq_s[64];
    __shared__ int tk1_s[64];
    __shared__ float rns0[64];
    __shared__ float rns1[64];
    __shared__ short kbuf[16384];   // K: hi [0,8192), lo [8192,16384)
    __shared__ short vbuf[16384];   // V^T: hi, lo

    // XCD swizzle: logical L = (p%8)*1024 + p/8 -> each batch on one XCD.
    const int p = blockIdx.x;
    const int bc = (p & 7) * 1024 + (p >> 3);
    const int b  = bc >> 9;
    const int c  = bc & 511;
    const int tid = threadIdx.x;
    const int w   = tid >> 6;   // wave 0..3
    const int l   = tid & 63;
    const int g   = l >> 4;     // quad 0..3
    const int m   = l & 15;
    const size_t bS = ((size_t)b << 12);
    const int* stb = st + ((size_t)b << 15);

    const int c1 = (c + 511) & 511;
    if (tid < 64) {
        tq_s[tid]  = stb[c * 64 + tid];
        tk1_s[tid] = stb[c1 * 64 + tid];
        rns0[tid] = rnrm_s[(((size_t)(b * H_ + (c >> 6))) << 12) + (size_t)(c & 63) * 64 + tid];
        rns1[tid] = rnrm_s[(((size_t)(b * H_ + (c1 >> 6))) << 12) + (size_t)(c1 & 63) * 64 + tid];
    }
    __syncthreads();

    const int qtok_m = tq_s[w * 16 + m];   // this lane's q column token

    bf16x8 qh[4], ql[4];
    f32x4 e4[4];
    f32x4 acc_o[8];
    #pragma unroll
    for (int dt = 0; dt < 8; ++dt) acc_o[dt] = (f32x4){0.f, 0.f, 0.f, 0.f};
    float densum = 0.0f;

    float4 kreg[8];
    float4 va[4], vb[4];

    auto issue_k = [&](const int* __restrict__ toks) {
        #pragma unroll
        for (int u = 0; u < 8; ++u) {
            int token = u * 8 + (tid >> 5);
            int cc = tid & 31;
            kreg[u] = *(const float4*)(qk + (bS + toks[token]) * D_ + cc * 4);
        }
    };
    auto write_k = [&]() {
        #pragma unroll
        for (int u = 0; u < 8; ++u) {
            int token = u * 8 + (tid >> 5);
            int cc = tid & 31;
            float4 vv = kreg[u];
            unsigned h0 = hi_pack(vv.x, vv.y), h1 = hi_pack(vv.z, vv.w);
            unsigned l0 = hi_pack(vv.x - truncbf(vv.x), vv.y - truncbf(vv.y));
            unsigned l1 = hi_pack(vv.z - truncbf(vv.z), vv.w - truncbf(vv.w));
            int kw = token * 128 + ((((cc >> 1) ^ (token & 7)) << 3) | ((cc & 1) << 2));
            *(int2*)&kbuf[kw] = make_int2((int)h0, (int)h1);
            *(int2*)&kbuf[8192 + kw] = make_int2((int)l0, (int)l1);
        }
    };
    auto issue_v = [&](const int* __restrict__ toks) {
        #pragma unroll
        for (int up = 0; up < 4; ++up) {
            int kq8 = w * 16 + (up & 1) * 8;
            int cc = (up >> 1) * 16 + m;
            va[up] = *(const float4*)(vglob + (bS + toks[kq8 + g]) * D_ + cc * 4);
            vb[up] = *(const float4*)(vglob + (bS + toks[kq8 + 4 + g]) * D_ + cc * 4);
        }
    };
    auto write_v = [&]() {
        #pragma unroll
        for (int up = 0; up < 4; ++up) {
            int kq8 = w * 16 + (up & 1) * 8;
            int cc = (up >> 1) * 16 + m;
            float wa[4], wb[4];
            transpose4(va[up], g, wa);          // wa[i] = (token kq8+i, dim cc*4+g)
            transpose4(vb[up], g, wb);
            unsigned h0 = hi_pack(wa[0], wa[1]), h1 = hi_pack(wa[2], wa[3]);
            unsigned h2 = hi_pack(wb[0], wb[1]), h3 = hi_pack(wb[2], wb[3]);
            unsigned l0 = hi_pack(wa[0] - truncbf(wa[0]), wa[1] - truncbf(wa[1]));
            unsigned l1 = hi_pack(wa[2] - truncbf(wa[2]), wa[3] - truncbf(wa[3]));
            unsigned l2 = hi_pack(wb[0] - truncbf(wb[0]), wb[1] - truncbf(wb[1]));
            unsigned l3 = hi_pack(wb[2] - truncbf(wb[2]), wb[3] - truncbf(wb[3]));
            int d = cc * 4 + g;
            int ds = d ^ ((d >> 3) & 7);
            int kg = kq8 >> 3;
            int idx = (kg * 128 + ds) * 8;
            *(int4*)&vbuf[idx] = make_int4((int)h0, (int)h1, (int)h2, (int)h3);
            *(int4*)&vbuf[8192 + idx] = make_int4((int)l0, (int)l1, (int)l2, (int)l3);
        }
    };
    // mode 0: self chunk (slot-equality mask); mode 1: look-back chunk
    // (token-id mask — handles hash-round-boundary wrap)
    auto qk_pass = [&](int mode, const float* __restrict__ rns,
                       const int* __restrict__ tkp) {
        #pragma unroll
        for (int kt = 0; kt < 4; ++kt) {
            f32x4 acc = (f32x4){0.f, 0.f, 0.f, 0.f};
            #pragma unroll
            for (int s4 = 0; s4 < 4; ++s4) {
                int kr = (kt * 16 + m) * 128 + (((s4 * 4 + g) ^ (m & 7)) << 3);
                bf16x8 ah = *(const bf16x8*)&kbuf[kr];
                bf16x8 al = *(const bf16x8*)&kbuf[8192 + kr];
                acc = __builtin_amdgcn_mfma_f32_16x16x32_bf16(ah, qh[s4], acc, 0, 0, 0);
                acc = __builtin_amdgcn_mfma_f32_16x16x32_bf16(ah, ql[s4], acc, 0, 0, 0);
                acc = __builtin_amdgcn_mfma_f32_16x16x32_bf16(al, qh[s4], acc, 0, 0, 0);
            }
            f32x4 rn4 = *(const f32x4*)&rns[kt * 16 + g * 4];
            int4v kt4;
            if (mode == 1) kt4 = *(const int4v*)&tkp[kt * 16 + g * 4];
            f32x4 e;
            #pragma unroll
            for (int r = 0; r < 4; ++r) {
                float ev = __expf(acc[r] * rn4[r]);
                if (mode == 0) {
                    if (kt == w && (g * 4 + r) == m) ev = 0.0f;
                } else {
                    if (kt4[r] == qtok_m) ev = 0.0f;
                }
                e[r] = ev;
                densum += ev;
            }
            e4[kt] = e;
        }
    };
    auto pv_pass = [&]() {
        #pragma unroll
        for (int s = 0; s < 2; ++s) {
            float pav[8];
            #pragma unroll
            for (int c2 = 0; c2 < 2; ++c2) {
                int srcLane = ((g & 1) * 2 + c2) * 16 + m;
                #pragma unroll
                for (int r = 0; r < 4; ++r) {
                    float v0 = __shfl(e4[2 * s][r], srcLane, 64);
                    float v1 = __shfl(e4[2 * s + 1][r], srcLane, 64);
                    pav[c2 * 4 + r] = (g >> 1) ? v1 : v0;
                }
            }
            BF8U pahu, palu;
            #pragma unroll
            for (int j2 = 0; j2 < 4; ++j2) {
                float x0 = pav[2 * j2], x1 = pav[2 * j2 + 1];
                pahu.i[j2] = (int)hi_pack(x0, x1);
                palu.i[j2] = (int)hi_pack(x0 - truncbf(x0), x1 - truncbf(x1));
            }
            bf16x8 pah = pahu.b, pal = palu.b;
            #pragma unroll
            for (int dt = 0; dt < 8; ++dt) {
                int d = dt * 16 + m;
                int ds = d ^ ((d >> 3) & 7);
                int base = ((s * 4 + g) * 128 + ds) * 8;
                bf16x8 vh = *(const bf16x8*)&vbuf[base];
                bf16x8 vl = *(const bf16x8*)&vbuf[8192 + base];
                acc_o[dt] = __builtin_amdgcn_mfma_f32_16x16x32_bf16(pah, vh, acc_o[dt], 0, 0, 0);
                acc_o[dt] = __builtin_amdgcn_mfma_f32_16x16x32_bf16(pal, vh, acc_o[dt], 0, 0, 0);
                acc_o[dt] = __builtin_amdgcn_mfma_f32_16x16x32_bf16(pah, vl, acc_o[dt], 0, 0, 0);
            }
        }
    };

    // ---- P1: gather K0 (self chunk = q tokens) -> kbuf
    issue_k(tq_s);
    write_k();
    __syncthreads();

    // ---- P2: Q frags from kbuf; issue V0; QK0; write V0
    #pragma unroll
    for (int s4 = 0; s4 < 4; ++s4) {
        int qr = (w * 16 + m) * 128 + (((s4 * 4 + g) ^ (m & 7)) << 3);
        qh[s4] = *(const bf16x8*)&kbuf[qr];
        ql[s4] = *(const bf16x8*)&kbuf[8192 + qr];
    }
    issue_v(tq_s);
    qk_pass(0, rns0, tq_s);
    write_v();
    __syncthreads();

    // ---- P3: issue K1; PV0 (reads vbuf); write K1 (kbuf)
    issue_k(tk1_s);
    pv_pass();
    write_k();
    __syncthreads();

    // ---- P4: issue V1; QK1 (reads kbuf); write V1 (vbuf)
    issue_v(tk1_s);
    qk_pass(1, rns1, tk1_s);
    write_v();
    __syncthreads();

    // ---- P5: PV1 + epilogue
    pv_pass();

    densum += __shfl_xor(densum, 16, 64);
    densum += __shfl_xor(densum, 32, 64);

    if (DENSE) {
        const int h = c >> 6;
        const size_t base = (((size_t)(b * H_ + h)) << 12) + (size_t)(c & 63) * 64;
        #pragma unroll
        for (int r = 0; r < 4; ++r) {
            int row = w * 16 + g * 4 + r;
            _Float16* nrow = snum + (base + row) * D_;
            #pragma unroll
            for (int dt = 0; dt < 8; ++dt)
                __builtin_nontemporal_store((_Float16)acc_o[dt][r], nrow + dt * 16 + m);
        }
        if (g == 0) __builtin_nontemporal_store(densum, sden + base + w * 16 + m);
    } else {
        if (g == 0) atomicAdd(den + bS + qtok_m, densum);
        int4v q4tok = *(const int4v*)&tq_s[w * 16 + g * 4];
        #pragma unroll
        for (int r = 0; r < 4; ++r) {
            float* obase = outnum + ((bS + q4tok[r]) * D_);
            #pragma unroll
            for (int dt = 0; dt < 8; ++dt)
                atomicAdd(obase + dt * 16 + m, acc_o[dt][r]);
        }
    }
}

// ---------------------------------------------------------------- combine
__global__ __launch_bounds__(256) void combine_kernel(
        const _Float16* __restrict__ snum, const float* __restrict__ sden,
        const int* __restrict__ inv, float* __restrict__ out) {
    int wv = threadIdx.x >> 6, l = threadIdx.x & 63;
    int t = blockIdx.x * 4 + wv;          // 0 .. B*S-1
    int b = t >> 12, s = t & 4095;
    float s0 = 0.f, s1 = 0.f, dsum = 0.f;
    #pragma unroll
    for (int h = 0; h < H_; ++h) {
        int bh = b * H_ + h;
        int pos = inv[((size_t)bh << 12) + s];
        size_t row = ((size_t)bh << 12) + pos;
        dsum += __builtin_nontemporal_load(sden + row);
        unsigned uv = __builtin_nontemporal_load(
            (const unsigned*)(snum + row * D_ + 2 * l));
        unsigned short us0 = (unsigned short)(uv & 0xFFFFu);
        unsigned short us1 = (unsigned short)(uv >> 16);
        _Float16 h0, h1;
        __builtin_memcpy(&h0, &us0, 2);
        __builtin_memcpy(&h1, &us1, 2);
        s0 += (float)h0;
        s1 += (float)h1;
    }
    float rd = 1.0f / dsum;
    f32x2v o2 = {s0 * rd, s1 * rd};
    __builtin_nontemporal_store(o2, (f32x2v*)(out + (size_t)t * D_ + 2 * l));
}

// ---------------------------------------------------------------- divide (fallback)
__global__ __launch_bounds__(256) void div_kernel(float* __restrict__ out,
                                                  const float* __restrict__ den) {
    int i = blockIdx.x * 256 + threadIdx.x;  // float4 index
    float4 o = ((float4*)out)[i];
    float dn = den[i >> 5];
    ((float4*)out)[i] = make_float4(o.x / dn, o.y / dn, o.z / dn, o.w / dn);
}

// ---------------------------------------------------------------- launch
extern "C" void kernel_launch(void* const* d_in, const int* in_sizes, int n_in,
                              void* d_out, int out_size, void* d_ws, size_t ws_size,
                              hipStream_t stream) {
    const float* qk  = (const float*)d_in[0];
    const float* v   = (const float*)d_in[1];
    const float* rot = (const float*)d_in[2];
    float* out = (float*)d_out;

    char* ws = (char*)d_ws;
    float* rnrm    = (float*)ws;                        //   262,144 B
    int* buckets   = (int*)(ws + 262144);               // 2,097,152 B
    int* inv       = buckets;                           // aliased (safe: RAW per index)
    int* st        = (int*)(ws + 2359296);              // 2,097,152 B
    float* rnrm_s  = (float*)(ws + 4456448);            // 2,097,152 B
    float* sden    = (float*)(ws + 6553600);            // 2,097,152 B
    _Float16* snum = (_Float16*)(ws + 8650752);         // 134,217,728 B
    const size_t need = 8650752ull + 134217728ull;

    norm_kernel<<<B_ * S_ / 8, 256, 0, stream>>>(qk, rnrm);
    hash_kernel<<<B_ * (S_ / 64), 256, 0, stream>>>(qk, rot, buckets);
    sort_kernel<<<B_ * H_, 256, 0, stream>>>(buckets, st, inv, rnrm, rnrm_s);

    if (ws_size >= need) {
        attn_mfma_kernel<true><<<B_ * C_, 256, 0, stream>>>(
            qk, rnrm_s, v, st, nullptr, nullptr, snum, sden);
        combine_kernel<<<B_ * S_ / 4, 256, 0, stream>>>(snum, sden, inv, out);
    } else {
        float* den = sden;   // reuse slot
        hipMemsetAsync(out, 0, (size_t)B_ * S_ * D_ * 4, stream);
        hipMemsetAsync(den, 0, (size_t)B_ * S_ * 4, stream);
        attn_mfma_kernel<false><<<B_ * C_, 256, 0, stream>>>(
            qk, rnrm_s, v, st, out, den, nullptr, nullptr);
        div_kernel<<<B_ * S_ * D_ / 4 / 256, 256, 0, stream>>>(out, den);
    }
}

// Round 11
// 358.702 us; speedup vs baseline: 1.2340x; 1.0066x over previous
//
#include <hip/hip_runtime.h>
#include <hip/hip_bf16.h>

// LSH attention (Reformer-style), B=16, S=4096, D=128, H=8, bucket=64.
// norm -> prep_rot (precompute transposed/swizzled bf16-split W) ->
// MFMA hash (copy-staged W, f64 margin-fallback argmax) -> counting sort ->
// MFMA chunked attention (2-buffer pipeline, setprio, dense f16 nt-stores) -> combine.

#define B_ 16
#define S_ 4096
#define D_ 128
#define H_ 8
#define C_ 512          // H * n_buckets
#define SCALE_ 0.08838834764831845f   // D^-0.5

typedef __attribute__((ext_vector_type(8))) short bf16x8;
typedef __attribute__((ext_vector_type(4))) float f32x4;
typedef __attribute__((ext_vector_type(2))) float f32x2v;
typedef __attribute__((ext_vector_type(4))) int int4v;

union BF8U { int4v i; bf16x8 b; };

// pack truncated-bf16 of two floats into one u32 (x0 -> low short)
__device__ __forceinline__ unsigned hi_pack(float x0, float x1) {
    unsigned a, b;
    __builtin_memcpy(&b, &x0, 4);
    __builtin_memcpy(&a, &x1, 4);
    return __builtin_amdgcn_perm(a, b, 0x07060302u);   // [x0.b2,x0.b3,x1.b2,x1.b3]
}
__device__ __forceinline__ float truncbf(float x) {
    unsigned u; __builtin_memcpy(&u, &x, 4);
    u &= 0xFFFF0000u;
    float f; __builtin_memcpy(&f, &u, 4);
    return f;
}

// ---------------------------------------------------------------- row 1/norm
__global__ __launch_bounds__(256) void norm_kernel(const float* __restrict__ qk,
                                                   float* __restrict__ rnrm) {
    int half = threadIdx.x >> 5;
    int lane32 = threadIdx.x & 31;
    size_t row = (size_t)blockIdx.x * 8 + half;
    float4 vv = ((const float4*)(qk + row * D_))[lane32];
    float ss = vv.x * vv.x + vv.y * vv.y + vv.z * vv.z + vv.w * vv.w;
    #pragma unroll
    for (int m = 1; m < 32; m <<= 1) ss += __shfl_xor(ss, m, 64);
    if (lane32 == 0) rnrm[row] = 1.0f / fmaxf(sqrtf(ss), 1e-12f);
}

// ---------------------------------------------------------------- prep rot
// Build the transposed+swizzled trunc-bf16 hi/lo image of W once:
// rth[hp*8192 + ia*128 + swz(ft,ia) + j] = bf16hi(rot[(ft*4+j)*256 + hp*64 + ia])
__global__ __launch_bounds__(256) void prep_rot_kernel(const float* __restrict__ rot,
                                                       short* __restrict__ rth,
                                                       short* __restrict__ rtl) {
    int x = blockIdx.x * 256 + threadIdx.x;   // 0..8191
    int hp = x >> 11;
    int ia = (x >> 5) & 63;
    int ft = x & 31;
    float v0 = rot[(size_t)(ft * 4 + 0) * 256 + hp * 64 + ia];
    float v1 = rot[(size_t)(ft * 4 + 1) * 256 + hp * 64 + ia];
    float v2 = rot[(size_t)(ft * 4 + 2) * 256 + hp * 64 + ia];
    float v3 = rot[(size_t)(ft * 4 + 3) * 256 + hp * 64 + ia];
    unsigned h0 = hi_pack(v0, v1), h1 = hi_pack(v2, v3);
    unsigned l0 = hi_pack(v0 - truncbf(v0), v1 - truncbf(v1));
    unsigned l1 = hi_pack(v2 - truncbf(v2), v3 - truncbf(v3));
    int off = ia * 128 + ((((ft >> 1) ^ (ia & 7)) << 3) | ((ft & 1) << 2));
    *(int2*)&rth[hp * 8192 + off] = make_int2((int)h0, (int)h1);
    *(int2*)&rtl[hp * 8192 + off] = make_int2((int)l0, (int)l1);
}

// ---------------------------------------------------------------- MFMA hashing
// W staged by linear copy from precomputed rth/rtl (L2-resident, no VALU).
__global__ __launch_bounds__(256) void hash_kernel(const float* __restrict__ qk,
                                                   const float* __restrict__ rot,
                                                   const short* __restrict__ rth,
                                                   const short* __restrict__ rtl,
                                                   int* __restrict__ buckets) {
    __shared__ float qtile[64 * 132];          // 33792 B
    __shared__ short wts[16384];               // Wt hi [0,8192), lo [8192,16384)
    __shared__ unsigned char flags[8][64];     // fallback flags

    const int b = blockIdx.x >> 6;
    const int tile = blockIdx.x & 63;
    const int tid = threadIdx.x;
    const int w = tid >> 6, l = tid & 63, g = l >> 4, m = l & 15;

    const float* qbase = qk + ((size_t)b * S_ + (size_t)tile * 64) * D_;
    #pragma unroll
    for (int u = 0; u < 8; ++u) {
        int fi = u * 256 + tid;
        int row = fi >> 5, c = fi & 31;
        float4 vv = ((const float4*)qbase)[fi];
        *((float4*)(qtile + row * 132 + c * 4)) = vv;
    }
    if (tid < 32) ((int4*)flags)[tid] = make_int4(0, 0, 0, 0);
    __syncthreads();

    // A-frags: Q[w*16+m][s*32+g*8+j] trunc hi/lo
    bf16x8 qh[4], qlr[4];
    #pragma unroll
    for (int s = 0; s < 4; ++s) {
        const float* qp = qtile + (w * 16 + m) * 132 + s * 32 + g * 8;
        float4 xa = *(const float4*)qp;
        float4 xb = *(const float4*)(qp + 4);
        BF8U hu, lu;
        hu.i[0] = (int)hi_pack(xa.x, xa.y); hu.i[1] = (int)hi_pack(xa.z, xa.w);
        hu.i[2] = (int)hi_pack(xb.x, xb.y); hu.i[3] = (int)hi_pack(xb.z, xb.w);
        lu.i[0] = (int)hi_pack(xa.x - truncbf(xa.x), xa.y - truncbf(xa.y));
        lu.i[1] = (int)hi_pack(xa.z - truncbf(xa.z), xa.w - truncbf(xa.w));
        lu.i[2] = (int)hi_pack(xb.x - truncbf(xb.x), xb.y - truncbf(xb.y));
        lu.i[3] = (int)hi_pack(xb.z - truncbf(xb.z), xb.w - truncbf(xb.w));
        qh[s] = hu.b; qlr[s] = lu.b;
    }

    for (int hp = 0; hp < 4; ++hp) {
        __syncthreads();                       // prior hp's wts reads done
        {   // linear copy 16KB hi + 16KB lo
            const int4* sh = (const int4*)(rth + hp * 8192);
            const int4* sl = (const int4*)(rtl + hp * 8192);
            int4* dh = (int4*)wts;
            int4* dl = (int4*)(wts + 8192);
            #pragma unroll
            for (int u = 0; u < 4; ++u) {
                dh[u * 256 + tid] = sh[u * 256 + tid];
                dl[u * 256 + tid] = sl[u * 256 + tid];
            }
        }
        __syncthreads();

        f32x4 dots_n[4];
        #pragma unroll
        for (int nt = 0; nt < 4; ++nt) {
            f32x4 acc = (f32x4){0.f, 0.f, 0.f, 0.f};
            #pragma unroll
            for (int s = 0; s < 4; ++s) {
                int kr = (nt * 16 + m) * 128 + (((s * 4 + g) ^ (m & 7)) << 3);
                bf16x8 bh = *(const bf16x8*)&wts[kr];
                bf16x8 bl = *(const bf16x8*)&wts[8192 + kr];
                acc = __builtin_amdgcn_mfma_f32_16x16x32_bf16(qh[s], bh, acc, 0, 0, 0);
                acc = __builtin_amdgcn_mfma_f32_16x16x32_bf16(qh[s], bl, acc, 0, 0, 0);
                acc = __builtin_amdgcn_mfma_f32_16x16x32_bf16(qlr[s], bh, acc, 0, 0, 0);
            }
            dots_n[nt] = acc;
        }

        #pragma unroll
        for (int hh = 0; hh < 2; ++hh) {
            int h = hp * 2 + hh;
            #pragma unroll
            for (int r = 0; r < 4; ++r) {
                float v1 = -1e30f, v2 = -1e30f; int i1 = 0;
                #pragma unroll
                for (int nn = 0; nn < 2; ++nn) {
                    float v = dots_n[hh * 2 + nn][r];
                    int i = nn * 16 + m;
                    if (v > v1 || (v == v1 && i < i1)) { v2 = v1; v1 = v; i1 = i; }
                    else v2 = fmaxf(v2, v);
                    float nv = -v; int ni = i + 32;
                    if (nv > v1 || (nv == v1 && ni < i1)) { v2 = v1; v1 = nv; i1 = ni; }
                    else v2 = fmaxf(v2, nv);
                }
                #pragma unroll
                for (int mask = 1; mask <= 8; mask <<= 1) {
                    float ov1 = __shfl_xor(v1, mask, 64);
                    int   oi1 = __shfl_xor(i1, mask, 64);
                    float ov2 = __shfl_xor(v2, mask, 64);
                    bool takeOther = (ov1 > v1) || (ov1 == v1 && oi1 < i1);
                    float loser = takeOther ? v1 : ov1;
                    float nv1 = takeOther ? ov1 : v1;
                    int   ni1 = takeOther ? oi1 : i1;
                    v2 = fmaxf(fmaxf(v2, ov2), loser);
                    v1 = nv1; i1 = ni1;
                }
                if (m == 0) {
                    int tok = w * 16 + g * 4 + r;
                    if (v1 - v2 < 2e-2f) flags[h][tok] = 1;
                    buckets[(((size_t)(b * H_ + h)) << 12) + tile * 64 + tok] = i1;
                }
            }
        }
    }
    __syncthreads();

    // exact f64 fallback for small-margin (tok,h) (rare)
    int tok = tid >> 2, part = tid & 3;
    for (int h = 0; h < H_; ++h) {
        if (!flags[h][tok]) continue;
        double pd[8] = {0, 0, 0, 0, 0, 0, 0, 0};
        #pragma unroll 2
        for (int f = 0; f < 128; ++f) {
            double q = (double)qtile[tok * 132 + f];
            const float* rp = rot + (size_t)f * 256 + h * 32 + part * 8;
            float4 r0 = *(const float4*)rp;
            float4 r1 = *(const float4*)(rp + 4);
            pd[0] = fma(q, (double)r0.x, pd[0]);
            pd[1] = fma(q, (double)r0.y, pd[1]);
            pd[2] = fma(q, (double)r0.z, pd[2]);
            pd[3] = fma(q, (double)r0.w, pd[3]);
            pd[4] = fma(q, (double)r1.x, pd[4]);
            pd[5] = fma(q, (double)r1.y, pd[5]);
            pd[6] = fma(q, (double)r1.z, pd[6]);
            pd[7] = fma(q, (double)r1.w, pd[7]);
        }
        double bv = -1e300; int bi = 0;
        #pragma unroll
        for (int ii = 0; ii < 8; ++ii) {
            int i = part * 8 + ii;
            double v = pd[ii];
            if (v > bv || (v == bv && i < bi)) { bv = v; bi = i; }
            double nv = -v; int ni = i + 32;
            if (nv > bv || (nv == bv && ni < bi)) { bv = nv; bi = ni; }
        }
        #pragma unroll
        for (int mm = 1; mm <= 2; mm <<= 1) {
            double ov = __shfl_xor(bv, mm, 64);
            int oi = __shfl_xor(bi, mm, 64);
            if (ov > bv || (ov == bv && oi < bi)) { bv = ov; bi = oi; }
        }
        if (part == 0) buckets[(((size_t)(b * H_ + h)) << 12) + tile * 64 + tok] = bi;
    }
}

// ---------------------------------------------------------------- stable counting sort
__global__ __launch_bounds__(256) void sort_kernel(const int* __restrict__ buckets,
                                                   int* __restrict__ st,
                                                   int* __restrict__ inv,
                                                   const float* __restrict__ rnrm,
                                                   float* __restrict__ rnrm_s) {
    __shared__ unsigned short hist[256][64];
    __shared__ int base[64];
    __shared__ int totals[64];
    int tid = threadIdx.x;
    const int* bkrow = buckets + (size_t)blockIdx.x * S_;
    const float* rnb = rnrm + (size_t)(blockIdx.x >> 3) * S_;

    unsigned int* h32 = (unsigned int*)hist;
    #pragma unroll
    for (int u = 0; u < 32; ++u) h32[u * 256 + tid] = 0;
    __syncthreads();

    #pragma unroll
    for (int u = 0; u < 16; ++u) {
        int t = tid * 16 + u;
        int bk = bkrow[t];
        hist[tid][bk]++;
    }
    __syncthreads();

    if (tid < 64) {
        int bucket = tid;
        int run = 0;
        for (int ch = 0; ch < 256; ++ch) {
            int v = hist[ch][bucket];
            hist[ch][bucket] = (unsigned short)run;
            run += v;
        }
        totals[bucket] = run;
    }
    __syncthreads();
    if (tid == 0) {
        int acc = 0;
        for (int k = 0; k < 64; ++k) { base[k] = acc; acc += totals[k]; }
    }
    __syncthreads();

    int* strow = st + (size_t)blockIdx.x * S_;
    int* invrow = inv + (size_t)blockIdx.x * S_;
    float* rnsrow = rnrm_s + (size_t)blockIdx.x * S_;
    #pragma unroll
    for (int u = 0; u < 16; ++u) {
        int t = tid * 16 + u;
        int bk = bkrow[t];
        int off = hist[tid][bk];
        hist[tid][bk] = (unsigned short)(off + 1);
        int pos = base[bk] + off;
        strow[pos] = t;
        invrow[t] = pos;
        rnsrow[pos] = rnb[t] * SCALE_;
    }
}

// ---------------------------------------------------------------- in-reg 4x4 transpose
__device__ __forceinline__ void transpose4(const float4 v, int g, float (&w_)[4]) {
    bool b0 = (g & 1) != 0, b1 = (g & 2) != 0;
    float k0 = b1 ? v.z : v.x;
    float k1 = b1 ? v.w : v.y;
    float s0 = b1 ? v.x : v.z;
    float s1 = b1 ? v.y : v.w;
    float r0 = __shfl_xor(s0, 32, 64);
    float r1 = __shfl_xor(s1, 32, 64);
    float kq_ = b0 ? k1 : k0;
    float rq_ = b0 ? r1 : r0;
    float sk  = b0 ? k0 : k1;
    float sr  = b0 ? r0 : r1;
    float tk_ = __shfl_xor(sk, 16, 64);
    float tr_ = __shfl_xor(sr, 16, 64);
    float A0 = b0 ? tk_ : kq_;
    float A1 = b0 ? kq_ : tk_;
    float B0 = b0 ? tr_ : rq_;
    float B1 = b0 ? rq_ : tr_;
    w_[0] = b1 ? B0 : A0;
    w_[1] = b1 ? B1 : A1;
    w_[2] = b1 ? A0 : B0;
    w_[3] = b1 ? A1 : B1;
}

// ---------------------------------------------------------------- MFMA attention
// One block per (b, chunk c): 64 q vs 128 k (chunks c, c-1 mod 512).
// Two LDS buffers (K 32KB, V 32KB); each phase: issue next gather -> MFMA pass
// (hides latency) -> convert+write. setprio(1) around MFMA clusters (T5).
template<bool DENSE>
__global__ __launch_bounds__(256, 2) void attn_mfma_kernel(
        const float* __restrict__ qk, const float* __restrict__ rnrm_s,
        const float* __restrict__ vglob, const int* __restrict__ st,
        float* __restrict__ outnum, float* __restrict__ den,
        _Float16* __restrict__ snum, float* __restrict__ sden) {
    __shared__ int tq_s[64];
    __shared__ int tk1_s[64];
    __shared__ float rns0[64];
    __shared__ float rns1[64];
    __shared__ short kbuf[16384];   // K: hi [0,8192), lo [8192,16384)
    __shared__ short vbuf[16384];   // V^T: hi, lo

    // XCD swizzle: logical L = (p%8)*1024 + p/8 -> each batch on one XCD.
    const int p = blockIdx.x;
    const int bc = (p & 7) * 1024 + (p >> 3);
    const int b  = bc >> 9;
    const int c  = bc & 511;
    const int tid = threadIdx.x;
    const int w   = tid >> 6;   // wave 0..3
    const int l   = tid & 63;
    const int g   = l >> 4;     // quad 0..3
    const int m   = l & 15;
    const size_t bS = ((size_t)b << 12);
    const int* stb = st + ((size_t)b << 15);

    const int c1 = (c + 511) & 511;
    if (tid < 64) {
        tq_s[tid]  = stb[c * 64 + tid];
        tk1_s[tid] = stb[c1 * 64 + tid];
        rns0[tid] = rnrm_s[(((size_t)(b * H_ + (c >> 6))) << 12) + (size_t)(c & 63) * 64 + tid];
        rns1[tid] = rnrm_s[(((size_t)(b * H_ + (c1 >> 6))) << 12) + (size_t)(c1 & 63) * 64 + tid];
    }
    __syncthreads();

    const int qtok_m = tq_s[w * 16 + m];   // this lane's q column token

    bf16x8 qh[4], ql[4];
    f32x4 e4[4];
    f32x4 acc_o[8];
    #pragma unroll
    for (int dt = 0; dt < 8; ++dt) acc_o[dt] = (f32x4){0.f, 0.f, 0.f, 0.f};
    float densum = 0.0f;

    float4 kreg[8];
    float4 va[4], vb[4];

    auto issue_k = [&](const int* __restrict__ toks) {
        #pragma unroll
        for (int u = 0; u < 8; ++u) {
            int token = u * 8 + (tid >> 5);
            int cc = tid & 31;
            kreg[u] = *(const float4*)(qk + (bS + toks[token]) * D_ + cc * 4);
        }
    };
    auto write_k = [&]() {
        #pragma unroll
        for (int u = 0; u < 8; ++u) {
            int token = u * 8 + (tid >> 5);
            int cc = tid & 31;
            float4 vv = kreg[u];
            unsigned h0 = hi_pack(vv.x, vv.y), h1 = hi_pack(vv.z, vv.w);
            unsigned l0 = hi_pack(vv.x - truncbf(vv.x), vv.y - truncbf(vv.y));
            unsigned l1 = hi_pack(vv.z - truncbf(vv.z), vv.w - truncbf(vv.w));
            int kw = token * 128 + ((((cc >> 1) ^ (token & 7)) << 3) | ((cc & 1) << 2));
            *(int2*)&kbuf[kw] = make_int2((int)h0, (int)h1);
            *(int2*)&kbuf[8192 + kw] = make_int2((int)l0, (int)l1);
        }
    };
    auto issue_v = [&](const int* __restrict__ toks) {
        #pragma unroll
        for (int up = 0; up < 4; ++up) {
            int kq8 = w * 16 + (up & 1) * 8;
            int cc = (up >> 1) * 16 + m;
            va[up] = *(const float4*)(vglob + (bS + toks[kq8 + g]) * D_ + cc * 4);
            vb[up] = *(const float4*)(vglob + (bS + toks[kq8 + 4 + g]) * D_ + cc * 4);
        }
    };
    auto write_v = [&]() {
        #pragma unroll
        for (int up = 0; up < 4; ++up) {
            int kq8 = w * 16 + (up & 1) * 8;
            int cc = (up >> 1) * 16 + m;
            float wa[4], wb[4];
            transpose4(va[up], g, wa);          // wa[i] = (token kq8+i, dim cc*4+g)
            transpose4(vb[up], g, wb);
            unsigned h0 = hi_pack(wa[0], wa[1]), h1 = hi_pack(wa[2], wa[3]);
            unsigned h2 = hi_pack(wb[0], wb[1]), h3 = hi_pack(wb[2], wb[3]);
            unsigned l0 = hi_pack(wa[0] - truncbf(wa[0]), wa[1] - truncbf(wa[1]));
            unsigned l1 = hi_pack(wa[2] - truncbf(wa[2]), wa[3] - truncbf(wa[3]));
            unsigned l2 = hi_pack(wb[0] - truncbf(wb[0]), wb[1] - truncbf(wb[1]));
            unsigned l3 = hi_pack(wb[2] - truncbf(wb[2]), wb[3] - truncbf(wb[3]));
            int d = cc * 4 + g;
            int ds = d ^ ((d >> 3) & 7);
            int kg = kq8 >> 3;
            int idx = (kg * 128 + ds) * 8;
            *(int4*)&vbuf[idx] = make_int4((int)h0, (int)h1, (int)h2, (int)h3);
            *(int4*)&vbuf[8192 + idx] = make_int4((int)l0, (int)l1, (int)l2, (int)l3);
        }
    };
    auto qk_pass = [&](int mode, const float* __restrict__ rns,
                       const int* __restrict__ tkp) {
        #pragma unroll
        for (int kt = 0; kt < 4; ++kt) {
            f32x4 acc = (f32x4){0.f, 0.f, 0.f, 0.f};
            __builtin_amdgcn_s_setprio(1);
            #pragma unroll
            for (int s4 = 0; s4 < 4; ++s4) {
                int kr = (kt * 16 + m) * 128 + (((s4 * 4 + g) ^ (m & 7)) << 3);
                bf16x8 ah = *(const bf16x8*)&kbuf[kr];
                bf16x8 al = *(const bf16x8*)&kbuf[8192 + kr];
                acc = __builtin_amdgcn_mfma_f32_16x16x32_bf16(ah, qh[s4], acc, 0, 0, 0);
                acc = __builtin_amdgcn_mfma_f32_16x16x32_bf16(ah, ql[s4], acc, 0, 0, 0);
                acc = __builtin_amdgcn_mfma_f32_16x16x32_bf16(al, qh[s4], acc, 0, 0, 0);
            }
            __builtin_amdgcn_s_setprio(0);
            f32x4 rn4 = *(const f32x4*)&rns[kt * 16 + g * 4];
            int4v kt4;
            if (mode == 1) kt4 = *(const int4v*)&tkp[kt * 16 + g * 4];
            f32x4 e;
            #pragma unroll
            for (int r = 0; r < 4; ++r) {
                float ev = __expf(acc[r] * rn4[r]);
                if (mode == 0) {
                    if (kt == w && (g * 4 + r) == m) ev = 0.0f;
                } else {
                    if (kt4[r] == qtok_m) ev = 0.0f;
                }
                e[r] = ev;
                densum += ev;
            }
            e4[kt] = e;
        }
    };
    auto pv_pass = [&]() {
        #pragma unroll
        for (int s = 0; s < 2; ++s) {
            float pav[8];
            #pragma unroll
            for (int c2 = 0; c2 < 2; ++c2) {
                int srcLane = ((g & 1) * 2 + c2) * 16 + m;
                #pragma unroll
                for (int r = 0; r < 4; ++r) {
                    float v0 = __shfl(e4[2 * s][r], srcLane, 64);
                    float v1 = __shfl(e4[2 * s + 1][r], srcLane, 64);
                    pav[c2 * 4 + r] = (g >> 1) ? v1 : v0;
                }
            }
            BF8U pahu, palu;
            #pragma unroll
            for (int j2 = 0; j2 < 4; ++j2) {
                float x0 = pav[2 * j2], x1 = pav[2 * j2 + 1];
                pahu.i[j2] = (int)hi_pack(x0, x1);
                palu.i[j2] = (int)hi_pack(x0 - truncbf(x0), x1 - truncbf(x1));
            }
            bf16x8 pah = pahu.b, pal = palu.b;
            __builtin_amdgcn_s_setprio(1);
            #pragma unroll
            for (int dt = 0; dt < 8; ++dt) {
                int d = dt * 16 + m;
                int ds = d ^ ((d >> 3) & 7);
                int base = ((s * 4 + g) * 128 + ds) * 8;
                bf16x8 vh = *(const bf16x8*)&vbuf[base];
                bf16x8 vl = *(const bf16x8*)&vbuf[8192 + base];
                acc_o[dt] = __builtin_amdgcn_mfma_f32_16x16x32_bf16(pah, vh, acc_o[dt], 0, 0, 0);
                acc_o[dt] = __builtin_amdgcn_mfma_f32_16x16x32_bf16(pal, vh, acc_o[dt], 0, 0, 0);
                acc_o[dt] = __builtin_amdgcn_mfma_f32_16x16x32_bf16(pah, vl, acc_o[dt], 0, 0, 0);
            }
            __builtin_amdgcn_s_setprio(0);
        }
    };

    // ---- P1: gather K0 (self chunk = q tokens) -> kbuf
    issue_k(tq_s);
    write_k();
    __syncthreads();

    // ---- P2: Q frags from kbuf; issue V0; QK0; write V0
    #pragma unroll
    for (int s4 = 0; s4 < 4; ++s4) {
        int qr = (w * 16 + m) * 128 + (((s4 * 4 + g) ^ (m & 7)) << 3);
        qh[s4] = *(const bf16x8*)&kbuf[qr];
        ql[s4] = *(const bf16x8*)&kbuf[8192 + qr];
    }
    issue_v(tq_s);
    qk_pass(0, rns0, tq_s);
    write_v();
    __syncthreads();

    // ---- P3: issue K1; PV0 (reads vbuf); write K1 (kbuf)
    issue_k(tk1_s);
    pv_pass();
    write_k();
    __syncthreads();

    // ---- P4: issue V1; QK1 (reads kbuf); write V1 (vbuf)
    issue_v(tk1_s);
    qk_pass(1, rns1, tk1_s);
    write_v();
    __syncthreads();

    // ---- P5: PV1 + epilogue
    pv_pass();

    densum += __shfl_xor(densum, 16, 64);
    densum += __shfl_xor(densum, 32, 64);

    if (DENSE) {
        const int h = c >> 6;
        const size_t base = (((size_t)(b * H_ + h)) << 12) + (size_t)(c & 63) * 64;
        #pragma unroll
        for (int r = 0; r < 4; ++r) {
            int row = w * 16 + g * 4 + r;
            _Float16* nrow = snum + (base + row) * D_;
            #pragma unroll
            for (int dt = 0; dt < 8; ++dt)
                __builtin_nontemporal_store((_Float16)acc_o[dt][r], nrow + dt * 16 + m);
        }
        if (g == 0) __builtin_nontemporal_store(densum, sden + base + w * 16 + m);
    } else {
        if (g == 0) atomicAdd(den + bS + qtok_m, densum);
        int4v q4tok = *(const int4v*)&tq_s[w * 16 + g * 4];
        #pragma unroll
        for (int r = 0; r < 4; ++r) {
            float* obase = outnum + ((bS + q4tok[r]) * D_);
            #pragma unroll
            for (int dt = 0; dt < 8; ++dt)
                atomicAdd(obase + dt * 16 + m, acc_o[dt][r]);
        }
    }
}

// ---------------------------------------------------------------- combine
__global__ __launch_bounds__(256) void combine_kernel(
        const _Float16* __restrict__ snum, const float* __restrict__ sden,
        const int* __restrict__ inv, float* __restrict__ out) {
    int wv = threadIdx.x >> 6, l = threadIdx.x & 63;
    int t = blockIdx.x * 4 + wv;          // 0 .. B*S-1
    int b = t >> 12, s = t & 4095;
    float s0 = 0.f, s1 = 0.f, dsum = 0.f;
    #pragma unroll
    for (int h = 0; h < H_; ++h) {
        int bh = b * H_ + h;
        int pos = inv[((size_t)bh << 12) + s];
        size_t row = ((size_t)bh << 12) + pos;
        dsum += __builtin_nontemporal_load(sden + row);
        unsigned uv = __builtin_nontemporal_load(
            (const unsigned*)(snum + row * D_ + 2 * l));
        unsigned short us0 = (unsigned short)(uv & 0xFFFFu);
        unsigned short us1 = (unsigned short)(uv >> 16);
        _Float16 h0, h1;
        __builtin_memcpy(&h0, &us0, 2);
        __builtin_memcpy(&h1, &us1, 2);
        s0 += (float)h0;
        s1 += (float)h1;
    }
    float rd = 1.0f / dsum;
    f32x2v o2 = {s0 * rd, s1 * rd};
    __builtin_nontemporal_store(o2, (f32x2v*)(out + (size_t)t * D_ + 2 * l));
}

// ---------------------------------------------------------------- divide (fallback)
__global__ __launch_bounds__(256) void div_kernel(float* __restrict__ out,
                                                  const float* __restrict__ den) {
    int i = blockIdx.x * 256 + threadIdx.x;  // float4 index
    float4 o = ((float4*)out)[i];
    float dn = den[i >> 5];
    ((float4*)out)[i] = make_float4(o.x / dn, o.y / dn, o.z / dn, o.w / dn);
}

// ---------------------------------------------------------------- launch
extern "C" void kernel_launch(void* const* d_in, const int* in_sizes, int n_in,
                              void* d_out, int out_size, void* d_ws, size_t ws_size,
                              hipStream_t stream) {
    const float* qk  = (const float*)d_in[0];
    const float* v   = (const float*)d_in[1];
    const float* rot = (const float*)d_in[2];
    float* out = (float*)d_out;

    char* ws = (char*)d_ws;
    float* rnrm    = (float*)ws;                        //   262,144 B
    int* buckets   = (int*)(ws + 262144);               // 2,097,152 B
    int* inv       = buckets;                           // aliased (safe: RAW per index)
    int* st        = (int*)(ws + 2359296);              // 2,097,152 B
    float* rnrm_s  = (float*)(ws + 4456448);            // 2,097,152 B
    float* sden    = (float*)(ws + 6553600);            // 2,097,152 B
    short* rth     = (short*)(ws + 8650752);            //    65,536 B
    short* rtl     = (short*)(ws + 8716288);            //    65,536 B
    _Float16* snum = (_Float16*)(ws + 8781824);         // 134,217,728 B
    const size_t need = 8781824ull + 134217728ull;

    norm_kernel<<<B_ * S_ / 8, 256, 0, stream>>>(qk, rnrm);
    prep_rot_kernel<<<32, 256, 0, stream>>>(rot, rth, rtl);
    hash_kernel<<<B_ * (S_ / 64), 256, 0, stream>>>(qk, rot, rth, rtl, buckets);
    sort_kernel<<<B_ * H_, 256, 0, stream>>>(buckets, st, inv, rnrm, rnrm_s);

    if (ws_size >= need) {
        attn_mfma_kernel<true><<<B_ * C_, 256, 0, stream>>>(
            qk, rnrm_s, v, st, nullptr, nullptr, snum, sden);
        combine_kernel<<<B_ * S_ / 4, 256, 0, stream>>>(snum, sden, inv, out);
    } else {
        float* den = sden;   // reuse slot
        hipMemsetAsync(out, 0, (size_t)B_ * S_ * D_ * 4, stream);
        hipMemsetAsync(den, 0, (size_t)B_ * S_ * 4, stream);
        attn_mfma_kernel<false><<<B_ * C_, 256, 0, stream>>>(
            qk, rnrm_s, v, st, out, den, nullptr, nullptr);
        div_kernel<<<B_ * S_ * D_ / 4 / 256, 256, 0, stream>>>(out, den);
    }
}

// Round 12
// 289.633 us; speedup vs baseline: 1.5282x; 1.2385x over previous
//
#include <hip/hip_runtime.h>
#include <hip/hip_bf16.h>

// LSH attention (Reformer-style), B=16, S=4096, D=128, H=8, bucket=64.
// norm -> prep_rot -> MFMA hash (bf16 3-term + f64 margin-fallback argmax) ->
// counting sort -> MFMA chunked attention (single-term f16 MFMA, 2-buffer
// pipeline, dense f16 nt-stores) -> combine.

#define B_ 16
#define S_ 4096
#define D_ 128
#define H_ 8
#define C_ 512          // H * n_buckets
#define SCALE_ 0.08838834764831845f   // D^-0.5

typedef __attribute__((ext_vector_type(8))) short bf16x8;
typedef __attribute__((ext_vector_type(8))) _Float16 f16x8;
typedef __attribute__((ext_vector_type(2))) _Float16 f16x2t;
typedef __attribute__((ext_vector_type(4))) float f32x4;
typedef __attribute__((ext_vector_type(2))) float f32x2v;
typedef __attribute__((ext_vector_type(4))) int int4v;

union BF8U { int4v i; bf16x8 b; };
union F16x8U { int4v i; f16x8 h; };

// pack truncated-bf16 of two floats into one u32 (x0 -> low short)
__device__ __forceinline__ unsigned hi_pack(float x0, float x1) {
    unsigned a, b;
    __builtin_memcpy(&b, &x0, 4);
    __builtin_memcpy(&a, &x1, 4);
    return __builtin_amdgcn_perm(a, b, 0x07060302u);   // [x0.b2,x0.b3,x1.b2,x1.b3]
}
__device__ __forceinline__ float truncbf(float x) {
    unsigned u; __builtin_memcpy(&u, &x, 4);
    u &= 0xFFFF0000u;
    float f; __builtin_memcpy(&f, &u, 4);
    return f;
}
// pack two floats as f16 (RNE) into one u32
__device__ __forceinline__ unsigned pack2f16(float x0, float x1) {
    f16x2t h = {(_Float16)x0, (_Float16)x1};
    unsigned u; __builtin_memcpy(&u, &h, 4);
    return u;
}

// ---------------------------------------------------------------- row 1/norm
__global__ __launch_bounds__(256) void norm_kernel(const float* __restrict__ qk,
                                                   float* __restrict__ rnrm) {
    int half = threadIdx.x >> 5;
    int lane32 = threadIdx.x & 31;
    size_t row = (size_t)blockIdx.x * 8 + half;
    float4 vv = ((const float4*)(qk + row * D_))[lane32];
    float ss = vv.x * vv.x + vv.y * vv.y + vv.z * vv.z + vv.w * vv.w;
    #pragma unroll
    for (int m = 1; m < 32; m <<= 1) ss += __shfl_xor(ss, m, 64);
    if (lane32 == 0) rnrm[row] = 1.0f / fmaxf(sqrtf(ss), 1e-12f);
}

// ---------------------------------------------------------------- prep rot
__global__ __launch_bounds__(256) void prep_rot_kernel(const float* __restrict__ rot,
                                                       short* __restrict__ rth,
                                                       short* __restrict__ rtl) {
    int x = blockIdx.x * 256 + threadIdx.x;   // 0..8191
    int hp = x >> 11;
    int ia = (x >> 5) & 63;
    int ft = x & 31;
    float v0 = rot[(size_t)(ft * 4 + 0) * 256 + hp * 64 + ia];
    float v1 = rot[(size_t)(ft * 4 + 1) * 256 + hp * 64 + ia];
    float v2 = rot[(size_t)(ft * 4 + 2) * 256 + hp * 64 + ia];
    float v3 = rot[(size_t)(ft * 4 + 3) * 256 + hp * 64 + ia];
    unsigned h0 = hi_pack(v0, v1), h1 = hi_pack(v2, v3);
    unsigned l0 = hi_pack(v0 - truncbf(v0), v1 - truncbf(v1));
    unsigned l1 = hi_pack(v2 - truncbf(v2), v3 - truncbf(v3));
    int off = ia * 128 + ((((ft >> 1) ^ (ia & 7)) << 3) | ((ft & 1) << 2));
    *(int2*)&rth[hp * 8192 + off] = make_int2((int)h0, (int)h1);
    *(int2*)&rtl[hp * 8192 + off] = make_int2((int)l0, (int)l1);
}

// ---------------------------------------------------------------- MFMA hashing
__global__ __launch_bounds__(256) void hash_kernel(const float* __restrict__ qk,
                                                   const float* __restrict__ rot,
                                                   const short* __restrict__ rth,
                                                   const short* __restrict__ rtl,
                                                   int* __restrict__ buckets) {
    __shared__ float qtile[64 * 132];          // 33792 B
    __shared__ short wts[16384];               // Wt hi [0,8192), lo [8192,16384)
    __shared__ unsigned char flags[8][64];     // fallback flags

    const int b = blockIdx.x >> 6;
    const int tile = blockIdx.x & 63;
    const int tid = threadIdx.x;
    const int w = tid >> 6, l = tid & 63, g = l >> 4, m = l & 15;

    const float* qbase = qk + ((size_t)b * S_ + (size_t)tile * 64) * D_;
    #pragma unroll
    for (int u = 0; u < 8; ++u) {
        int fi = u * 256 + tid;
        int row = fi >> 5, c = fi & 31;
        float4 vv = ((const float4*)qbase)[fi];
        *((float4*)(qtile + row * 132 + c * 4)) = vv;
    }
    if (tid < 32) ((int4*)flags)[tid] = make_int4(0, 0, 0, 0);
    __syncthreads();

    // A-frags: Q[w*16+m][s*32+g*8+j] trunc hi/lo
    bf16x8 qh[4], qlr[4];
    #pragma unroll
    for (int s = 0; s < 4; ++s) {
        const float* qp = qtile + (w * 16 + m) * 132 + s * 32 + g * 8;
        float4 xa = *(const float4*)qp;
        float4 xb = *(const float4*)(qp + 4);
        BF8U hu, lu;
        hu.i[0] = (int)hi_pack(xa.x, xa.y); hu.i[1] = (int)hi_pack(xa.z, xa.w);
        hu.i[2] = (int)hi_pack(xb.x, xb.y); hu.i[3] = (int)hi_pack(xb.z, xb.w);
        lu.i[0] = (int)hi_pack(xa.x - truncbf(xa.x), xa.y - truncbf(xa.y));
        lu.i[1] = (int)hi_pack(xa.z - truncbf(xa.z), xa.w - truncbf(xa.w));
        lu.i[2] = (int)hi_pack(xb.x - truncbf(xb.x), xb.y - truncbf(xb.y));
        lu.i[3] = (int)hi_pack(xb.z - truncbf(xb.z), xb.w - truncbf(xb.w));
        qh[s] = hu.b; qlr[s] = lu.b;
    }

    for (int hp = 0; hp < 4; ++hp) {
        __syncthreads();                       // prior hp's wts reads done
        {   // linear copy 16KB hi + 16KB lo
            const int4* sh = (const int4*)(rth + hp * 8192);
            const int4* sl = (const int4*)(rtl + hp * 8192);
            int4* dh = (int4*)wts;
            int4* dl = (int4*)(wts + 8192);
            #pragma unroll
            for (int u = 0; u < 4; ++u) {
                dh[u * 256 + tid] = sh[u * 256 + tid];
                dl[u * 256 + tid] = sl[u * 256 + tid];
            }
        }
        __syncthreads();

        f32x4 dots_n[4];
        #pragma unroll
        for (int nt = 0; nt < 4; ++nt) {
            f32x4 acc = (f32x4){0.f, 0.f, 0.f, 0.f};
            #pragma unroll
            for (int s = 0; s < 4; ++s) {
                int kr = (nt * 16 + m) * 128 + (((s * 4 + g) ^ (m & 7)) << 3);
                bf16x8 bh = *(const bf16x8*)&wts[kr];
                bf16x8 bl = *(const bf16x8*)&wts[8192 + kr];
                acc = __builtin_amdgcn_mfma_f32_16x16x32_bf16(qh[s], bh, acc, 0, 0, 0);
                acc = __builtin_amdgcn_mfma_f32_16x16x32_bf16(qh[s], bl, acc, 0, 0, 0);
                acc = __builtin_amdgcn_mfma_f32_16x16x32_bf16(qlr[s], bh, acc, 0, 0, 0);
            }
            dots_n[nt] = acc;
        }

        #pragma unroll
        for (int hh = 0; hh < 2; ++hh) {
            int h = hp * 2 + hh;
            #pragma unroll
            for (int r = 0; r < 4; ++r) {
                float v1 = -1e30f, v2 = -1e30f; int i1 = 0;
                #pragma unroll
                for (int nn = 0; nn < 2; ++nn) {
                    float v = dots_n[hh * 2 + nn][r];
                    int i = nn * 16 + m;
                    if (v > v1 || (v == v1 && i < i1)) { v2 = v1; v1 = v; i1 = i; }
                    else v2 = fmaxf(v2, v);
                    float nv = -v; int ni = i + 32;
                    if (nv > v1 || (nv == v1 && ni < i1)) { v2 = v1; v1 = nv; i1 = ni; }
                    else v2 = fmaxf(v2, nv);
                }
                #pragma unroll
                for (int mask = 1; mask <= 8; mask <<= 1) {
                    float ov1 = __shfl_xor(v1, mask, 64);
                    int   oi1 = __shfl_xor(i1, mask, 64);
                    float ov2 = __shfl_xor(v2, mask, 64);
                    bool takeOther = (ov1 > v1) || (ov1 == v1 && oi1 < i1);
                    float loser = takeOther ? v1 : ov1;
                    float nv1 = takeOther ? ov1 : v1;
                    int   ni1 = takeOther ? oi1 : i1;
                    v2 = fmaxf(fmaxf(v2, ov2), loser);
                    v1 = nv1; i1 = ni1;
                }
                if (m == 0) {
                    int tok = w * 16 + g * 4 + r;
                    if (v1 - v2 < 2e-2f) flags[h][tok] = 1;
                    buckets[(((size_t)(b * H_ + h)) << 12) + tile * 64 + tok] = i1;
                }
            }
        }
    }
    __syncthreads();

    // exact f64 fallback for small-margin (tok,h) (rare)
    int tok = tid >> 2, part = tid & 3;
    for (int h = 0; h < H_; ++h) {
        if (!flags[h][tok]) continue;
        double pd[8] = {0, 0, 0, 0, 0, 0, 0, 0};
        #pragma unroll 2
        for (int f = 0; f < 128; ++f) {
            double q = (double)qtile[tok * 132 + f];
            const float* rp = rot + (size_t)f * 256 + h * 32 + part * 8;
            float4 r0 = *(const float4*)rp;
            float4 r1 = *(const float4*)(rp + 4);
            pd[0] = fma(q, (double)r0.x, pd[0]);
            pd[1] = fma(q, (double)r0.y, pd[1]);
            pd[2] = fma(q, (double)r0.z, pd[2]);
            pd[3] = fma(q, (double)r0.w, pd[3]);
            pd[4] = fma(q, (double)r1.x, pd[4]);
            pd[5] = fma(q, (double)r1.y, pd[5]);
            pd[6] = fma(q, (double)r1.z, pd[6]);
            pd[7] = fma(q, (double)r1.w, pd[7]);
        }
        double bv = -1e300; int bi = 0;
        #pragma unroll
        for (int ii = 0; ii < 8; ++ii) {
            int i = part * 8 + ii;
            double v = pd[ii];
            if (v > bv || (v == bv && i < bi)) { bv = v; bi = i; }
            double nv = -v; int ni = i + 32;
            if (nv > bv || (nv == bv && ni < bi)) { bv = nv; bi = ni; }
        }
        #pragma unroll
        for (int mm = 1; mm <= 2; mm <<= 1) {
            double ov = __shfl_xor(bv, mm, 64);
            int oi = __shfl_xor(bi, mm, 64);
            if (ov > bv || (ov == bv && oi < bi)) { bv = ov; bi = oi; }
        }
        if (part == 0) buckets[(((size_t)(b * H_ + h)) << 12) + tile * 64 + tok] = bi;
    }
}

// ---------------------------------------------------------------- stable counting sort
__global__ __launch_bounds__(256) void sort_kernel(const int* __restrict__ buckets,
                                                   int* __restrict__ st,
                                                   int* __restrict__ inv,
                                                   const float* __restrict__ rnrm,
                                                   float* __restrict__ rnrm_s) {
    __shared__ unsigned short hist[256][64];
    __shared__ int base[64];
    __shared__ int totals[64];
    int tid = threadIdx.x;
    const int* bkrow = buckets + (size_t)blockIdx.x * S_;
    const float* rnb = rnrm + (size_t)(blockIdx.x >> 3) * S_;

    unsigned int* h32 = (unsigned int*)hist;
    #pragma unroll
    for (int u = 0; u < 32; ++u) h32[u * 256 + tid] = 0;
    __syncthreads();

    #pragma unroll
    for (int u = 0; u < 16; ++u) {
        int t = tid * 16 + u;
        int bk = bkrow[t];
        hist[tid][bk]++;
    }
    __syncthreads();

    if (tid < 64) {
        int bucket = tid;
        int run = 0;
        for (int ch = 0; ch < 256; ++ch) {
            int v = hist[ch][bucket];
            hist[ch][bucket] = (unsigned short)run;
            run += v;
        }
        totals[bucket] = run;
    }
    __syncthreads();
    if (tid == 0) {
        int acc = 0;
        for (int k = 0; k < 64; ++k) { base[k] = acc; acc += totals[k]; }
    }
    __syncthreads();

    int* strow = st + (size_t)blockIdx.x * S_;
    int* invrow = inv + (size_t)blockIdx.x * S_;
    float* rnsrow = rnrm_s + (size_t)blockIdx.x * S_;
    #pragma unroll
    for (int u = 0; u < 16; ++u) {
        int t = tid * 16 + u;
        int bk = bkrow[t];
        int off = hist[tid][bk];
        hist[tid][bk] = (unsigned short)(off + 1);
        int pos = base[bk] + off;
        strow[pos] = t;
        invrow[t] = pos;
        rnsrow[pos] = rnb[t] * SCALE_;
    }
}

// ---------------------------------------------------------------- in-reg 4x4 transpose
__device__ __forceinline__ void transpose4(const float4 v, int g, float (&w_)[4]) {
    bool b0 = (g & 1) != 0, b1 = (g & 2) != 0;
    float k0 = b1 ? v.z : v.x;
    float k1 = b1 ? v.w : v.y;
    float s0 = b1 ? v.x : v.z;
    float s1 = b1 ? v.y : v.w;
    float r0 = __shfl_xor(s0, 32, 64);
    float r1 = __shfl_xor(s1, 32, 64);
    float kq_ = b0 ? k1 : k0;
    float rq_ = b0 ? r1 : r0;
    float sk  = b0 ? k0 : k1;
    float sr  = b0 ? r0 : r1;
    float tk_ = __shfl_xor(sk, 16, 64);
    float tr_ = __shfl_xor(sr, 16, 64);
    float A0 = b0 ? tk_ : kq_;
    float A1 = b0 ? kq_ : tk_;
    float B0 = b0 ? tr_ : rq_;
    float B1 = b0 ? rq_ : tr_;
    w_[0] = b1 ? B0 : A0;
    w_[1] = b1 ? B1 : A1;
    w_[2] = b1 ? A0 : B0;
    w_[3] = b1 ? A1 : B1;
}

// ---------------------------------------------------------------- MFMA attention
// One block per (b, chunk c): 64 q vs 128 k (chunks c, c-1 mod 512).
// Single-term f16 MFMA (error ~2^-10 random-walk, within threshold budget).
// Two LDS buffers (K 16KB, V 16KB) -> 4 blocks/CU; per phase: issue next
// gather -> MFMA pass (hides latency) -> convert+write.
template<bool DENSE>
__global__ __launch_bounds__(256, 4) void attn_mfma_kernel(
        const float* __restrict__ qk, const float* __restrict__ rnrm_s,
        const float* __restrict__ vglob, const int* __restrict__ st,
        float* __restrict__ outnum, float* __restrict__ den,
        _Float16* __restrict__ snum, float* __restrict__ sden) {
    __shared__ int tq_s[64];
    __shared__ int tk1_s[64];
    __shared__ float rns0[64];
    __shared__ float rns1[64];
    __shared__ short kbuf[8192];    // K f16, swizzled rows (16 KB)
    __shared__ short vbuf[8192];    // V^T f16, swizzled (16 KB)

    // XCD swizzle: logical L = (p%8)*1024 + p/8 -> each batch on one XCD.
    const int p = blockIdx.x;
    const int bc = (p & 7) * 1024 + (p >> 3);
    const int b  = bc >> 9;
    const int c  = bc & 511;
    const int tid = threadIdx.x;
    const int w   = tid >> 6;   // wave 0..3
    const int l   = tid & 63;
    const int g   = l >> 4;     // quad 0..3
    const int m   = l & 15;
    const size_t bS = ((size_t)b << 12);
    const int* stb = st + ((size_t)b << 15);

    const int c1 = (c + 511) & 511;
    if (tid < 64) {
        tq_s[tid]  = stb[c * 64 + tid];
        tk1_s[tid] = stb[c1 * 64 + tid];
        rns0[tid] = rnrm_s[(((size_t)(b * H_ + (c >> 6))) << 12) + (size_t)(c & 63) * 64 + tid];
        rns1[tid] = rnrm_s[(((size_t)(b * H_ + (c1 >> 6))) << 12) + (size_t)(c1 & 63) * 64 + tid];
    }
    __syncthreads();

    const int qtok_m = tq_s[w * 16 + m];   // this lane's q column token

    f16x8 qh[4];
    f32x4 e4[4];
    f32x4 acc_o[8];
    #pragma unroll
    for (int dt = 0; dt < 8; ++dt) acc_o[dt] = (f32x4){0.f, 0.f, 0.f, 0.f};
    float densum = 0.0f;

    float4 kreg[8];
    float4 va[4], vb[4];

    auto issue_k = [&](const int* __restrict__ toks) {
        #pragma unroll
        for (int u = 0; u < 8; ++u) {
            int token = u * 8 + (tid >> 5);
            int cc = tid & 31;
            kreg[u] = *(const float4*)(qk + (bS + toks[token]) * D_ + cc * 4);
        }
    };
    auto write_k = [&]() {
        #pragma unroll
        for (int u = 0; u < 8; ++u) {
            int token = u * 8 + (tid >> 5);
            int cc = tid & 31;
            float4 vv = kreg[u];
            unsigned h0 = pack2f16(vv.x, vv.y), h1 = pack2f16(vv.z, vv.w);
            int kw = token * 128 + ((((cc >> 1) ^ (token & 7)) << 3) | ((cc & 1) << 2));
            *(int2*)&kbuf[kw] = make_int2((int)h0, (int)h1);
        }
    };
    auto issue_v = [&](const int* __restrict__ toks) {
        #pragma unroll
        for (int up = 0; up < 4; ++up) {
            int kq8 = w * 16 + (up & 1) * 8;
            int cc = (up >> 1) * 16 + m;
            va[up] = *(const float4*)(vglob + (bS + toks[kq8 + g]) * D_ + cc * 4);
            vb[up] = *(const float4*)(vglob + (bS + toks[kq8 + 4 + g]) * D_ + cc * 4);
        }
    };
    auto write_v = [&]() {
        #pragma unroll
        for (int up = 0; up < 4; ++up) {
            int kq8 = w * 16 + (up & 1) * 8;
            int cc = (up >> 1) * 16 + m;
            float wa[4], wb[4];
            transpose4(va[up], g, wa);          // wa[i] = (token kq8+i, dim cc*4+g)
            transpose4(vb[up], g, wb);
            unsigned h0 = pack2f16(wa[0], wa[1]), h1 = pack2f16(wa[2], wa[3]);
            unsigned h2 = pack2f16(wb[0], wb[1]), h3 = pack2f16(wb[2], wb[3]);
            int d = cc * 4 + g;
            int ds = d ^ ((d >> 3) & 7);
            int kg = kq8 >> 3;
            int idx = (kg * 128 + ds) * 8;
            *(int4*)&vbuf[idx] = make_int4((int)h0, (int)h1, (int)h2, (int)h3);
        }
    };
    auto qk_pass = [&](int mode, const float* __restrict__ rns,
                       const int* __restrict__ tkp) {
        #pragma unroll
        for (int kt = 0; kt < 4; ++kt) {
            f32x4 acc = (f32x4){0.f, 0.f, 0.f, 0.f};
            #pragma unroll
            for (int s4 = 0; s4 < 4; ++s4) {
                int kr = (kt * 16 + m) * 128 + (((s4 * 4 + g) ^ (m & 7)) << 3);
                f16x8 ah = *(const f16x8*)&kbuf[kr];
                acc = __builtin_amdgcn_mfma_f32_16x16x32_f16(ah, qh[s4], acc, 0, 0, 0);
            }
            f32x4 rn4 = *(const f32x4*)&rns[kt * 16 + g * 4];
            int4v kt4;
            if (mode == 1) kt4 = *(const int4v*)&tkp[kt * 16 + g * 4];
            f32x4 e;
            #pragma unroll
            for (int r = 0; r < 4; ++r) {
                float ev = __expf(acc[r] * rn4[r]);
                if (mode == 0) {
                    if (kt == w && (g * 4 + r) == m) ev = 0.0f;
                } else {
                    if (kt4[r] == qtok_m) ev = 0.0f;
                }
                e[r] = ev;
                densum += ev;
            }
            e4[kt] = e;
        }
    };
    auto pv_pass = [&]() {
        #pragma unroll
        for (int s = 0; s < 2; ++s) {
            float pav[8];
            #pragma unroll
            for (int c2 = 0; c2 < 2; ++c2) {
                int srcLane = ((g & 1) * 2 + c2) * 16 + m;
                #pragma unroll
                for (int r = 0; r < 4; ++r) {
                    float v0 = __shfl(e4[2 * s][r], srcLane, 64);
                    float v1 = __shfl(e4[2 * s + 1][r], srcLane, 64);
                    pav[c2 * 4 + r] = (g >> 1) ? v1 : v0;
                }
            }
            F16x8U pahu;
            #pragma unroll
            for (int j2 = 0; j2 < 4; ++j2)
                pahu.i[j2] = (int)pack2f16(pav[2 * j2], pav[2 * j2 + 1]);
            f16x8 pah = pahu.h;
            #pragma unroll
            for (int dt = 0; dt < 8; ++dt) {
                int d = dt * 16 + m;
                int ds = d ^ ((d >> 3) & 7);
                int base = ((s * 4 + g) * 128 + ds) * 8;
                f16x8 vh = *(const f16x8*)&vbuf[base];
                acc_o[dt] = __builtin_amdgcn_mfma_f32_16x16x32_f16(pah, vh, acc_o[dt], 0, 0, 0);
            }
        }
    };

    // ---- P1: gather K0 (self chunk = q tokens) -> kbuf
    issue_k(tq_s);
    write_k();
    __syncthreads();

    // ---- P2: Q frags from kbuf; issue V0; QK0; write V0
    #pragma unroll
    for (int s4 = 0; s4 < 4; ++s4) {
        int qr = (w * 16 + m) * 128 + (((s4 * 4 + g) ^ (m & 7)) << 3);
        qh[s4] = *(const f16x8*)&kbuf[qr];
    }
    issue_v(tq_s);
    qk_pass(0, rns0, tq_s);
    write_v();
    __syncthreads();

    // ---- P3: issue K1; PV0 (reads vbuf); write K1 (kbuf)
    issue_k(tk1_s);
    pv_pass();
    write_k();
    __syncthreads();

    // ---- P4: issue V1; QK1 (reads kbuf); write V1 (vbuf)
    issue_v(tk1_s);
    qk_pass(1, rns1, tk1_s);
    write_v();
    __syncthreads();

    // ---- P5: PV1 + epilogue
    pv_pass();

    densum += __shfl_xor(densum, 16, 64);
    densum += __shfl_xor(densum, 32, 64);

    if (DENSE) {
        const int h = c >> 6;
        const size_t base = (((size_t)(b * H_ + h)) << 12) + (size_t)(c & 63) * 64;
        #pragma unroll
        for (int r = 0; r < 4; ++r) {
            int row = w * 16 + g * 4 + r;
            _Float16* nrow = snum + (base + row) * D_;
            #pragma unroll
            for (int dt = 0; dt < 8; ++dt)
                __builtin_nontemporal_store((_Float16)acc_o[dt][r], nrow + dt * 16 + m);
        }
        if (g == 0) __builtin_nontemporal_store(densum, sden + base + w * 16 + m);
    } else {
        if (g == 0) atomicAdd(den + bS + qtok_m, densum);
        int4v q4tok = *(const int4v*)&tq_s[w * 16 + g * 4];
        #pragma unroll
        for (int r = 0; r < 4; ++r) {
            float* obase = outnum + ((bS + q4tok[r]) * D_);
            #pragma unroll
            for (int dt = 0; dt < 8; ++dt)
                atomicAdd(obase + dt * 16 + m, acc_o[dt][r]);
        }
    }
}

// ---------------------------------------------------------------- combine
__global__ __launch_bounds__(256) void combine_kernel(
        const _Float16* __restrict__ snum, const float* __restrict__ sden,
        const int* __restrict__ inv, float* __restrict__ out) {
    int wv = threadIdx.x >> 6, l = threadIdx.x & 63;
    int t = blockIdx.x * 4 + wv;          // 0 .. B*S-1
    int b = t >> 12, s = t & 4095;
    float s0 = 0.f, s1 = 0.f, dsum = 0.f;
    #pragma unroll
    for (int h = 0; h < H_; ++h) {
        int bh = b * H_ + h;
        int pos = inv[((size_t)bh << 12) + s];
        size_t row = ((size_t)bh << 12) + pos;
        dsum += __builtin_nontemporal_load(sden + row);
        unsigned uv = __builtin_nontemporal_load(
            (const unsigned*)(snum + row * D_ + 2 * l));
        unsigned short us0 = (unsigned short)(uv & 0xFFFFu);
        unsigned short us1 = (unsigned short)(uv >> 16);
        _Float16 h0, h1;
        __builtin_memcpy(&h0, &us0, 2);
        __builtin_memcpy(&h1, &us1, 2);
        s0 += (float)h0;
        s1 += (float)h1;
    }
    float rd = 1.0f / dsum;
    f32x2v o2 = {s0 * rd, s1 * rd};
    __builtin_nontemporal_store(o2, (f32x2v*)(out + (size_t)t * D_ + 2 * l));
}

// ---------------------------------------------------------------- divide (fallback)
__global__ __launch_bounds__(256) void div_kernel(float* __restrict__ out,
                                                  const float* __restrict__ den) {
    int i = blockIdx.x * 256 + threadIdx.x;  // float4 index
    float4 o = ((float4*)out)[i];
    float dn = den[i >> 5];
    ((float4*)out)[i] = make_float4(o.x / dn, o.y / dn, o.z / dn, o.w / dn);
}

// ---------------------------------------------------------------- launch
extern "C" void kernel_launch(void* const* d_in, const int* in_sizes, int n_in,
                              void* d_out, int out_size, void* d_ws, size_t ws_size,
                              hipStream_t stream) {
    const float* qk  = (const float*)d_in[0];
    const float* v   = (const float*)d_in[1];
    const float* rot = (const float*)d_in[2];
    float* out = (float*)d_out;

    char* ws = (char*)d_ws;
    float* rnrm    = (float*)ws;                        //   262,144 B
    int* buckets   = (int*)(ws + 262144);               // 2,097,152 B
    int* inv       = buckets;                           // aliased (safe: RAW per index)
    int* st        = (int*)(ws + 2359296);              // 2,097,152 B
    float* rnrm_s  = (float*)(ws + 4456448);            // 2,097,152 B
    float* sden    = (float*)(ws + 6553600);            // 2,097,152 B
    short* rth     = (short*)(ws + 8650752);            //    65,536 B
    short* rtl     = (short*)(ws + 8716288);            //    65,536 B
    _Float16* snum = (_Float16*)(ws + 8781824);         // 134,217,728 B
    const size_t need = 8781824ull + 134217728ull;

    norm_kernel<<<B_ * S_ / 8, 256, 0, stream>>>(qk, rnrm);
    prep_rot_kernel<<<32, 256, 0, stream>>>(rot, rth, rtl);
    hash_kernel<<<B_ * (S_ / 64), 256, 0, stream>>>(qk, rot, rth, rtl, buckets);
    sort_kernel<<<B_ * H_, 256, 0, stream>>>(buckets, st, inv, rnrm, rnrm_s);

    if (ws_size >= need) {
        attn_mfma_kernel<true><<<B_ * C_, 256, 0, stream>>>(
            qk, rnrm_s, v, st, nullptr, nullptr, snum, sden);
        combine_kernel<<<B_ * S_ / 4, 256, 0, stream>>>(snum, sden, inv, out);
    } else {
        float* den = sden;   // reuse slot
        hipMemsetAsync(out, 0, (size_t)B_ * S_ * D_ * 4, stream);
        hipMemsetAsync(den, 0, (size_t)B_ * S_ * 4, stream);
        attn_mfma_kernel<false><<<B_ * C_, 256, 0, stream>>>(
            qk, rnrm_s, v, st, out, den, nullptr, nullptr);
        div_kernel<<<B_ * S_ * D_ / 4 / 256, 256, 0, stream>>>(out, den);
    }
}

// Round 13
// 274.365 us; speedup vs baseline: 1.6133x; 1.0556x over previous
//
#include <hip/hip_runtime.h>
#include <hip/hip_bf16.h>

// LSH attention (Reformer-style), B=16, S=4096, D=128, H=8, bucket=64.
// norm -> prep_rot -> zero-LDS MFMA hash (bf16 3-term, global W-frags,
// f64 margin-fallback argmax) -> counting sort -> MFMA chunked attention
// (single-term f16, 2-buffer pipeline, dense f16 nt-stores) -> combine.

#define B_ 16
#define S_ 4096
#define D_ 128
#define H_ 8
#define C_ 512          // H * n_buckets
#define SCALE_ 0.08838834764831845f   // D^-0.5

typedef __attribute__((ext_vector_type(8))) short bf16x8;
typedef __attribute__((ext_vector_type(8))) _Float16 f16x8;
typedef __attribute__((ext_vector_type(2))) _Float16 f16x2t;
typedef __attribute__((ext_vector_type(4))) float f32x4;
typedef __attribute__((ext_vector_type(2))) float f32x2v;
typedef __attribute__((ext_vector_type(4))) int int4v;

union BF8U { int4v i; bf16x8 b; };
union F16x8U { int4v i; f16x8 h; };

// pack truncated-bf16 of two floats into one u32 (x0 -> low short)
__device__ __forceinline__ unsigned hi_pack(float x0, float x1) {
    unsigned a, b;
    __builtin_memcpy(&b, &x0, 4);
    __builtin_memcpy(&a, &x1, 4);
    return __builtin_amdgcn_perm(a, b, 0x07060302u);   // [x0.b2,x0.b3,x1.b2,x1.b3]
}
__device__ __forceinline__ float truncbf(float x) {
    unsigned u; __builtin_memcpy(&u, &x, 4);
    u &= 0xFFFF0000u;
    float f; __builtin_memcpy(&f, &u, 4);
    return f;
}
// pack two floats as f16 (RNE) into one u32
__device__ __forceinline__ unsigned pack2f16(float x0, float x1) {
    f16x2t h = {(_Float16)x0, (_Float16)x1};
    unsigned u; __builtin_memcpy(&u, &h, 4);
    return u;
}

// ---------------------------------------------------------------- row 1/norm
__global__ __launch_bounds__(256) void norm_kernel(const float* __restrict__ qk,
                                                   float* __restrict__ rnrm) {
    int half = threadIdx.x >> 5;
    int lane32 = threadIdx.x & 31;
    size_t row = (size_t)blockIdx.x * 8 + half;
    float4 vv = ((const float4*)(qk + row * D_))[lane32];
    float ss = vv.x * vv.x + vv.y * vv.y + vv.z * vv.z + vv.w * vv.w;
    #pragma unroll
    for (int m = 1; m < 32; m <<= 1) ss += __shfl_xor(ss, m, 64);
    if (lane32 == 0) rnrm[row] = 1.0f / fmaxf(sqrtf(ss), 1e-12f);
}

// ---------------------------------------------------------------- prep rot
// rth[hp*8192 + ia*128 + swz(ft,ia)] = bf16hi of rot[(ft*4+j)*256 + hp*64 + ia]
__global__ __launch_bounds__(256) void prep_rot_kernel(const float* __restrict__ rot,
                                                       short* __restrict__ rth,
                                                       short* __restrict__ rtl) {
    int x = blockIdx.x * 256 + threadIdx.x;   // 0..8191
    int hp = x >> 11;
    int ia = (x >> 5) & 63;
    int ft = x & 31;
    float v0 = rot[(size_t)(ft * 4 + 0) * 256 + hp * 64 + ia];
    float v1 = rot[(size_t)(ft * 4 + 1) * 256 + hp * 64 + ia];
    float v2 = rot[(size_t)(ft * 4 + 2) * 256 + hp * 64 + ia];
    float v3 = rot[(size_t)(ft * 4 + 3) * 256 + hp * 64 + ia];
    unsigned h0 = hi_pack(v0, v1), h1 = hi_pack(v2, v3);
    unsigned l0 = hi_pack(v0 - truncbf(v0), v1 - truncbf(v1));
    unsigned l1 = hi_pack(v2 - truncbf(v2), v3 - truncbf(v3));
    int off = ia * 128 + ((((ft >> 1) ^ (ia & 7)) << 3) | ((ft & 1) << 2));
    *(int2*)&rth[hp * 8192 + off] = make_int2((int)h0, (int)h1);
    *(int2*)&rtl[hp * 8192 + off] = make_int2((int)l0, (int)l1);
}

// ---------------------------------------------------------------- MFMA hashing
// Zero-LDS: Q A-frags and W B-frags loaded straight from global (rth/rtl is
// 128 KB, L2-resident across all 1024 blocks). No barriers in the main loop.
__global__ __launch_bounds__(256) void hash_kernel(const float* __restrict__ qk,
                                                   const float* __restrict__ rot,
                                                   const short* __restrict__ rth,
                                                   const short* __restrict__ rtl,
                                                   int* __restrict__ buckets) {
    __shared__ unsigned char flags[8][64];     // fallback flags (512 B)

    const int b = blockIdx.x >> 6;
    const int tile = blockIdx.x & 63;
    const int tid = threadIdx.x;
    const int w = tid >> 6, l = tid & 63, g = l >> 4, m = l & 15;

    if (tid < 32) ((int4*)flags)[tid] = make_int4(0, 0, 0, 0);
    __syncthreads();

    // A-frags: Q[w*16+m][s*32+g*8+j] trunc hi/lo, straight from global
    const float* qrow = qk + ((size_t)b * S_ + (size_t)tile * 64 + w * 16 + m) * D_;
    bf16x8 qh[4], qlr[4];
    #pragma unroll
    for (int s = 0; s < 4; ++s) {
        float4 xa = *(const float4*)(qrow + s * 32 + g * 8);
        float4 xb = *(const float4*)(qrow + s * 32 + g * 8 + 4);
        BF8U hu, lu;
        hu.i[0] = (int)hi_pack(xa.x, xa.y); hu.i[1] = (int)hi_pack(xa.z, xa.w);
        hu.i[2] = (int)hi_pack(xb.x, xb.y); hu.i[3] = (int)hi_pack(xb.z, xb.w);
        lu.i[0] = (int)hi_pack(xa.x - truncbf(xa.x), xa.y - truncbf(xa.y));
        lu.i[1] = (int)hi_pack(xa.z - truncbf(xa.z), xa.w - truncbf(xa.w));
        lu.i[2] = (int)hi_pack(xb.x - truncbf(xb.x), xb.y - truncbf(xb.y));
        lu.i[3] = (int)hi_pack(xb.z - truncbf(xb.z), xb.w - truncbf(xb.w));
        qh[s] = hu.b; qlr[s] = lu.b;
    }

    #pragma unroll
    for (int hp = 0; hp < 4; ++hp) {
        // dots tiles: C[tok = w*16+g*4+r][i = nt*16+m]; B-frags from global
        f32x4 dots_n[4];
        #pragma unroll
        for (int nt = 0; nt < 4; ++nt) {
            f32x4 acc = (f32x4){0.f, 0.f, 0.f, 0.f};
            #pragma unroll
            for (int s = 0; s < 4; ++s) {
                int kr = hp * 8192 + (nt * 16 + m) * 128 + (((s * 4 + g) ^ (m & 7)) << 3);
                bf16x8 bh = *(const bf16x8*)&rth[kr];
                bf16x8 bl = *(const bf16x8*)&rtl[kr];
                acc = __builtin_amdgcn_mfma_f32_16x16x32_bf16(qh[s], bh, acc, 0, 0, 0);
                acc = __builtin_amdgcn_mfma_f32_16x16x32_bf16(qh[s], bl, acc, 0, 0, 0);
                acc = __builtin_amdgcn_mfma_f32_16x16x32_bf16(qlr[s], bh, acc, 0, 0, 0);
            }
            dots_n[nt] = acc;
        }

        // argmax per (token, h); h = hp*2 + hh
        #pragma unroll
        for (int hh = 0; hh < 2; ++hh) {
            int h = hp * 2 + hh;
            #pragma unroll
            for (int r = 0; r < 4; ++r) {
                float v1 = -1e30f, v2 = -1e30f; int i1 = 0;
                #pragma unroll
                for (int nn = 0; nn < 2; ++nn) {
                    float v = dots_n[hh * 2 + nn][r];
                    int i = nn * 16 + m;
                    if (v > v1 || (v == v1 && i < i1)) { v2 = v1; v1 = v; i1 = i; }
                    else v2 = fmaxf(v2, v);
                    float nv = -v; int ni = i + 32;
                    if (nv > v1 || (nv == v1 && ni < i1)) { v2 = v1; v1 = nv; i1 = ni; }
                    else v2 = fmaxf(v2, nv);
                }
                #pragma unroll
                for (int mask = 1; mask <= 8; mask <<= 1) {
                    float ov1 = __shfl_xor(v1, mask, 64);
                    int   oi1 = __shfl_xor(i1, mask, 64);
                    float ov2 = __shfl_xor(v2, mask, 64);
                    bool takeOther = (ov1 > v1) || (ov1 == v1 && oi1 < i1);
                    float loser = takeOther ? v1 : ov1;
                    float nv1 = takeOther ? ov1 : v1;
                    int   ni1 = takeOther ? oi1 : i1;
                    v2 = fmaxf(fmaxf(v2, ov2), loser);
                    v1 = nv1; i1 = ni1;
                }
                if (m == 0) {
                    int tok = w * 16 + g * 4 + r;
                    if (v1 - v2 < 2e-2f) flags[h][tok] = 1;
                    buckets[(((size_t)(b * H_ + h)) << 12) + tile * 64 + tok] = i1;
                }
            }
        }
    }
    __syncthreads();

    // exact f64 fallback for small-margin (tok,h) (rare); reads qk from global
    int tok = tid >> 2, part = tid & 3;
    const float* qtok = qk + ((size_t)b * S_ + (size_t)tile * 64 + tok) * D_;
    for (int h = 0; h < H_; ++h) {
        if (!flags[h][tok]) continue;
        double pd[8] = {0, 0, 0, 0, 0, 0, 0, 0};
        #pragma unroll 2
        for (int f = 0; f < 128; ++f) {
            double q = (double)qtok[f];
            const float* rp = rot + (size_t)f * 256 + h * 32 + part * 8;
            float4 r0 = *(const float4*)rp;
            float4 r1 = *(const float4*)(rp + 4);
            pd[0] = fma(q, (double)r0.x, pd[0]);
            pd[1] = fma(q, (double)r0.y, pd[1]);
            pd[2] = fma(q, (double)r0.z, pd[2]);
            pd[3] = fma(q, (double)r0.w, pd[3]);
            pd[4] = fma(q, (double)r1.x, pd[4]);
            pd[5] = fma(q, (double)r1.y, pd[5]);
            pd[6] = fma(q, (double)r1.z, pd[6]);
            pd[7] = fma(q, (double)r1.w, pd[7]);
        }
        double bv = -1e300; int bi = 0;
        #pragma unroll
        for (int ii = 0; ii < 8; ++ii) {
            int i = part * 8 + ii;
            double v = pd[ii];
            if (v > bv || (v == bv && i < bi)) { bv = v; bi = i; }
            double nv = -v; int ni = i + 32;
            if (nv > bv || (nv == bv && ni < bi)) { bv = nv; bi = ni; }
        }
        #pragma unroll
        for (int mm = 1; mm <= 2; mm <<= 1) {
            double ov = __shfl_xor(bv, mm, 64);
            int oi = __shfl_xor(bi, mm, 64);
            if (ov > bv || (ov == bv && oi < bi)) { bv = ov; bi = oi; }
        }
        if (part == 0) buckets[(((size_t)(b * H_ + h)) << 12) + tile * 64 + tok] = bi;
    }
}

// ---------------------------------------------------------------- stable counting sort
__global__ __launch_bounds__(256) void sort_kernel(const int* __restrict__ buckets,
                                                   int* __restrict__ st,
                                                   int* __restrict__ inv,
                                                   const float* __restrict__ rnrm,
                                                   float* __restrict__ rnrm_s) {
    __shared__ unsigned short hist[256][64];
    __shared__ int base[64];
    __shared__ int totals[64];
    int tid = threadIdx.x;
    const int* bkrow = buckets + (size_t)blockIdx.x * S_;
    const float* rnb = rnrm + (size_t)(blockIdx.x >> 3) * S_;

    unsigned int* h32 = (unsigned int*)hist;
    #pragma unroll
    for (int u = 0; u < 32; ++u) h32[u * 256 + tid] = 0;
    __syncthreads();

    #pragma unroll
    for (int u = 0; u < 16; ++u) {
        int t = tid * 16 + u;
        int bk = bkrow[t];
        hist[tid][bk]++;
    }
    __syncthreads();

    if (tid < 64) {
        int bucket = tid;
        int run = 0;
        for (int ch = 0; ch < 256; ++ch) {
            int v = hist[ch][bucket];
            hist[ch][bucket] = (unsigned short)run;
            run += v;
        }
        totals[bucket] = run;
    }
    __syncthreads();
    if (tid == 0) {
        int acc = 0;
        for (int k = 0; k < 64; ++k) { base[k] = acc; acc += totals[k]; }
    }
    __syncthreads();

    int* strow = st + (size_t)blockIdx.x * S_;
    int* invrow = inv + (size_t)blockIdx.x * S_;
    float* rnsrow = rnrm_s + (size_t)blockIdx.x * S_;
    #pragma unroll
    for (int u = 0; u < 16; ++u) {
        int t = tid * 16 + u;
        int bk = bkrow[t];
        int off = hist[tid][bk];
        hist[tid][bk] = (unsigned short)(off + 1);
        int pos = base[bk] + off;
        strow[pos] = t;
        invrow[t] = pos;
        rnsrow[pos] = rnb[t] * SCALE_;
    }
}

// ---------------------------------------------------------------- in-reg 4x4 transpose
__device__ __forceinline__ void transpose4(const float4 v, int g, float (&w_)[4]) {
    bool b0 = (g & 1) != 0, b1 = (g & 2) != 0;
    float k0 = b1 ? v.z : v.x;
    float k1 = b1 ? v.w : v.y;
    float s0 = b1 ? v.x : v.z;
    float s1 = b1 ? v.y : v.w;
    float r0 = __shfl_xor(s0, 32, 64);
    float r1 = __shfl_xor(s1, 32, 64);
    float kq_ = b0 ? k1 : k0;
    float rq_ = b0 ? r1 : r0;
    float sk  = b0 ? k0 : k1;
    float sr  = b0 ? r0 : r1;
    float tk_ = __shfl_xor(sk, 16, 64);
    float tr_ = __shfl_xor(sr, 16, 64);
    float A0 = b0 ? tk_ : kq_;
    float A1 = b0 ? kq_ : tk_;
    float B0 = b0 ? tr_ : rq_;
    float B1 = b0 ? rq_ : tr_;
    w_[0] = b1 ? B0 : A0;
    w_[1] = b1 ? B1 : A1;
    w_[2] = b1 ? A0 : B0;
    w_[3] = b1 ? A1 : B1;
}

// ---------------------------------------------------------------- MFMA attention
// One block per (b, chunk c): 64 q vs 128 k (chunks c, c-1 mod 512).
// Single-term f16 MFMA; two LDS buffers (K 16KB, V 16KB) -> 4 blocks/CU.
template<bool DENSE>
__global__ __launch_bounds__(256, 4) void attn_mfma_kernel(
        const float* __restrict__ qk, const float* __restrict__ rnrm_s,
        const float* __restrict__ vglob, const int* __restrict__ st,
        float* __restrict__ outnum, float* __restrict__ den,
        _Float16* __restrict__ snum, float* __restrict__ sden) {
    __shared__ int tq_s[64];
    __shared__ int tk1_s[64];
    __shared__ float rns0[64];
    __shared__ float rns1[64];
    __shared__ short kbuf[8192];    // K f16, swizzled rows (16 KB)
    __shared__ short vbuf[8192];    // V^T f16, swizzled (16 KB)

    // XCD swizzle: logical L = (p%8)*1024 + p/8 -> each batch on one XCD.
    const int p = blockIdx.x;
    const int bc = (p & 7) * 1024 + (p >> 3);
    const int b  = bc >> 9;
    const int c  = bc & 511;
    const int tid = threadIdx.x;
    const int w   = tid >> 6;   // wave 0..3
    const int l   = tid & 63;
    const int g   = l >> 4;     // quad 0..3
    const int m   = l & 15;
    const size_t bS = ((size_t)b << 12);
    const int* stb = st + ((size_t)b << 15);

    const int c1 = (c + 511) & 511;
    if (tid < 64) {
        tq_s[tid]  = stb[c * 64 + tid];
        tk1_s[tid] = stb[c1 * 64 + tid];
        rns0[tid] = rnrm_s[(((size_t)(b * H_ + (c >> 6))) << 12) + (size_t)(c & 63) * 64 + tid];
        rns1[tid] = rnrm_s[(((size_t)(b * H_ + (c1 >> 6))) << 12) + (size_t)(c1 & 63) * 64 + tid];
    }
    __syncthreads();

    const int qtok_m = tq_s[w * 16 + m];   // this lane's q column token

    f16x8 qh[4];
    f32x4 e4[4];
    f32x4 acc_o[8];
    #pragma unroll
    for (int dt = 0; dt < 8; ++dt) acc_o[dt] = (f32x4){0.f, 0.f, 0.f, 0.f};
    float densum = 0.0f;

    float4 kreg[8];
    float4 va[4], vb[4];

    auto issue_k = [&](const int* __restrict__ toks) {
        #pragma unroll
        for (int u = 0; u < 8; ++u) {
            int token = u * 8 + (tid >> 5);
            int cc = tid & 31;
            kreg[u] = *(const float4*)(qk + (bS + toks[token]) * D_ + cc * 4);
        }
    };
    auto write_k = [&]() {
        #pragma unroll
        for (int u = 0; u < 8; ++u) {
            int token = u * 8 + (tid >> 5);
            int cc = tid & 31;
            float4 vv = kreg[u];
            unsigned h0 = pack2f16(vv.x, vv.y), h1 = pack2f16(vv.z, vv.w);
            int kw = token * 128 + ((((cc >> 1) ^ (token & 7)) << 3) | ((cc & 1) << 2));
            *(int2*)&kbuf[kw] = make_int2((int)h0, (int)h1);
        }
    };
    auto issue_v = [&](const int* __restrict__ toks) {
        #pragma unroll
        for (int up = 0; up < 4; ++up) {
            int kq8 = w * 16 + (up & 1) * 8;
            int cc = (up >> 1) * 16 + m;
            va[up] = *(const float4*)(vglob + (bS + toks[kq8 + g]) * D_ + cc * 4);
            vb[up] = *(const float4*)(vglob + (bS + toks[kq8 + 4 + g]) * D_ + cc * 4);
        }
    };
    auto write_v = [&]() {
        #pragma unroll
        for (int up = 0; up < 4; ++up) {
            int kq8 = w * 16 + (up & 1) * 8;
            int cc = (up >> 1) * 16 + m;
            float wa[4], wb[4];
            transpose4(va[up], g, wa);          // wa[i] = (token kq8+i, dim cc*4+g)
            transpose4(vb[up], g, wb);
            unsigned h0 = pack2f16(wa[0], wa[1]), h1 = pack2f16(wa[2], wa[3]);
            unsigned h2 = pack2f16(wb[0], wb[1]), h3 = pack2f16(wb[2], wb[3]);
            int d = cc * 4 + g;
            int ds = d ^ ((d >> 3) & 7);
            int kg = kq8 >> 3;
            int idx = (kg * 128 + ds) * 8;
            *(int4*)&vbuf[idx] = make_int4((int)h0, (int)h1, (int)h2, (int)h3);
        }
    };
    auto qk_pass = [&](int mode, const float* __restrict__ rns,
                       const int* __restrict__ tkp) {
        #pragma unroll
        for (int kt = 0; kt < 4; ++kt) {
            f32x4 acc = (f32x4){0.f, 0.f, 0.f, 0.f};
            #pragma unroll
            for (int s4 = 0; s4 < 4; ++s4) {
                int kr = (kt * 16 + m) * 128 + (((s4 * 4 + g) ^ (m & 7)) << 3);
                f16x8 ah = *(const f16x8*)&kbuf[kr];
                acc = __builtin_amdgcn_mfma_f32_16x16x32_f16(ah, qh[s4], acc, 0, 0, 0);
            }
            f32x4 rn4 = *(const f32x4*)&rns[kt * 16 + g * 4];
            int4v kt4;
            if (mode == 1) kt4 = *(const int4v*)&tkp[kt * 16 + g * 4];
            f32x4 e;
            #pragma unroll
            for (int r = 0; r < 4; ++r) {
                float ev = __expf(acc[r] * rn4[r]);
                if (mode == 0) {
                    if (kt == w && (g * 4 + r) == m) ev = 0.0f;
                } else {
                    if (kt4[r] == qtok_m) ev = 0.0f;
                }
                e[r] = ev;
                densum += ev;
            }
            e4[kt] = e;
        }
    };
    auto pv_pass = [&]() {
        #pragma unroll
        for (int s = 0; s < 2; ++s) {
            float pav[8];
            #pragma unroll
            for (int c2 = 0; c2 < 2; ++c2) {
                int srcLane = ((g & 1) * 2 + c2) * 16 + m;
                #pragma unroll
                for (int r = 0; r < 4; ++r) {
                    float v0 = __shfl(e4[2 * s][r], srcLane, 64);
                    float v1 = __shfl(e4[2 * s + 1][r], srcLane, 64);
                    pav[c2 * 4 + r] = (g >> 1) ? v1 : v0;
                }
            }
            F16x8U pahu;
            #pragma unroll
            for (int j2 = 0; j2 < 4; ++j2)
                pahu.i[j2] = (int)pack2f16(pav[2 * j2], pav[2 * j2 + 1]);
            f16x8 pah = pahu.h;
            #pragma unroll
            for (int dt = 0; dt < 8; ++dt) {
                int d = dt * 16 + m;
                int ds = d ^ ((d >> 3) & 7);
                int base = ((s * 4 + g) * 128 + ds) * 8;
                f16x8 vh = *(const f16x8*)&vbuf[base];
                acc_o[dt] = __builtin_amdgcn_mfma_f32_16x16x32_f16(pah, vh, acc_o[dt], 0, 0, 0);
            }
        }
    };

    // ---- P1: gather K0 (self chunk = q tokens) -> kbuf
    issue_k(tq_s);
    write_k();
    __syncthreads();

    // ---- P2: Q frags from kbuf; issue V0; QK0; write V0
    #pragma unroll
    for (int s4 = 0; s4 < 4; ++s4) {
        int qr = (w * 16 + m) * 128 + (((s4 * 4 + g) ^ (m & 7)) << 3);
        qh[s4] = *(const f16x8*)&kbuf[qr];
    }
    issue_v(tq_s);
    qk_pass(0, rns0, tq_s);
    write_v();
    __syncthreads();

    // ---- P3: issue K1; PV0 (reads vbuf); write K1 (kbuf)
    issue_k(tk1_s);
    pv_pass();
    write_k();
    __syncthreads();

    // ---- P4: issue V1; QK1 (reads kbuf); write V1 (vbuf)
    issue_v(tk1_s);
    qk_pass(1, rns1, tk1_s);
    write_v();
    __syncthreads();

    // ---- P5: PV1 + epilogue
    pv_pass();

    densum += __shfl_xor(densum, 16, 64);
    densum += __shfl_xor(densum, 32, 64);

    if (DENSE) {
        const int h = c >> 6;
        const size_t base = (((size_t)(b * H_ + h)) << 12) + (size_t)(c & 63) * 64;
        #pragma unroll
        for (int r = 0; r < 4; ++r) {
            int row = w * 16 + g * 4 + r;
            _Float16* nrow = snum + (base + row) * D_;
            #pragma unroll
            for (int dt = 0; dt < 8; ++dt)
                __builtin_nontemporal_store((_Float16)acc_o[dt][r], nrow + dt * 16 + m);
        }
        if (g == 0) __builtin_nontemporal_store(densum, sden + base + w * 16 + m);
    } else {
        if (g == 0) atomicAdd(den + bS + qtok_m, densum);
        int4v q4tok = *(const int4v*)&tq_s[w * 16 + g * 4];
        #pragma unroll
        for (int r = 0; r < 4; ++r) {
            float* obase = outnum + ((bS + q4tok[r]) * D_);
            #pragma unroll
            for (int dt = 0; dt < 8; ++dt)
                atomicAdd(obase + dt * 16 + m, acc_o[dt][r]);
        }
    }
}

// ---------------------------------------------------------------- combine
__global__ __launch_bounds__(256) void combine_kernel(
        const _Float16* __restrict__ snum, const float* __restrict__ sden,
        const int* __restrict__ inv, float* __restrict__ out) {
    int wv = threadIdx.x >> 6, l = threadIdx.x & 63;
    int t = blockIdx.x * 4 + wv;          // 0 .. B*S-1
    int b = t >> 12, s = t & 4095;
    float s0 = 0.f, s1 = 0.f, dsum = 0.f;
    #pragma unroll
    for (int h = 0; h < H_; ++h) {
        int bh = b * H_ + h;
        int pos = inv[((size_t)bh << 12) + s];
        size_t row = ((size_t)bh << 12) + pos;
        dsum += __builtin_nontemporal_load(sden + row);
        unsigned uv = __builtin_nontemporal_load(
            (const unsigned*)(snum + row * D_ + 2 * l));
        unsigned short us0 = (unsigned short)(uv & 0xFFFFu);
        unsigned short us1 = (unsigned short)(uv >> 16);
        _Float16 h0, h1;
        __builtin_memcpy(&h0, &us0, 2);
        __builtin_memcpy(&h1, &us1, 2);
        s0 += (float)h0;
        s1 += (float)h1;
    }
    float rd = 1.0f / dsum;
    f32x2v o2 = {s0 * rd, s1 * rd};
    __builtin_nontemporal_store(o2, (f32x2v*)(out + (size_t)t * D_ + 2 * l));
}

// ---------------------------------------------------------------- divide (fallback)
__global__ __launch_bounds__(256) void div_kernel(float* __restrict__ out,
                                                  const float* __restrict__ den) {
    int i = blockIdx.x * 256 + threadIdx.x;  // float4 index
    float4 o = ((float4*)out)[i];
    float dn = den[i >> 5];
    ((float4*)out)[i] = make_float4(o.x / dn, o.y / dn, o.z / dn, o.w / dn);
}

// ---------------------------------------------------------------- launch
extern "C" void kernel_launch(void* const* d_in, const int* in_sizes, int n_in,
                              void* d_out, int out_size, void* d_ws, size_t ws_size,
                              hipStream_t stream) {
    const float* qk  = (const float*)d_in[0];
    const float* v   = (const float*)d_in[1];
    const float* rot = (const float*)d_in[2];
    float* out = (float*)d_out;

    char* ws = (char*)d_ws;
    float* rnrm    = (float*)ws;                        //   262,144 B
    int* buckets   = (int*)(ws + 262144);               // 2,097,152 B
    int* inv       = buckets;                           // aliased (safe: RAW per index)
    int* st        = (int*)(ws + 2359296);              // 2,097,152 B
    float* rnrm_s  = (float*)(ws + 4456448);            // 2,097,152 B
    float* sden    = (float*)(ws + 6553600);            // 2,097,152 B
    short* rth     = (short*)(ws + 8650752);            //    65,536 B
    short* rtl     = (short*)(ws + 8716288);            //    65,536 B
    _Float16* snum = (_Float16*)(ws + 8781824);         // 134,217,728 B
    const size_t need = 8781824ull + 134217728ull;

    norm_kernel<<<B_ * S_ / 8, 256, 0, stream>>>(qk, rnrm);
    prep_rot_kernel<<<32, 256, 0, stream>>>(rot, rth, rtl);
    hash_kernel<<<B_ * (S_ / 64), 256, 0, stream>>>(qk, rot, rth, rtl, buckets);
    sort_kernel<<<B_ * H_, 256, 0, stream>>>(buckets, st, inv, rnrm, rnrm_s);

    if (ws_size >= need) {
        attn_mfma_kernel<true><<<B_ * C_, 256, 0, stream>>>(
            qk, rnrm_s, v, st, nullptr, nullptr, snum, sden);
        combine_kernel<<<B_ * S_ / 4, 256, 0, stream>>>(snum, sden, inv, out);
    } else {
        float* den = sden;   // reuse slot
        hipMemsetAsync(out, 0, (size_t)B_ * S_ * D_ * 4, stream);
        hipMemsetAsync(den, 0, (size_t)B_ * S_ * 4, stream);
        attn_mfma_kernel<false><<<B_ * C_, 256, 0, stream>>>(
            qk, rnrm_s, v, st, out, den, nullptr, nullptr);
        div_kernel<<<B_ * S_ * D_ / 4 / 256, 256, 0, stream>>>(out, den);
    }
}

// Round 14
// 263.134 us; speedup vs baseline: 1.6821x; 1.0427x over previous
//
#include <hip/hip_runtime.h>
#include <hip/hip_bf16.h>

// LSH attention (Reformer-style), B=16, S=4096, D=128, H=8, bucket=64.
// norm -> prep_rot -> zero-LDS MFMA hash (hp-split grid, u64-key argmax,
// f64 margin-fallback) -> counting sort -> MFMA chunked attention
// (single-term f16, 2-buffer pipeline, dense f16 nt-stores) -> combine.

#define B_ 16
#define S_ 4096
#define D_ 128
#define H_ 8
#define C_ 512          // H * n_buckets
#define SCALE_ 0.08838834764831845f   // D^-0.5

typedef __attribute__((ext_vector_type(8))) short bf16x8;
typedef __attribute__((ext_vector_type(8))) _Float16 f16x8;
typedef __attribute__((ext_vector_type(2))) _Float16 f16x2t;
typedef __attribute__((ext_vector_type(4))) float f32x4;
typedef __attribute__((ext_vector_type(2))) float f32x2v;
typedef __attribute__((ext_vector_type(4))) int int4v;

union BF8U { int4v i; bf16x8 b; };
union F16x8U { int4v i; f16x8 h; };

// pack truncated-bf16 of two floats into one u32 (x0 -> low short)
__device__ __forceinline__ unsigned hi_pack(float x0, float x1) {
    unsigned a, b;
    __builtin_memcpy(&b, &x0, 4);
    __builtin_memcpy(&a, &x1, 4);
    return __builtin_amdgcn_perm(a, b, 0x07060302u);   // [x0.b2,x0.b3,x1.b2,x1.b3]
}
__device__ __forceinline__ float truncbf(float x) {
    unsigned u; __builtin_memcpy(&u, &x, 4);
    u &= 0xFFFF0000u;
    float f; __builtin_memcpy(&f, &u, 4);
    return f;
}
// pack two floats as f16 (RNE) into one u32
__device__ __forceinline__ unsigned pack2f16(float x0, float x1) {
    f16x2t h = {(_Float16)x0, (_Float16)x1};
    unsigned u; __builtin_memcpy(&u, &h, 4);
    return u;
}
// monotone float->u32 key map (order-preserving, all positives > negatives)
__device__ __forceinline__ unsigned enc_ks(unsigned u) {
    return (u & 0x80000000u) ? ~u : (u | 0x80000000u);
}
__device__ __forceinline__ float dec_ks(unsigned ks) {
    unsigned u = (ks & 0x80000000u) ? (ks ^ 0x80000000u) : ~ks;
    float f; __builtin_memcpy(&f, &u, 4);
    return f;
}

// ---------------------------------------------------------------- row 1/norm
__global__ __launch_bounds__(256) void norm_kernel(const float* __restrict__ qk,
                                                   float* __restrict__ rnrm) {
    int half = threadIdx.x >> 5;
    int lane32 = threadIdx.x & 31;
    size_t row = (size_t)blockIdx.x * 8 + half;
    float4 vv = ((const float4*)(qk + row * D_))[lane32];
    float ss = vv.x * vv.x + vv.y * vv.y + vv.z * vv.z + vv.w * vv.w;
    #pragma unroll
    for (int m = 1; m < 32; m <<= 1) ss += __shfl_xor(ss, m, 64);
    if (lane32 == 0) rnrm[row] = 1.0f / fmaxf(sqrtf(ss), 1e-12f);
}

// ---------------------------------------------------------------- prep rot
// rth[hp*8192 + ia*128 + swz(ft,ia)] = bf16hi of rot[(ft*4+j)*256 + hp*64 + ia]
__global__ __launch_bounds__(256) void prep_rot_kernel(const float* __restrict__ rot,
                                                       short* __restrict__ rth,
                                                       short* __restrict__ rtl) {
    int x = blockIdx.x * 256 + threadIdx.x;   // 0..8191
    int hp = x >> 11;
    int ia = (x >> 5) & 63;
    int ft = x & 31;
    float v0 = rot[(size_t)(ft * 4 + 0) * 256 + hp * 64 + ia];
    float v1 = rot[(size_t)(ft * 4 + 1) * 256 + hp * 64 + ia];
    float v2 = rot[(size_t)(ft * 4 + 2) * 256 + hp * 64 + ia];
    float v3 = rot[(size_t)(ft * 4 + 3) * 256 + hp * 64 + ia];
    unsigned h0 = hi_pack(v0, v1), h1 = hi_pack(v2, v3);
    unsigned l0 = hi_pack(v0 - truncbf(v0), v1 - truncbf(v1));
    unsigned l1 = hi_pack(v2 - truncbf(v2), v3 - truncbf(v3));
    int off = ia * 128 + ((((ft >> 1) ^ (ia & 7)) << 3) | ((ft & 1) << 2));
    *(int2*)&rth[hp * 8192 + off] = make_int2((int)h0, (int)h1);
    *(int2*)&rtl[hp * 8192 + off] = make_int2((int)l0, (int)l1);
}

// ---------------------------------------------------------------- MFMA hashing
// One block per (b, tile, hp): 64 tokens x 64 cols (heads 2hp, 2hp+1).
// Zero-LDS main path; compact u64-key argmax; f64 fallback for tight margins.
__global__ __launch_bounds__(256, 4) void hash_kernel(
        const float* __restrict__ qk, const float* __restrict__ rot,
        const short* __restrict__ rth, const short* __restrict__ rtl,
        int* __restrict__ buckets) {
    __shared__ unsigned char flags[2][64];     // fallback flags (128 B)

    const int bid = blockIdx.x;
    const int b = bid >> 8;
    const int tile = (bid >> 2) & 63;
    const int hp = bid & 3;
    const int tid = threadIdx.x;
    const int w = tid >> 6, l = tid & 63, g = l >> 4, m = l & 15;

    if (tid < 8) ((int4*)flags)[tid] = make_int4(0, 0, 0, 0);
    __syncthreads();

    // A-frags: Q[w*16+m][s*32+g*8+j] trunc hi/lo, straight from global
    const float* qrow = qk + ((size_t)b * S_ + (size_t)tile * 64 + w * 16 + m) * D_;
    bf16x8 qh[4], qlr[4];
    #pragma unroll
    for (int s = 0; s < 4; ++s) {
        float4 xa = *(const float4*)(qrow + s * 32 + g * 8);
        float4 xb = *(const float4*)(qrow + s * 32 + g * 8 + 4);
        BF8U hu, lu;
        hu.i[0] = (int)hi_pack(xa.x, xa.y); hu.i[1] = (int)hi_pack(xa.z, xa.w);
        hu.i[2] = (int)hi_pack(xb.x, xb.y); hu.i[3] = (int)hi_pack(xb.z, xb.w);
        lu.i[0] = (int)hi_pack(xa.x - truncbf(xa.x), xa.y - truncbf(xa.y));
        lu.i[1] = (int)hi_pack(xa.z - truncbf(xa.z), xa.w - truncbf(xa.w));
        lu.i[2] = (int)hi_pack(xb.x - truncbf(xb.x), xb.y - truncbf(xb.y));
        lu.i[3] = (int)hi_pack(xb.z - truncbf(xb.z), xb.w - truncbf(xb.w));
        qh[s] = hu.b; qlr[s] = lu.b;
    }

    // dots tiles: C[tok = w*16+g*4+r][col = nt*16+m]; B-frags from global
    f32x4 dots_n[4];
    #pragma unroll
    for (int nt = 0; nt < 4; ++nt) {
        f32x4 acc = (f32x4){0.f, 0.f, 0.f, 0.f};
        #pragma unroll
        for (int s = 0; s < 4; ++s) {
            int kr = hp * 8192 + (nt * 16 + m) * 128 + (((s * 4 + g) ^ (m & 7)) << 3);
            bf16x8 bh = *(const bf16x8*)&rth[kr];
            bf16x8 bl = *(const bf16x8*)&rtl[kr];
            acc = __builtin_amdgcn_mfma_f32_16x16x32_bf16(qh[s], bh, acc, 0, 0, 0);
            acc = __builtin_amdgcn_mfma_f32_16x16x32_bf16(qh[s], bl, acc, 0, 0, 0);
            acc = __builtin_amdgcn_mfma_f32_16x16x32_bf16(qlr[s], bh, acc, 0, 0, 0);
        }
        dots_n[nt] = acc;
    }

    // argmax per (token, hh) via u64 keys: key = (enc(v)<<6) | (63-i)
    #pragma unroll
    for (int hh = 0; hh < 2; ++hh) {
        int h = hp * 2 + hh;
        #pragma unroll
        for (int r = 0; r < 4; ++r) {
            unsigned long long kM = 0ull, kS = 0ull;
            #pragma unroll
            for (int nn = 0; nn < 2; ++nn) {
                float v = dots_n[hh * 2 + nn][r];
                unsigned u; __builtin_memcpy(&u, &v, 4);
                int i = nn * 16 + m;
                unsigned long long kp =
                    ((unsigned long long)enc_ks(u) << 6) | (unsigned)(63 - i);
                unsigned long long kn =
                    ((unsigned long long)enc_ks(u ^ 0x80000000u) << 6) |
                    (unsigned)(63 - (i + 32));
                if (kp > kM) { kS = kM; kM = kp; } else if (kp > kS) kS = kp;
                if (kn > kM) { kS = kM; kM = kn; } else if (kn > kS) kS = kn;
            }
            #pragma unroll
            for (int st = 1; st <= 8; st <<= 1) {
                unsigned long long oM = __shfl_xor(kM, st, 64);
                unsigned long long oS = __shfl_xor(kS, st, 64);
                unsigned long long lo = kM < oM ? kM : oM;
                kM = kM > oM ? kM : oM;
                unsigned long long hs = kS > oS ? kS : oS;
                kS = hs > lo ? hs : lo;
            }
            if (m == 0) {
                int tok = w * 16 + g * 4 + r;
                int i1 = 63 - (int)(kM & 63ull);
                float v1 = dec_ks((unsigned)(kM >> 6));
                float v2 = dec_ks((unsigned)(kS >> 6));
                if (v1 - v2 < 2e-2f) flags[hh][tok] = 1;
                buckets[(((size_t)(b * H_ + h)) << 12) + tile * 64 + tok] = i1;
            }
        }
    }
    __syncthreads();

    // exact f64 fallback for small-margin (tok,hh) (rare); reads qk from global
    int tok = tid >> 2, part = tid & 3;
    const float* qtok = qk + ((size_t)b * S_ + (size_t)tile * 64 + tok) * D_;
    for (int hh = 0; hh < 2; ++hh) {
        if (!flags[hh][tok]) continue;
        int h = hp * 2 + hh;
        double pd[8] = {0, 0, 0, 0, 0, 0, 0, 0};
        #pragma unroll 2
        for (int f = 0; f < 128; ++f) {
            double q = (double)qtok[f];
            const float* rp = rot + (size_t)f * 256 + h * 32 + part * 8;
            float4 r0 = *(const float4*)rp;
            float4 r1 = *(const float4*)(rp + 4);
            pd[0] = fma(q, (double)r0.x, pd[0]);
            pd[1] = fma(q, (double)r0.y, pd[1]);
            pd[2] = fma(q, (double)r0.z, pd[2]);
            pd[3] = fma(q, (double)r0.w, pd[3]);
            pd[4] = fma(q, (double)r1.x, pd[4]);
            pd[5] = fma(q, (double)r1.y, pd[5]);
            pd[6] = fma(q, (double)r1.z, pd[6]);
            pd[7] = fma(q, (double)r1.w, pd[7]);
        }
        double bv = -1e300; int bi = 0;
        #pragma unroll
        for (int ii = 0; ii < 8; ++ii) {
            int i = part * 8 + ii;
            double v = pd[ii];
            if (v > bv || (v == bv && i < bi)) { bv = v; bi = i; }
            double nv = -v; int ni = i + 32;
            if (nv > bv || (nv == bv && ni < bi)) { bv = nv; bi = ni; }
        }
        #pragma unroll
        for (int mm = 1; mm <= 2; mm <<= 1) {
            double ov = __shfl_xor(bv, mm, 64);
            int oi = __shfl_xor(bi, mm, 64);
            if (ov > bv || (ov == bv && oi < bi)) { bv = ov; bi = oi; }
        }
        if (part == 0)
            buckets[(((size_t)(b * H_ + h)) << 12) + tile * 64 + tok] = bi;
    }
}

// ---------------------------------------------------------------- stable counting sort
__global__ __launch_bounds__(256) void sort_kernel(const int* __restrict__ buckets,
                                                   int* __restrict__ st,
                                                   int* __restrict__ inv,
                                                   const float* __restrict__ rnrm,
                                                   float* __restrict__ rnrm_s) {
    __shared__ unsigned short hist[256][64];
    __shared__ int base[64];
    __shared__ int totals[64];
    int tid = threadIdx.x;
    const int* bkrow = buckets + (size_t)blockIdx.x * S_;
    const float* rnb = rnrm + (size_t)(blockIdx.x >> 3) * S_;

    unsigned int* h32 = (unsigned int*)hist;
    #pragma unroll
    for (int u = 0; u < 32; ++u) h32[u * 256 + tid] = 0;
    __syncthreads();

    #pragma unroll
    for (int u = 0; u < 16; ++u) {
        int t = tid * 16 + u;
        int bk = bkrow[t];
        hist[tid][bk]++;
    }
    __syncthreads();

    if (tid < 64) {
        int bucket = tid;
        int run = 0;
        for (int ch = 0; ch < 256; ++ch) {
            int v = hist[ch][bucket];
            hist[ch][bucket] = (unsigned short)run;
            run += v;
        }
        totals[bucket] = run;
    }
    __syncthreads();
    if (tid == 0) {
        int acc = 0;
        for (int k = 0; k < 64; ++k) { base[k] = acc; acc += totals[k]; }
    }
    __syncthreads();

    int* strow = st + (size_t)blockIdx.x * S_;
    int* invrow = inv + (size_t)blockIdx.x * S_;
    float* rnsrow = rnrm_s + (size_t)blockIdx.x * S_;
    #pragma unroll
    for (int u = 0; u < 16; ++u) {
        int t = tid * 16 + u;
        int bk = bkrow[t];
        int off = hist[tid][bk];
        hist[tid][bk] = (unsigned short)(off + 1);
        int pos = base[bk] + off;
        strow[pos] = t;
        invrow[t] = pos;
        rnsrow[pos] = rnb[t] * SCALE_;
    }
}

// ---------------------------------------------------------------- in-reg 4x4 transpose
__device__ __forceinline__ void transpose4(const float4 v, int g, float (&w_)[4]) {
    bool b0 = (g & 1) != 0, b1 = (g & 2) != 0;
    float k0 = b1 ? v.z : v.x;
    float k1 = b1 ? v.w : v.y;
    float s0 = b1 ? v.x : v.z;
    float s1 = b1 ? v.y : v.w;
    float r0 = __shfl_xor(s0, 32, 64);
    float r1 = __shfl_xor(s1, 32, 64);
    float kq_ = b0 ? k1 : k0;
    float rq_ = b0 ? r1 : r0;
    float sk  = b0 ? k0 : k1;
    float sr  = b0 ? r0 : r1;
    float tk_ = __shfl_xor(sk, 16, 64);
    float tr_ = __shfl_xor(sr, 16, 64);
    float A0 = b0 ? tk_ : kq_;
    float A1 = b0 ? kq_ : tk_;
    float B0 = b0 ? tr_ : rq_;
    float B1 = b0 ? rq_ : tr_;
    w_[0] = b1 ? B0 : A0;
    w_[1] = b1 ? B1 : A1;
    w_[2] = b1 ? A0 : B0;
    w_[3] = b1 ? A1 : B1;
}

// ---------------------------------------------------------------- MFMA attention
// One block per (b, chunk c): 64 q vs 128 k (chunks c, c-1 mod 512).
// Single-term f16 MFMA; two LDS buffers (K 16KB, V 16KB) -> 4 blocks/CU.
template<bool DENSE>
__global__ __launch_bounds__(256, 4) void attn_mfma_kernel(
        const float* __restrict__ qk, const float* __restrict__ rnrm_s,
        const float* __restrict__ vglob, const int* __restrict__ st,
        float* __restrict__ outnum, float* __restrict__ den,
        _Float16* __restrict__ snum, float* __restrict__ sden) {
    __shared__ int tq_s[64];
    __shared__ int tk1_s[64];
    __shared__ float rns0[64];
    __shared__ float rns1[64];
    __shared__ short kbuf[8192];    // K f16, swizzled rows (16 KB)
    __shared__ short vbuf[8192];    // V^T f16, swizzled (16 KB)

    // XCD swizzle: logical L = (p%8)*1024 + p/8 -> each batch on one XCD.
    const int p = blockIdx.x;
    const int bc = (p & 7) * 1024 + (p >> 3);
    const int b  = bc >> 9;
    const int c  = bc & 511;
    const int tid = threadIdx.x;
    const int w   = tid >> 6;   // wave 0..3
    const int l   = tid & 63;
    const int g   = l >> 4;     // quad 0..3
    const int m   = l & 15;
    const size_t bS = ((size_t)b << 12);
    const int* stb = st + ((size_t)b << 15);

    const int c1 = (c + 511) & 511;
    if (tid < 64) {
        tq_s[tid]  = stb[c * 64 + tid];
        tk1_s[tid] = stb[c1 * 64 + tid];
        rns0[tid] = rnrm_s[(((size_t)(b * H_ + (c >> 6))) << 12) + (size_t)(c & 63) * 64 + tid];
        rns1[tid] = rnrm_s[(((size_t)(b * H_ + (c1 >> 6))) << 12) + (size_t)(c1 & 63) * 64 + tid];
    }
    __syncthreads();

    const int qtok_m = tq_s[w * 16 + m];   // this lane's q column token

    f16x8 qh[4];
    f32x4 e4[4];
    f32x4 acc_o[8];
    #pragma unroll
    for (int dt = 0; dt < 8; ++dt) acc_o[dt] = (f32x4){0.f, 0.f, 0.f, 0.f};
    float densum = 0.0f;

    float4 kreg[8];
    float4 va[4], vb[4];

    auto issue_k = [&](const int* __restrict__ toks) {
        #pragma unroll
        for (int u = 0; u < 8; ++u) {
            int token = u * 8 + (tid >> 5);
            int cc = tid & 31;
            kreg[u] = *(const float4*)(qk + (bS + toks[token]) * D_ + cc * 4);
        }
    };
    auto write_k = [&]() {
        #pragma unroll
        for (int u = 0; u < 8; ++u) {
            int token = u * 8 + (tid >> 5);
            int cc = tid & 31;
            float4 vv = kreg[u];
            unsigned h0 = pack2f16(vv.x, vv.y), h1 = pack2f16(vv.z, vv.w);
            int kw = token * 128 + ((((cc >> 1) ^ (token & 7)) << 3) | ((cc & 1) << 2));
            *(int2*)&kbuf[kw] = make_int2((int)h0, (int)h1);
        }
    };
    auto issue_v = [&](const int* __restrict__ toks) {
        #pragma unroll
        for (int up = 0; up < 4; ++up) {
            int kq8 = w * 16 + (up & 1) * 8;
            int cc = (up >> 1) * 16 + m;
            va[up] = *(const float4*)(vglob + (bS + toks[kq8 + g]) * D_ + cc * 4);
            vb[up] = *(const float4*)(vglob + (bS + toks[kq8 + 4 + g]) * D_ + cc * 4);
        }
    };
    auto write_v = [&]() {
        #pragma unroll
        for (int up = 0; up < 4; ++up) {
            int kq8 = w * 16 + (up & 1) * 8;
            int cc = (up >> 1) * 16 + m;
            float wa[4], wb[4];
            transpose4(va[up], g, wa);          // wa[i] = (token kq8+i, dim cc*4+g)
            transpose4(vb[up], g, wb);
            unsigned h0 = pack2f16(wa[0], wa[1]), h1 = pack2f16(wa[2], wa[3]);
            unsigned h2 = pack2f16(wb[0], wb[1]), h3 = pack2f16(wb[2], wb[3]);
            int d = cc * 4 + g;
            int ds = d ^ ((d >> 3) & 7);
            int kg = kq8 >> 3;
            int idx = (kg * 128 + ds) * 8;
            *(int4*)&vbuf[idx] = make_int4((int)h0, (int)h1, (int)h2, (int)h3);
        }
    };
    auto qk_pass = [&](int mode, const float* __restrict__ rns,
                       const int* __restrict__ tkp) {
        #pragma unroll
        for (int kt = 0; kt < 4; ++kt) {
            f32x4 acc = (f32x4){0.f, 0.f, 0.f, 0.f};
            #pragma unroll
            for (int s4 = 0; s4 < 4; ++s4) {
                int kr = (kt * 16 + m) * 128 + (((s4 * 4 + g) ^ (m & 7)) << 3);
                f16x8 ah = *(const f16x8*)&kbuf[kr];
                acc = __builtin_amdgcn_mfma_f32_16x16x32_f16(ah, qh[s4], acc, 0, 0, 0);
            }
            f32x4 rn4 = *(const f32x4*)&rns[kt * 16 + g * 4];
            int4v kt4;
            if (mode == 1) kt4 = *(const int4v*)&tkp[kt * 16 + g * 4];
            f32x4 e;
            #pragma unroll
            for (int r = 0; r < 4; ++r) {
                float ev = __expf(acc[r] * rn4[r]);
                if (mode == 0) {
                    if (kt == w && (g * 4 + r) == m) ev = 0.0f;
                } else {
                    if (kt4[r] == qtok_m) ev = 0.0f;
                }
                e[r] = ev;
                densum += ev;
            }
            e4[kt] = e;
        }
    };
    auto pv_pass = [&]() {
        #pragma unroll
        for (int s = 0; s < 2; ++s) {
            float pav[8];
            #pragma unroll
            for (int c2 = 0; c2 < 2; ++c2) {
                int srcLane = ((g & 1) * 2 + c2) * 16 + m;
                #pragma unroll
                for (int r = 0; r < 4; ++r) {
                    float v0 = __shfl(e4[2 * s][r], srcLane, 64);
                    float v1 = __shfl(e4[2 * s + 1][r], srcLane, 64);
                    pav[c2 * 4 + r] = (g >> 1) ? v1 : v0;
                }
            }
            F16x8U pahu;
            #pragma unroll
            for (int j2 = 0; j2 < 4; ++j2)
                pahu.i[j2] = (int)pack2f16(pav[2 * j2], pav[2 * j2 + 1]);
            f16x8 pah = pahu.h;
            #pragma unroll
            for (int dt = 0; dt < 8; ++dt) {
                int d = dt * 16 + m;
                int ds = d ^ ((d >> 3) & 7);
                int base = ((s * 4 + g) * 128 + ds) * 8;
                f16x8 vh = *(const f16x8*)&vbuf[base];
                acc_o[dt] = __builtin_amdgcn_mfma_f32_16x16x32_f16(pah, vh, acc_o[dt], 0, 0, 0);
            }
        }
    };

    // ---- P1: gather K0 (self chunk = q tokens) -> kbuf
    issue_k(tq_s);
    write_k();
    __syncthreads();

    // ---- P2: Q frags from kbuf; issue V0; QK0; write V0
    #pragma unroll
    for (int s4 = 0; s4 < 4; ++s4) {
        int qr = (w * 16 + m) * 128 + (((s4 * 4 + g) ^ (m & 7)) << 3);
        qh[s4] = *(const f16x8*)&kbuf[qr];
    }
    issue_v(tq_s);
    qk_pass(0, rns0, tq_s);
    write_v();
    __syncthreads();

    // ---- P3: issue K1; PV0 (reads vbuf); write K1 (kbuf)
    issue_k(tk1_s);
    pv_pass();
    write_k();
    __syncthreads();

    // ---- P4: issue V1; QK1 (reads kbuf); write V1 (vbuf)
    issue_v(tk1_s);
    qk_pass(1, rns1, tk1_s);
    write_v();
    __syncthreads();

    // ---- P5: PV1 + epilogue
    pv_pass();

    densum += __shfl_xor(densum, 16, 64);
    densum += __shfl_xor(densum, 32, 64);

    if (DENSE) {
        const int h = c >> 6;
        const size_t base = (((size_t)(b * H_ + h)) << 12) + (size_t)(c & 63) * 64;
        #pragma unroll
        for (int r = 0; r < 4; ++r) {
            int row = w * 16 + g * 4 + r;
            _Float16* nrow = snum + (base + row) * D_;
            #pragma unroll
            for (int dt = 0; dt < 8; ++dt)
                __builtin_nontemporal_store((_Float16)acc_o[dt][r], nrow + dt * 16 + m);
        }
        if (g == 0) __builtin_nontemporal_store(densum, sden + base + w * 16 + m);
    } else {
        if (g == 0) atomicAdd(den + bS + qtok_m, densum);
        int4v q4tok = *(const int4v*)&tq_s[w * 16 + g * 4];
        #pragma unroll
        for (int r = 0; r < 4; ++r) {
            float* obase = outnum + ((bS + q4tok[r]) * D_);
            #pragma unroll
            for (int dt = 0; dt < 8; ++dt)
                atomicAdd(obase + dt * 16 + m, acc_o[dt][r]);
        }
    }
}

// ---------------------------------------------------------------- combine
__global__ __launch_bounds__(256) void combine_kernel(
        const _Float16* __restrict__ snum, const float* __restrict__ sden,
        const int* __restrict__ inv, float* __restrict__ out) {
    int wv = threadIdx.x >> 6, l = threadIdx.x & 63;
    int t = blockIdx.x * 4 + wv;          // 0 .. B*S-1
    int b = t >> 12, s = t & 4095;
    float s0 = 0.f, s1 = 0.f, dsum = 0.f;
    #pragma unroll
    for (int h = 0; h < H_; ++h) {
        int bh = b * H_ + h;
        int pos = inv[((size_t)bh << 12) + s];
        size_t row = ((size_t)bh << 12) + pos;
        dsum += __builtin_nontemporal_load(sden + row);
        unsigned uv = __builtin_nontemporal_load(
            (const unsigned*)(snum + row * D_ + 2 * l));
        unsigned short us0 = (unsigned short)(uv & 0xFFFFu);
        unsigned short us1 = (unsigned short)(uv >> 16);
        _Float16 h0, h1;
        __builtin_memcpy(&h0, &us0, 2);
        __builtin_memcpy(&h1, &us1, 2);
        s0 += (float)h0;
        s1 += (float)h1;
    }
    float rd = 1.0f / dsum;
    f32x2v o2 = {s0 * rd, s1 * rd};
    __builtin_nontemporal_store(o2, (f32x2v*)(out + (size_t)t * D_ + 2 * l));
}

// ---------------------------------------------------------------- divide (fallback)
__global__ __launch_bounds__(256) void div_kernel(float* __restrict__ out,
                                                  const float* __restrict__ den) {
    int i = blockIdx.x * 256 + threadIdx.x;  // float4 index
    float4 o = ((float4*)out)[i];
    float dn = den[i >> 5];
    ((float4*)out)[i] = make_float4(o.x / dn, o.y / dn, o.z / dn, o.w / dn);
}

// ---------------------------------------------------------------- launch
extern "C" void kernel_launch(void* const* d_in, const int* in_sizes, int n_in,
                              void* d_out, int out_size, void* d_ws, size_t ws_size,
                              hipStream_t stream) {
    const float* qk  = (const float*)d_in[0];
    const float* v   = (const float*)d_in[1];
    const float* rot = (const float*)d_in[2];
    float* out = (float*)d_out;

    char* ws = (char*)d_ws;
    float* rnrm    = (float*)ws;                        //   262,144 B
    int* buckets   = (int*)(ws + 262144);               // 2,097,152 B
    int* inv       = buckets;                           // aliased (safe: RAW per index)
    int* st        = (int*)(ws + 2359296);              // 2,097,152 B
    float* rnrm_s  = (float*)(ws + 4456448);            // 2,097,152 B
    float* sden    = (float*)(ws + 6553600);            // 2,097,152 B
    short* rth     = (short*)(ws + 8650752);            //    65,536 B
    short* rtl     = (short*)(ws + 8716288);            //    65,536 B
    _Float16* snum = (_Float16*)(ws + 8781824);         // 134,217,728 B
    const size_t need = 8781824ull + 134217728ull;

    norm_kernel<<<B_ * S_ / 8, 256, 0, stream>>>(qk, rnrm);
    prep_rot_kernel<<<32, 256, 0, stream>>>(rot, rth, rtl);
    hash_kernel<<<B_ * (S_ / 64) * 4, 256, 0, stream>>>(qk, rot, rth, rtl, buckets);
    sort_kernel<<<B_ * H_, 256, 0, stream>>>(buckets, st, inv, rnrm, rnrm_s);

    if (ws_size >= need) {
        attn_mfma_kernel<true><<<B_ * C_, 256, 0, stream>>>(
            qk, rnrm_s, v, st, nullptr, nullptr, snum, sden);
        combine_kernel<<<B_ * S_ / 4, 256, 0, stream>>>(snum, sden, inv, out);
    } else {
        float* den = sden;   // reuse slot
        hipMemsetAsync(out, 0, (size_t)B_ * S_ * D_ * 4, stream);
        hipMemsetAsync(den, 0, (size_t)B_ * S_ * 4, stream);
        attn_mfma_kernel<false><<<B_ * C_, 256, 0, stream>>>(
            qk, rnrm_s, v, st, out, den, nullptr, nullptr);
        div_kernel<<<B_ * S_ * D_ / 4 / 256, 256, 0, stream>>>(out, den);
    }
}